// Round 4
// baseline (789.915 us; speedup 1.0000x reference)
//
#include <hip/hip_runtime.h>

#define NB 65536
#define NSTEP 128
#define HD 64
#define RB 1.05f
#define SCALE 2.8853900817779268f   // 2*log2(e)

typedef __bf16 bf16x8 __attribute__((ext_vector_type(8)));
typedef float f32x4 __attribute__((ext_vector_type(4)));
typedef unsigned int uint;
typedef unsigned short ushort;

extern "C" __device__ float __ocml_native_exp2_f32(float);
#if __has_builtin(__builtin_amdgcn_exp2f)
#define EXP2(x) __builtin_amdgcn_exp2f(x)
#else
#define EXP2(x) __ocml_native_exp2_f32(x)
#endif

// tanh(x) = 1 - 2/(1+e^{2x})  (classic form, used on the once-only u_pre0 path)
__device__ __forceinline__ float tanh_fast(float x) {
    float e2 = __expf(2.0f * x);
    return 1.0f - 2.0f * __builtin_amdgcn_rcpf(1.0f + e2);
}

// tanh from pre-scaled input z = 2*log2(e)*x :  1 - 2/(1+2^z)
__device__ __forceinline__ float tanh_s(float z) {
    return 1.0f - 2.0f * __builtin_amdgcn_rcpf(1.0f + EXP2(z));
}

// pack two f32 -> (bf16(b)<<16)|bf16(a), truncation, single v_perm_b32
__device__ __forceinline__ uint pack_bf16_trunc(float a, float b) {
    return __builtin_amdgcn_perm(__float_as_uint(b), __float_as_uint(a), 0x07060302u);
}

__device__ __forceinline__ ushort bf16_rne(float f) {
    uint u = __float_as_uint(f);
    u += 0x7fffu + ((u >> 16) & 1u);
    return (ushort)(u >> 16);
}

// Pack SCALE*Wg1 (N x 64 x 64 f32) into bf16 A-fragments for mfma_f32_16x16x32_bf16.
// A = SCALE*W1^T.  lane holds A[row = I*16 + (lane&15)][k = kk*32 + (lane>>4)*8 + e]
// blob index: wsA[((t*2+kk)*4+I)*64 + lane]  (uint4 = 8 bf16)
__global__ __launch_bounds__(256) void prep_kernel(const float* __restrict__ Wg1,
                                                   uint4* __restrict__ wsA) {
    int tid  = blockIdx.x * 256 + threadIdx.x;
    int lane = tid & 63;
    int I    = (tid >> 6) & 3;
    int kk   = (tid >> 8) & 1;
    int t    = tid >> 9;
    int row  = I * 16 + (lane & 15);
    int k0   = kk * 32 + ((lane >> 4) & 3) * 8;
    const float* src = Wg1 + ((size_t)t * HD + k0) * HD + row;
    ushort o[8];
#pragma unroll
    for (int e = 0; e < 8; e++) o[e] = bf16_rne(src[(size_t)e * HD] * SCALE);
    uint4 v;
    v.x = (uint)o[0] | ((uint)o[1] << 16);
    v.y = (uint)o[2] | ((uint)o[3] << 16);
    v.z = (uint)o[4] | ((uint)o[5] << 16);
    v.w = (uint)o[6] | ((uint)o[7] << 16);
    wsA[tid] = v;
}

// scaled bias copies: dst[0..8191] = SCALE*bg0, dst[8192..16383] = SCALE*bg1
__global__ __launch_bounds__(256) void prep_bias(const float* __restrict__ bg0,
                                                 const float* __restrict__ bg1,
                                                 float* __restrict__ dst) {
    int i = blockIdx.x * 256 + threadIdx.x;
    dst[i] = SCALE * bg0[i];
    dst[8192 + i] = SCALE * bg1[i];
}

// --------- shared helper (unscaled, used for u_pre0 and the fallback) ----------
template <int PACKED>
__device__ __forceinline__ void mlp_h2(float xx, float xy, float xz,
                                       const float* __restrict__ w0,
                                       const float* __restrict__ c0,
                                       const uint4* __restrict__ apk,
                                       const float* __restrict__ w1,
                                       int lane, f32x4* acc) {
    const int g16 = (lane >> 4) & 3;
    const int l15 = lane & 15;
#pragma unroll
    for (int kk = 0; kk < 2; kk++) {
        bf16x8 af[4];
        if (PACKED) {
            const uint4* bp = apk + kk * 256 + lane;
#pragma unroll
            for (int I = 0; I < 4; I++) af[I] = __builtin_bit_cast(bf16x8, bp[I * 64]);
        } else {
#pragma unroll
            for (int I = 0; I < 4; I++) {
                uint pk[4];
#pragma unroll
                for (int ep = 0; ep < 4; ep++) {
                    float f0 = w1[(kk * 32 + g16 * 8 + 2 * ep + 0) * HD + I * 16 + l15];
                    float f1 = w1[(kk * 32 + g16 * 8 + 2 * ep + 1) * HD + I * 16 + l15];
                    pk[ep] = (uint)bf16_rne(f0) | ((uint)bf16_rne(f1) << 16);
                }
                uint4 v; v.x = pk[0]; v.y = pk[1]; v.z = pk[2]; v.w = pk[3];
                af[I] = __builtin_bit_cast(bf16x8, v);
            }
        }
        const float* wk = w0 + kk * 32 + g16 * 8;
        float4 wxa = *(const float4*)(wk);
        float4 wxb = *(const float4*)(wk + 4);
        float4 wya = *(const float4*)(wk + HD);
        float4 wyb = *(const float4*)(wk + HD + 4);
        float4 wza = *(const float4*)(wk + 2 * HD);
        float4 wzb = *(const float4*)(wk + 2 * HD + 4);
        const float* ck = c0 + kk * 32 + g16 * 8;
        float4 cva = *(const float4*)(ck);
        float4 cvb = *(const float4*)(ck + 4);
        float p0 = fmaf(xx, wxa.x, fmaf(xy, wya.x, fmaf(xz, wza.x, cva.x)));
        float p1 = fmaf(xx, wxa.y, fmaf(xy, wya.y, fmaf(xz, wza.y, cva.y)));
        float p2 = fmaf(xx, wxa.z, fmaf(xy, wya.z, fmaf(xz, wza.z, cva.z)));
        float p3 = fmaf(xx, wxa.w, fmaf(xy, wya.w, fmaf(xz, wza.w, cva.w)));
        float p4 = fmaf(xx, wxb.x, fmaf(xy, wyb.x, fmaf(xz, wzb.x, cvb.x)));
        float p5 = fmaf(xx, wxb.y, fmaf(xy, wyb.y, fmaf(xz, wzb.y, cvb.y)));
        float p6 = fmaf(xx, wxb.z, fmaf(xy, wyb.z, fmaf(xz, wzb.z, cvb.z)));
        float p7 = fmaf(xx, wxb.w, fmaf(xy, wyb.w, fmaf(xz, wzb.w, cvb.w)));
        uint4 bv;
        bv.x = pack_bf16_trunc(tanh_fast(p0), tanh_fast(p1));
        bv.y = pack_bf16_trunc(tanh_fast(p2), tanh_fast(p3));
        bv.z = pack_bf16_trunc(tanh_fast(p4), tanh_fast(p5));
        bv.w = pack_bf16_trunc(tanh_fast(p6), tanh_fast(p7));
        bf16x8 bf = __builtin_bit_cast(bf16x8, bv);
#pragma unroll
        for (int I = 0; I < 4; I++)
            acc[I] = __builtin_amdgcn_mfma_f32_16x16x32_bf16(af[I], bf, acc[I], 0, 0, 0);
    }
}

// ------------------------- fast path (prefetch + scaled) -------------------------

struct StepBuf { uint4 af[8]; float2 dB; };

struct PState {
    float xtx, xty, xtz, xix, xiy, xiz;
    float g00, g01, g02, g10, g11, g12, g20, g21, g22;
    float u_pre;
};

__device__ __forceinline__ void load_step(int t, int lane, int p,
                                          const uint4* __restrict__ wsA,
                                          const float* __restrict__ dBt,
                                          StepBuf& s) {
    const uint4* bp = wsA + (size_t)t * 512 + lane;
#pragma unroll
    for (int f = 0; f < 8; f++) s.af[f] = bp[f * 64];
    s.dB = *(const float2*)(dBt + ((size_t)t * NB + p) * 2);
}

__device__ __forceinline__ void do_step(int t, int lane, int g16, const StepBuf& s,
                                        const float* __restrict__ Wg0,
                                        const float* __restrict__ c0s,
                                        const float* __restrict__ c1s,
                                        const float* __restrict__ Wg2,
                                        const float* __restrict__ bg2,
                                        PState& S) {
    const float* w0 = Wg0 + (size_t)t * 3 * HD;
    const float* c0 = c0s + (size_t)t * HD;     // pre-scaled by SCALE
    const float* c1 = c1s + (size_t)t * HD;     // pre-scaled by SCALE
    const float* w2 = Wg2 + (size_t)t * HD * 3;
    const float* c2 = bg2 + (size_t)t * 3;

    // --- geometry (bit-identical to R3) ---
    float r = sqrtf(fmaf(S.xtx, S.xtx, fmaf(S.xty, S.xty, S.xtz * S.xtz)));
    float uu = S.xtz / r;
    uu = fminf(fmaxf(uu, -0.999999f), 0.999999f);
    float ca = sqrtf((1.0f - uu) * (1.0f + uu));
    float sa = -uu;
    float rho = sqrtf(fmaf(S.xtx, S.xtx, S.xty * S.xty));
    float cp = (rho > 0.0f) ? (S.xtx / rho) : 1.0f;
    float sp = (rho > 0.0f) ? (S.xty / rho) : 0.0f;
    float T00 = cp * ca, T01 = -sp, T02 = cp * sa;
    float T10 = sp * ca, T11 = cp,  T12 = sp * sa;
    float T20 = -sa,               T22 = ca;   // T21 = 0

    // --- MLP layer 1 + MFMA (scaled weights; inputs pre-multiplied by SCALE) ---
    float xx2 = S.xix * SCALE, xy2 = S.xiy * SCALE, xz2 = S.xiz * SCALE;
    f32x4 acc[4];
#pragma unroll
    for (int I = 0; I < 4; I++) acc[I] = (f32x4){0.f, 0.f, 0.f, 0.f};
#pragma unroll
    for (int kk = 0; kk < 2; kk++) {
        const float* wk = w0 + kk * 32 + g16 * 8;
        float4 wxa = *(const float4*)(wk);
        float4 wxb = *(const float4*)(wk + 4);
        float4 wya = *(const float4*)(wk + HD);
        float4 wyb = *(const float4*)(wk + HD + 4);
        float4 wza = *(const float4*)(wk + 2 * HD);
        float4 wzb = *(const float4*)(wk + 2 * HD + 4);
        const float* ck = c0 + kk * 32 + g16 * 8;
        float4 cva = *(const float4*)(ck);
        float4 cvb = *(const float4*)(ck + 4);
        float p0 = fmaf(xx2, wxa.x, fmaf(xy2, wya.x, fmaf(xz2, wza.x, cva.x)));
        float p1 = fmaf(xx2, wxa.y, fmaf(xy2, wya.y, fmaf(xz2, wza.y, cva.y)));
        float p2 = fmaf(xx2, wxa.z, fmaf(xy2, wya.z, fmaf(xz2, wza.z, cva.z)));
        float p3 = fmaf(xx2, wxa.w, fmaf(xy2, wya.w, fmaf(xz2, wza.w, cva.w)));
        float p4 = fmaf(xx2, wxb.x, fmaf(xy2, wyb.x, fmaf(xz2, wzb.x, cvb.x)));
        float p5 = fmaf(xx2, wxb.y, fmaf(xy2, wyb.y, fmaf(xz2, wzb.y, cvb.y)));
        float p6 = fmaf(xx2, wxb.z, fmaf(xy2, wyb.z, fmaf(xz2, wzb.z, cvb.z)));
        float p7 = fmaf(xx2, wxb.w, fmaf(xy2, wyb.w, fmaf(xz2, wzb.w, cvb.w)));
        uint4 bv;
        bv.x = pack_bf16_trunc(tanh_s(p0), tanh_s(p1));
        bv.y = pack_bf16_trunc(tanh_s(p2), tanh_s(p3));
        bv.z = pack_bf16_trunc(tanh_s(p4), tanh_s(p5));
        bv.w = pack_bf16_trunc(tanh_s(p6), tanh_s(p7));
        bf16x8 bf = __builtin_bit_cast(bf16x8, bv);
#pragma unroll
        for (int I = 0; I < 4; I++) {
            bf16x8 af = __builtin_bit_cast(bf16x8, s.af[kk * 4 + I]);
            acc[I] = __builtin_amdgcn_mfma_f32_16x16x32_bf16(af, bf, acc[I], 0, 0, 0);
        }
    }

    // --- layer 3 (acc and c1 both carry SCALE) ---
    float pj0 = 0.f, pj1 = 0.f, pj2 = 0.f;
#pragma unroll
    for (int I = 0; I < 4; I++) {
        const float* wp = w2 + 3 * (I * 16 + g16 * 4);
        float4 wa = *(const float4*)(wp);
        float4 wb = *(const float4*)(wp + 4);
        float4 wc = *(const float4*)(wp + 8);
        float4 cv = *(const float4*)(c1 + I * 16 + g16 * 4);
        float th0 = tanh_s(acc[I][0] + cv.x);
        float th1 = tanh_s(acc[I][1] + cv.y);
        float th2 = tanh_s(acc[I][2] + cv.z);
        float th3 = tanh_s(acc[I][3] + cv.w);
        pj0 = fmaf(th0, wa.x, pj0); pj1 = fmaf(th0, wa.y, pj1); pj2 = fmaf(th0, wa.z, pj2);
        pj0 = fmaf(th1, wa.w, pj0); pj1 = fmaf(th1, wb.x, pj1); pj2 = fmaf(th1, wb.y, pj2);
        pj0 = fmaf(th2, wb.z, pj0); pj1 = fmaf(th2, wb.w, pj1); pj2 = fmaf(th2, wc.x, pj2);
        pj0 = fmaf(th3, wc.y, pj0); pj1 = fmaf(th3, wc.z, pj1); pj2 = fmaf(th3, wc.w, pj2);
    }
    pj0 += __shfl_xor(pj0, 16, 64); pj0 += __shfl_xor(pj0, 32, 64);
    pj1 += __shfl_xor(pj1, 16, 64); pj1 += __shfl_xor(pj1, 32, 64);
    pj2 += __shfl_xor(pj2, 16, 64); pj2 += __shfl_xor(pj2, 32, 64);
    float gv0 = pj0 + c2[0];
    float gv1 = pj1 + c2[1];
    float gv2 = pj2 + c2[2];

    // --- v = g @ (gt @ Ti), columns 1,2 only ---
    float M01 = fmaf(-sp, S.g00, cp * S.g01);
    float M11 = fmaf(-sp, S.g10, cp * S.g11);
    float M21 = fmaf(-sp, S.g20, cp * S.g21);
    float M02 = fmaf(S.g00, T02, fmaf(S.g01, T12, S.g02 * T22));
    float M12 = fmaf(S.g10, T02, fmaf(S.g11, T12, S.g12 * T22));
    float M22 = fmaf(S.g20, T02, fmaf(S.g21, T12, S.g22 * T22));
    float v1 = fmaf(gv0, M01, fmaf(gv1, M11, gv2 * M21));
    float v2 = fmaf(gv0, M02, fmaf(gv1, M12, gv2 * M22));

    float dB0 = s.dB.x, dB1 = s.dB.y;
    S.u_pre += fmaf(v1, dB1, -v2 * dB0);

    // --- dX3 / dX (bit-identical to R3) ---
    float s0d, c0d, s1d, c1d;
    __sincosf(dB0, &s0d, &c0d);
    __sincosf(dB1, &s1d, &c1d);
    float dx30 = fmaf(c0d, c1d, -1.0f);
    float dx31 = c0d * s1d;
    float dx32 = -s0d;

    float dX0 = fmaf(T00, dx30, fmaf(T01, dx31, T02 * dx32));
    float dX1 = fmaf(T10, dx30, fmaf(T11, dx31, T12 * dx32));
    float dX2 = fmaf(T20, dx30, T22 * dx32);

    S.xtx += dX0; S.xty += dX1; S.xtz += dX2;

    float xi0 = S.xix + fmaf(S.g00, dX0, fmaf(S.g01, dX1, S.g02 * dX2));
    float xi1 = S.xiy + fmaf(S.g10, dX0, fmaf(S.g11, dX1, S.g12 * dX2));
    float xi2 = S.xiz + fmaf(S.g20, dX0, fmaf(S.g21, dX1, S.g22 * dX2));

    float ri = sqrtf(fmaf(xi0, xi0, fmaf(xi1, xi1, xi2 * xi2)));
    bool outb = ri > RB;
    float n0 = xi0 / ri, n1 = xi1 / ri, n2 = xi2 / ri;
    float coef = 2.0f * (ri - RB);

    S.xix = outb ? fmaf(-coef, n0, xi0) : xi0;
    S.xiy = outb ? fmaf(-coef, n1, xi1) : xi1;
    S.xiz = outb ? fmaf(-coef, n2, xi2) : xi2;

    float mm0 = fmaf(n0, S.g00, fmaf(n1, S.g10, n2 * S.g20));
    float mm1 = fmaf(n0, S.g01, fmaf(n1, S.g11, n2 * S.g21));
    float mm2 = fmaf(n0, S.g02, fmaf(n1, S.g12, n2 * S.g22));
    float tn0 = 2.0f * n0, tn1 = 2.0f * n1, tn2 = 2.0f * n2;
    S.g00 = outb ? fmaf(-tn0, mm0, S.g00) : S.g00;
    S.g01 = outb ? fmaf(-tn0, mm1, S.g01) : S.g01;
    S.g02 = outb ? fmaf(-tn0, mm2, S.g02) : S.g02;
    S.g10 = outb ? fmaf(-tn1, mm0, S.g10) : S.g10;
    S.g11 = outb ? fmaf(-tn1, mm1, S.g11) : S.g11;
    S.g12 = outb ? fmaf(-tn1, mm2, S.g12) : S.g12;
    S.g20 = outb ? fmaf(-tn2, mm0, S.g20) : S.g20;
    S.g21 = outb ? fmaf(-tn2, mm1, S.g21) : S.g21;
    S.g22 = outb ? fmaf(-tn2, mm2, S.g22) : S.g22;
}

__global__ __launch_bounds__(256, 4) void sde_fast(
    const float* __restrict__ xt0,
    const float* __restrict__ dBt,
    const float* __restrict__ W0u, const float* __restrict__ b0u,
    const float* __restrict__ W1u, const float* __restrict__ b1u,
    const float* __restrict__ W2u, const float* __restrict__ b2u,
    const float* __restrict__ Wg0, const float* __restrict__ bg0,
    const float* __restrict__ Wg1, const float* __restrict__ bg1,
    const float* __restrict__ Wg2, const float* __restrict__ bg2,
    const uint4* __restrict__ wsA, const float* __restrict__ wsBias,
    float* __restrict__ out)
{
    const int tid  = threadIdx.x;
    const int lane = tid & 63;
    const int wv   = tid >> 6;
    const int g16  = (lane >> 4) & 3;
    const int l15  = lane & 15;
    const int p    = blockIdx.x * 64 + wv * 16 + l15;

    const float* c0s = wsBias;           // SCALE*bg0, N*64
    const float* c1s = wsBias + 8192;    // SCALE*bg1, N*64

    PState S;
    S.xtx = xt0[p * 3 + 0];
    S.xty = xt0[p * 3 + 1];
    S.xtz = xt0[p * 3 + 2];
    S.xix = S.xtx; S.xiy = S.xty; S.xiz = S.xtz;
    S.g00 = 1.f; S.g01 = 0.f; S.g02 = 0.f;
    S.g10 = 0.f; S.g11 = 1.f; S.g12 = 0.f;
    S.g20 = 0.f; S.g21 = 0.f; S.g22 = 1.f;

    // ---- u_pre0 (once; unscaled path, identical to R3) ----
    {
        f32x4 acc[4];
#pragma unroll
        for (int I = 0; I < 4; I++) acc[I] = (f32x4){0.f, 0.f, 0.f, 0.f};
        mlp_h2<0>(S.xtx, S.xty, S.xtz, W0u, b0u, nullptr, W1u, lane, acc);
        float pj = 0.f;
#pragma unroll
        for (int I = 0; I < 4; I++) {
            float4 wv2 = *(const float4*)(W2u + I * 16 + g16 * 4);
            float4 cv  = *(const float4*)(b1u + I * 16 + g16 * 4);
            pj = fmaf(tanh_fast(acc[I][0] + cv.x), wv2.x, pj);
            pj = fmaf(tanh_fast(acc[I][1] + cv.y), wv2.y, pj);
            pj = fmaf(tanh_fast(acc[I][2] + cv.z), wv2.z, pj);
            pj = fmaf(tanh_fast(acc[I][3] + cv.w), wv2.w, pj);
        }
        pj += __shfl_xor(pj, 16, 64);
        pj += __shfl_xor(pj, 32, 64);
        S.u_pre = pj + b2u[0];
    }

    // ---- time loop, unroll x2 with register prefetch ----
    StepBuf sA, sB;
    load_step(0, lane, p, wsA, dBt, sA);
#pragma unroll 1
    for (int t = 0; t < NSTEP; t += 2) {
        load_step(t + 1, lane, p, wsA, dBt, sB);
        do_step(t, lane, g16, sA, Wg0, c0s, c1s, Wg2, bg2, S);
        load_step((t + 2 < NSTEP) ? (t + 2) : (NSTEP - 1), lane, p, wsA, dBt, sA);
        do_step(t + 1, lane, g16, sB, Wg0, c0s, c1s, Wg2, bg2, S);
    }

    float u_rel = fmaf(S.xix, S.xix, fmaf(S.xiy, S.xiy, S.xiz * S.xiz));
    if (g16 == 0) {
        out[p] = S.u_pre;
        out[NB + p] = u_rel;
    }
}

// ------------------------- fallback (R3 kernel, unpacked) -------------------------
__global__ __launch_bounds__(256, 4) void sde_ref(
    const float* __restrict__ xt0,
    const float* __restrict__ dBt,
    const float* __restrict__ W0u, const float* __restrict__ b0u,
    const float* __restrict__ W1u, const float* __restrict__ b1u,
    const float* __restrict__ W2u, const float* __restrict__ b2u,
    const float* __restrict__ Wg0, const float* __restrict__ bg0,
    const float* __restrict__ Wg1, const float* __restrict__ bg1,
    const float* __restrict__ Wg2, const float* __restrict__ bg2,
    float* __restrict__ out)
{
    const int tid  = threadIdx.x;
    const int lane = tid & 63;
    const int wv   = tid >> 6;
    const int g16  = (lane >> 4) & 3;
    const int l15  = lane & 15;
    const int p    = blockIdx.x * 64 + wv * 16 + l15;

    float xtx = xt0[p * 3 + 0];
    float xty = xt0[p * 3 + 1];
    float xtz = xt0[p * 3 + 2];
    float xix = xtx, xiy = xty, xiz = xtz;
    float g00 = 1.f, g01 = 0.f, g02 = 0.f;
    float g10 = 0.f, g11 = 1.f, g12 = 0.f;
    float g20 = 0.f, g21 = 0.f, g22 = 1.f;

    float u_pre;
    {
        f32x4 acc[4];
#pragma unroll
        for (int I = 0; I < 4; I++) acc[I] = (f32x4){0.f, 0.f, 0.f, 0.f};
        mlp_h2<0>(xtx, xty, xtz, W0u, b0u, nullptr, W1u, lane, acc);
        float pj = 0.f;
#pragma unroll
        for (int I = 0; I < 4; I++) {
            float4 wv2 = *(const float4*)(W2u + I * 16 + g16 * 4);
            float4 cv  = *(const float4*)(b1u + I * 16 + g16 * 4);
            pj = fmaf(tanh_fast(acc[I][0] + cv.x), wv2.x, pj);
            pj = fmaf(tanh_fast(acc[I][1] + cv.y), wv2.y, pj);
            pj = fmaf(tanh_fast(acc[I][2] + cv.z), wv2.z, pj);
            pj = fmaf(tanh_fast(acc[I][3] + cv.w), wv2.w, pj);
        }
        pj += __shfl_xor(pj, 16, 64);
        pj += __shfl_xor(pj, 32, 64);
        u_pre = pj + b2u[0];
    }

#pragma unroll 1
    for (int t = 0; t < NSTEP; t++) {
        const float* w0 = Wg0 + (size_t)t * 3 * HD;
        const float* c0 = bg0 + (size_t)t * HD;
        const float* c1 = bg1 + (size_t)t * HD;
        const float* w2 = Wg2 + (size_t)t * HD * 3;
        const float* c2 = bg2 + (size_t)t * 3;

        float r = sqrtf(fmaf(xtx, xtx, fmaf(xty, xty, xtz * xtz)));
        float uu = xtz / r;
        uu = fminf(fmaxf(uu, -0.999999f), 0.999999f);
        float ca = sqrtf((1.0f - uu) * (1.0f + uu));
        float sa = -uu;
        float rho = sqrtf(fmaf(xtx, xtx, xty * xty));
        float cp = (rho > 0.0f) ? (xtx / rho) : 1.0f;
        float sp = (rho > 0.0f) ? (xty / rho) : 0.0f;
        float T00 = cp * ca, T01 = -sp, T02 = cp * sa;
        float T10 = sp * ca, T11 = cp,  T12 = sp * sa;
        float T20 = -sa,               T22 = ca;

        f32x4 acc[4];
#pragma unroll
        for (int I = 0; I < 4; I++) acc[I] = (f32x4){0.f, 0.f, 0.f, 0.f};
        mlp_h2<0>(xix, xiy, xiz, w0, c0, nullptr, Wg1 + (size_t)t * HD * HD, lane, acc);

        float pj0 = 0.f, pj1 = 0.f, pj2 = 0.f;
#pragma unroll
        for (int I = 0; I < 4; I++) {
            const float* wp = w2 + 3 * (I * 16 + g16 * 4);
            float4 wa = *(const float4*)(wp);
            float4 wb = *(const float4*)(wp + 4);
            float4 wc = *(const float4*)(wp + 8);
            float4 cv = *(const float4*)(c1 + I * 16 + g16 * 4);
            float th0 = tanh_fast(acc[I][0] + cv.x);
            float th1 = tanh_fast(acc[I][1] + cv.y);
            float th2 = tanh_fast(acc[I][2] + cv.z);
            float th3 = tanh_fast(acc[I][3] + cv.w);
            pj0 = fmaf(th0, wa.x, pj0); pj1 = fmaf(th0, wa.y, pj1); pj2 = fmaf(th0, wa.z, pj2);
            pj0 = fmaf(th1, wa.w, pj0); pj1 = fmaf(th1, wb.x, pj1); pj2 = fmaf(th1, wb.y, pj2);
            pj0 = fmaf(th2, wb.z, pj0); pj1 = fmaf(th2, wb.w, pj1); pj2 = fmaf(th2, wc.x, pj2);
            pj0 = fmaf(th3, wc.y, pj0); pj1 = fmaf(th3, wc.z, pj1); pj2 = fmaf(th3, wc.w, pj2);
        }
        pj0 += __shfl_xor(pj0, 16, 64); pj0 += __shfl_xor(pj0, 32, 64);
        pj1 += __shfl_xor(pj1, 16, 64); pj1 += __shfl_xor(pj1, 32, 64);
        pj2 += __shfl_xor(pj2, 16, 64); pj2 += __shfl_xor(pj2, 32, 64);
        float gv0 = pj0 + c2[0];
        float gv1 = pj1 + c2[1];
        float gv2 = pj2 + c2[2];

        float M01 = fmaf(-sp, g00, cp * g01);
        float M11 = fmaf(-sp, g10, cp * g11);
        float M21 = fmaf(-sp, g20, cp * g21);
        float M02 = fmaf(g00, T02, fmaf(g01, T12, g02 * T22));
        float M12 = fmaf(g10, T02, fmaf(g11, T12, g12 * T22));
        float M22 = fmaf(g20, T02, fmaf(g21, T12, g22 * T22));
        float v1 = fmaf(gv0, M01, fmaf(gv1, M11, gv2 * M21));
        float v2 = fmaf(gv0, M02, fmaf(gv1, M12, gv2 * M22));

        const float2 dB = *(const float2*)(dBt + ((size_t)t * NB + p) * 2);
        float dB0 = dB.x, dB1 = dB.y;
        u_pre += fmaf(v1, dB1, -v2 * dB0);

        float s0d, c0d, s1d, c1d;
        __sincosf(dB0, &s0d, &c0d);
        __sincosf(dB1, &s1d, &c1d);
        float dx30 = fmaf(c0d, c1d, -1.0f);
        float dx31 = c0d * s1d;
        float dx32 = -s0d;

        float dX0 = fmaf(T00, dx30, fmaf(T01, dx31, T02 * dx32));
        float dX1 = fmaf(T10, dx30, fmaf(T11, dx31, T12 * dx32));
        float dX2 = fmaf(T20, dx30, T22 * dx32);

        xtx += dX0; xty += dX1; xtz += dX2;

        float xi0 = xix + fmaf(g00, dX0, fmaf(g01, dX1, g02 * dX2));
        float xi1 = xiy + fmaf(g10, dX0, fmaf(g11, dX1, g12 * dX2));
        float xi2 = xiz + fmaf(g20, dX0, fmaf(g21, dX1, g22 * dX2));

        float ri = sqrtf(fmaf(xi0, xi0, fmaf(xi1, xi1, xi2 * xi2)));
        bool outb = ri > RB;
        float n0 = xi0 / ri, n1 = xi1 / ri, n2 = xi2 / ri;
        float coef = 2.0f * (ri - RB);

        xix = outb ? fmaf(-coef, n0, xi0) : xi0;
        xiy = outb ? fmaf(-coef, n1, xi1) : xi1;
        xiz = outb ? fmaf(-coef, n2, xi2) : xi2;

        float mm0 = fmaf(n0, g00, fmaf(n1, g10, n2 * g20));
        float mm1 = fmaf(n0, g01, fmaf(n1, g11, n2 * g21));
        float mm2 = fmaf(n0, g02, fmaf(n1, g12, n2 * g22));
        float tn0 = 2.0f * n0, tn1 = 2.0f * n1, tn2 = 2.0f * n2;
        g00 = outb ? fmaf(-tn0, mm0, g00) : g00;
        g01 = outb ? fmaf(-tn0, mm1, g01) : g01;
        g02 = outb ? fmaf(-tn0, mm2, g02) : g02;
        g10 = outb ? fmaf(-tn1, mm0, g10) : g10;
        g11 = outb ? fmaf(-tn1, mm1, g11) : g11;
        g12 = outb ? fmaf(-tn1, mm2, g12) : g12;
        g20 = outb ? fmaf(-tn2, mm0, g20) : g20;
        g21 = outb ? fmaf(-tn2, mm1, g21) : g21;
        g22 = outb ? fmaf(-tn2, mm2, g22) : g22;
    }

    float u_rel = fmaf(xix, xix, fmaf(xiy, xiy, xiz * xiz));
    if (g16 == 0) {
        out[p] = u_pre;
        out[NB + p] = u_rel;
    }
}

extern "C" void kernel_launch(void* const* d_in, const int* in_sizes, int n_in,
                              void* d_out, int out_size, void* d_ws, size_t ws_size,
                              hipStream_t stream) {
    const float* xt0 = (const float*)d_in[0];
    const float* dBt = (const float*)d_in[1];
    const float* W0u = (const float*)d_in[2];
    const float* b0u = (const float*)d_in[3];
    const float* W1u = (const float*)d_in[4];
    const float* b1u = (const float*)d_in[5];
    const float* W2u = (const float*)d_in[6];
    const float* b2u = (const float*)d_in[7];
    const float* Wg0 = (const float*)d_in[8];
    const float* bg0 = (const float*)d_in[9];
    const float* Wg1 = (const float*)d_in[10];
    const float* bg1 = (const float*)d_in[11];
    const float* Wg2 = (const float*)d_in[12];
    const float* bg2 = (const float*)d_in[13];
    float* out = (float*)d_out;

    const size_t szA    = (size_t)NSTEP * 2 * 4 * 64 * sizeof(uint4);   // 1 MB
    const size_t szBias = (size_t)2 * NSTEP * HD * sizeof(float);       // 64 KB
    dim3 grid(NB * 4 / 256), block(256);
    if (ws_size >= szA + szBias && d_ws != nullptr) {
        uint4* wsA    = (uint4*)d_ws;
        float* wsBias = (float*)((char*)d_ws + szA);
        hipLaunchKernelGGL(prep_kernel, dim3(256), dim3(256), 0, stream, Wg1, wsA);
        hipLaunchKernelGGL(prep_bias, dim3(32), dim3(256), 0, stream, bg0, bg1, wsBias);
        hipLaunchKernelGGL(sde_fast, grid, block, 0, stream,
                           xt0, dBt, W0u, b0u, W1u, b1u, W2u, b2u,
                           Wg0, bg0, Wg1, bg1, Wg2, bg2,
                           (const uint4*)wsA, (const float*)wsBias, out);
    } else {
        hipLaunchKernelGGL(sde_ref, grid, block, 0, stream,
                           xt0, dBt, W0u, b0u, W1u, b1u, W2u, b2u,
                           Wg0, bg0, Wg1, bg1, Wg2, bg2, out);
    }
}

// Round 5
// 745.682 us; speedup vs baseline: 1.0593x; 1.0593x over previous
//
#include <hip/hip_runtime.h>

#define NB 65536
#define NSTEP 128
#define HD 64
#define RB 1.05f

typedef __bf16 bf16x8 __attribute__((ext_vector_type(8)));
typedef float f32x4 __attribute__((ext_vector_type(4)));
typedef float v2f __attribute__((ext_vector_type(2)));
typedef unsigned int uint;
typedef unsigned short ushort;

// tanh(x) = 1 - 2/(1+e^{2x})
__device__ __forceinline__ float tanh_fast(float x) {
    float e2 = __expf(2.0f * x);
    return 1.0f - 2.0f * __builtin_amdgcn_rcpf(1.0f + e2);
}

// packed fma (v_pk_fma_f32): bit-identical to per-element fmaf
__device__ __forceinline__ v2f fma2(v2f a, v2f b, v2f c) {
    return __builtin_elementwise_fma(a, b, c);
}

// pack two f32 -> (bf16(b)<<16)|bf16(a), truncation, single v_perm_b32
__device__ __forceinline__ uint pack_bf16_trunc(float a, float b) {
    return __builtin_amdgcn_perm(__float_as_uint(b), __float_as_uint(a), 0x07060302u);
}

__device__ __forceinline__ ushort bf16_rne(float f) {
    uint u = __float_as_uint(f);
    u += 0x7fffu + ((u >> 16) & 1u);
    return (ushort)(u >> 16);
}

// Pack Wg1 (N x 64 x 64 f32) into bf16 A-fragments for mfma_f32_16x16x32_bf16.
// A = W1^T (A[row][k] = W1[k][row]).  lane holds A[row = I*16 + (lane&15)]
// [k = kk*32 + (lane>>4)*8 + e].  blob: wsA[((t*2+kk)*4+I)*64 + lane]
__global__ __launch_bounds__(256) void prep_kernel(const float* __restrict__ Wg1,
                                                   uint4* __restrict__ wsA) {
    int tid  = blockIdx.x * 256 + threadIdx.x;
    int lane = tid & 63;
    int I    = (tid >> 6) & 3;
    int kk   = (tid >> 8) & 1;
    int t    = tid >> 9;
    int row  = I * 16 + (lane & 15);
    int k0   = kk * 32 + ((lane >> 4) & 3) * 8;
    const float* src = Wg1 + ((size_t)t * HD + k0) * HD + row;
    ushort o[8];
#pragma unroll
    for (int e = 0; e < 8; e++) o[e] = bf16_rne(src[(size_t)e * HD]);
    uint4 v;
    v.x = (uint)o[0] | ((uint)o[1] << 16);
    v.y = (uint)o[2] | ((uint)o[3] << 16);
    v.z = (uint)o[4] | ((uint)o[5] << 16);
    v.w = (uint)o[6] | ((uint)o[7] << 16);
    wsA[tid] = v;
}

// --------- unpacked helper (u_pre0 prologue and the fallback kernel) ----------
__device__ __forceinline__ void mlp_h2_unpacked(float xx, float xy, float xz,
                                                const float* __restrict__ w0,
                                                const float* __restrict__ c0,
                                                const float* __restrict__ w1,
                                                int lane, f32x4* acc) {
    const int g16 = (lane >> 4) & 3;
    const int l15 = lane & 15;
#pragma unroll
    for (int kk = 0; kk < 2; kk++) {
        bf16x8 af[4];
#pragma unroll
        for (int I = 0; I < 4; I++) {
            uint pk[4];
#pragma unroll
            for (int ep = 0; ep < 4; ep++) {
                float f0 = w1[(kk * 32 + g16 * 8 + 2 * ep + 0) * HD + I * 16 + l15];
                float f1 = w1[(kk * 32 + g16 * 8 + 2 * ep + 1) * HD + I * 16 + l15];
                pk[ep] = (uint)bf16_rne(f0) | ((uint)bf16_rne(f1) << 16);
            }
            uint4 v; v.x = pk[0]; v.y = pk[1]; v.z = pk[2]; v.w = pk[3];
            af[I] = __builtin_bit_cast(bf16x8, v);
        }
        const float* wk = w0 + kk * 32 + g16 * 8;
        float4 wxa = *(const float4*)(wk);
        float4 wxb = *(const float4*)(wk + 4);
        float4 wya = *(const float4*)(wk + HD);
        float4 wyb = *(const float4*)(wk + HD + 4);
        float4 wza = *(const float4*)(wk + 2 * HD);
        float4 wzb = *(const float4*)(wk + 2 * HD + 4);
        const float* ck = c0 + kk * 32 + g16 * 8;
        float4 cva = *(const float4*)(ck);
        float4 cvb = *(const float4*)(ck + 4);
        float p0 = fmaf(xx, wxa.x, fmaf(xy, wya.x, fmaf(xz, wza.x, cva.x)));
        float p1 = fmaf(xx, wxa.y, fmaf(xy, wya.y, fmaf(xz, wza.y, cva.y)));
        float p2 = fmaf(xx, wxa.z, fmaf(xy, wya.z, fmaf(xz, wza.z, cva.z)));
        float p3 = fmaf(xx, wxa.w, fmaf(xy, wya.w, fmaf(xz, wza.w, cva.w)));
        float p4 = fmaf(xx, wxb.x, fmaf(xy, wyb.x, fmaf(xz, wzb.x, cvb.x)));
        float p5 = fmaf(xx, wxb.y, fmaf(xy, wyb.y, fmaf(xz, wzb.y, cvb.y)));
        float p6 = fmaf(xx, wxb.z, fmaf(xy, wyb.z, fmaf(xz, wzb.z, cvb.z)));
        float p7 = fmaf(xx, wxb.w, fmaf(xy, wyb.w, fmaf(xz, wzb.w, cvb.w)));
        uint4 bv;
        bv.x = pack_bf16_trunc(tanh_fast(p0), tanh_fast(p1));
        bv.y = pack_bf16_trunc(tanh_fast(p2), tanh_fast(p3));
        bv.z = pack_bf16_trunc(tanh_fast(p4), tanh_fast(p5));
        bv.w = pack_bf16_trunc(tanh_fast(p6), tanh_fast(p7));
        bf16x8 bf = __builtin_bit_cast(bf16x8, bv);
#pragma unroll
        for (int I = 0; I < 4; I++)
            acc[I] = __builtin_amdgcn_mfma_f32_16x16x32_bf16(af[I], bf, acc[I], 0, 0, 0);
    }
}

// ------------------------------ fast path ------------------------------
__global__ __launch_bounds__(256, 4) void sde_fast(
    const float* __restrict__ xt0,
    const float* __restrict__ dBt,
    const float* __restrict__ W0u, const float* __restrict__ b0u,
    const float* __restrict__ W1u, const float* __restrict__ b1u,
    const float* __restrict__ W2u, const float* __restrict__ b2u,
    const float* __restrict__ Wg0, const float* __restrict__ bg0,
    const float* __restrict__ Wg1, const float* __restrict__ bg1,
    const float* __restrict__ Wg2, const float* __restrict__ bg2,
    const uint4* __restrict__ wsA,
    float* __restrict__ out)
{
    const int tid  = threadIdx.x;
    const int lane = tid & 63;
    const int wv   = tid >> 6;
    const int g16  = (lane >> 4) & 3;
    const int l15  = lane & 15;
    const int p    = blockIdx.x * 64 + wv * 16 + l15;   // particle (4 lanes share)

    float xtx = xt0[p * 3 + 0];
    float xty = xt0[p * 3 + 1];
    float xtz = xt0[p * 3 + 2];
    float xix = xtx, xiy = xty, xiz = xtz;
    float g00 = 1.f, g01 = 0.f, g02 = 0.f;
    float g10 = 0.f, g11 = 1.f, g12 = 0.f;
    float g20 = 0.f, g21 = 0.f, g22 = 1.f;

    // ---- u_pre0 (once; scalar/unpacked path, identical to R3) ----
    float u_pre;
    {
        f32x4 acc[4];
#pragma unroll
        for (int I = 0; I < 4; I++) acc[I] = (f32x4){0.f, 0.f, 0.f, 0.f};
        mlp_h2_unpacked(xtx, xty, xtz, W0u, b0u, W1u, lane, acc);
        float pj = 0.f;
#pragma unroll
        for (int I = 0; I < 4; I++) {
            float4 wv2 = *(const float4*)(W2u + I * 16 + g16 * 4);
            float4 cv  = *(const float4*)(b1u + I * 16 + g16 * 4);
            pj = fmaf(tanh_fast(acc[I][0] + cv.x), wv2.x, pj);
            pj = fmaf(tanh_fast(acc[I][1] + cv.y), wv2.y, pj);
            pj = fmaf(tanh_fast(acc[I][2] + cv.z), wv2.z, pj);
            pj = fmaf(tanh_fast(acc[I][3] + cv.w), wv2.w, pj);
        }
        pj += __shfl_xor(pj, 16, 64);
        pj += __shfl_xor(pj, 32, 64);
        u_pre = pj + b2u[0];
    }

    // dB software pipeline: 1 step ahead (2 VGPRs, no struct)
    float2 dBcur = *(const float2*)(dBt + (size_t)p * 2);

#pragma unroll 1
    for (int t = 0; t < NSTEP; t++) {
        // --- issue this step's A-fragment loads first (L2-resident, wave-uniform) ---
        const uint4* bp = wsA + (size_t)t * 512 + lane;
        uint4 afr[8];
#pragma unroll
        for (int f = 0; f < 8; f++) afr[f] = bp[f * 64];
        // --- issue next step's dB load (HBM/L3 stream) ---
        int tn = (t + 1 < NSTEP) ? (t + 1) : (NSTEP - 1);
        float2 dBnext = *(const float2*)(dBt + ((size_t)tn * NB + p) * 2);

        const float* w0 = Wg0 + (size_t)t * 3 * HD;
        const float* c0 = bg0 + (size_t)t * HD;
        const float* c1 = bg1 + (size_t)t * HD;
        const float* w2 = Wg2 + (size_t)t * HD * 3;
        const float* c2 = bg2 + (size_t)t * 3;

        // --- geometry (bit-identical to R3) ---
        float r = sqrtf(fmaf(xtx, xtx, fmaf(xty, xty, xtz * xtz)));
        float uu = xtz / r;
        uu = fminf(fmaxf(uu, -0.999999f), 0.999999f);
        float ca = sqrtf((1.0f - uu) * (1.0f + uu));
        float sa = -uu;
        float rho = sqrtf(fmaf(xtx, xtx, xty * xty));
        float cp = (rho > 0.0f) ? (xtx / rho) : 1.0f;
        float sp = (rho > 0.0f) ? (xty / rho) : 0.0f;
        float T00 = cp * ca, T01 = -sp, T02 = cp * sa;
        float T10 = sp * ca, T11 = cp,  T12 = sp * sa;
        float T20 = -sa,               T22 = ca;   // T21 = 0

        // --- layer 1 (v_pk_fma_f32; element-wise identical to R3's fmaf chains) ---
        v2f xv = (v2f){xix, xix};
        v2f yv = (v2f){xiy, xiy};
        v2f zv = (v2f){xiz, xiz};
        f32x4 acc[4];
#pragma unroll
        for (int I = 0; I < 4; I++) acc[I] = (f32x4){0.f, 0.f, 0.f, 0.f};
#pragma unroll
        for (int kk = 0; kk < 2; kk++) {
            const float* wk = w0 + kk * 32 + g16 * 8;
            float4 wxa = *(const float4*)(wk);
            float4 wxb = *(const float4*)(wk + 4);
            float4 wya = *(const float4*)(wk + HD);
            float4 wyb = *(const float4*)(wk + HD + 4);
            float4 wza = *(const float4*)(wk + 2 * HD);
            float4 wzb = *(const float4*)(wk + 2 * HD + 4);
            const float* ck = c0 + kk * 32 + g16 * 8;
            float4 cva = *(const float4*)(ck);
            float4 cvb = *(const float4*)(ck + 4);
            v2f p01 = fma2(xv, (v2f){wxa.x, wxa.y},
                      fma2(yv, (v2f){wya.x, wya.y},
                      fma2(zv, (v2f){wza.x, wza.y}, (v2f){cva.x, cva.y})));
            v2f p23 = fma2(xv, (v2f){wxa.z, wxa.w},
                      fma2(yv, (v2f){wya.z, wya.w},
                      fma2(zv, (v2f){wza.z, wza.w}, (v2f){cva.z, cva.w})));
            v2f p45 = fma2(xv, (v2f){wxb.x, wxb.y},
                      fma2(yv, (v2f){wyb.x, wyb.y},
                      fma2(zv, (v2f){wzb.x, wzb.y}, (v2f){cvb.x, cvb.y})));
            v2f p67 = fma2(xv, (v2f){wxb.z, wxb.w},
                      fma2(yv, (v2f){wyb.z, wyb.w},
                      fma2(zv, (v2f){wzb.z, wzb.w}, (v2f){cvb.z, cvb.w})));
            uint4 bv;
            bv.x = pack_bf16_trunc(tanh_fast(p01.x), tanh_fast(p01.y));
            bv.y = pack_bf16_trunc(tanh_fast(p23.x), tanh_fast(p23.y));
            bv.z = pack_bf16_trunc(tanh_fast(p45.x), tanh_fast(p45.y));
            bv.w = pack_bf16_trunc(tanh_fast(p67.x), tanh_fast(p67.y));
            bf16x8 bf = __builtin_bit_cast(bf16x8, bv);
#pragma unroll
            for (int I = 0; I < 4; I++) {
                bf16x8 af = __builtin_bit_cast(bf16x8, afr[kk * 4 + I]);
                acc[I] = __builtin_amdgcn_mfma_f32_16x16x32_bf16(af, bf, acc[I], 0, 0, 0);
            }
        }

        // --- layer 3 (pk-fma on the (c0,c1) weight pairs; identical arithmetic) ---
        v2f pj01 = (v2f){0.f, 0.f};
        float pj2 = 0.f;
#pragma unroll
        for (int I = 0; I < 4; I++) {
            const float* wp = w2 + 3 * (I * 16 + g16 * 4);
            float4 wa = *(const float4*)(wp);
            float4 wb = *(const float4*)(wp + 4);
            float4 wc = *(const float4*)(wp + 8);
            float4 cv = *(const float4*)(c1 + I * 16 + g16 * 4);
            float th0 = tanh_fast(acc[I][0] + cv.x);
            float th1 = tanh_fast(acc[I][1] + cv.y);
            float th2 = tanh_fast(acc[I][2] + cv.z);
            float th3 = tanh_fast(acc[I][3] + cv.w);
            pj01 = fma2((v2f){th0, th0}, (v2f){wa.x, wa.y}, pj01); pj2 = fmaf(th0, wa.z, pj2);
            pj01 = fma2((v2f){th1, th1}, (v2f){wa.w, wb.x}, pj01); pj2 = fmaf(th1, wb.y, pj2);
            pj01 = fma2((v2f){th2, th2}, (v2f){wb.z, wb.w}, pj01); pj2 = fmaf(th2, wc.x, pj2);
            pj01 = fma2((v2f){th3, th3}, (v2f){wc.y, wc.z}, pj01); pj2 = fmaf(th3, wc.w, pj2);
        }
        float pj0 = pj01.x, pj1 = pj01.y;
        pj0 += __shfl_xor(pj0, 16, 64); pj0 += __shfl_xor(pj0, 32, 64);
        pj1 += __shfl_xor(pj1, 16, 64); pj1 += __shfl_xor(pj1, 32, 64);
        pj2 += __shfl_xor(pj2, 16, 64); pj2 += __shfl_xor(pj2, 32, 64);
        float gv0 = pj0 + c2[0];
        float gv1 = pj1 + c2[1];
        float gv2 = pj2 + c2[2];

        // --- v = g @ (gt @ Ti), columns 1,2 only ---
        float M01 = fmaf(-sp, g00, cp * g01);
        float M11 = fmaf(-sp, g10, cp * g11);
        float M21 = fmaf(-sp, g20, cp * g21);
        float M02 = fmaf(g00, T02, fmaf(g01, T12, g02 * T22));
        float M12 = fmaf(g10, T02, fmaf(g11, T12, g12 * T22));
        float M22 = fmaf(g20, T02, fmaf(g21, T12, g22 * T22));
        float v1 = fmaf(gv0, M01, fmaf(gv1, M11, gv2 * M21));
        float v2 = fmaf(gv0, M02, fmaf(gv1, M12, gv2 * M22));

        float dB0 = dBcur.x, dB1 = dBcur.y;
        u_pre += fmaf(v1, dB1, -v2 * dB0);

        // --- dX3 / dX (bit-identical to R3) ---
        float s0d, c0d, s1d, c1d;
        __sincosf(dB0, &s0d, &c0d);
        __sincosf(dB1, &s1d, &c1d);
        float dx30 = fmaf(c0d, c1d, -1.0f);
        float dx31 = c0d * s1d;
        float dx32 = -s0d;

        float dX0 = fmaf(T00, dx30, fmaf(T01, dx31, T02 * dx32));
        float dX1 = fmaf(T10, dx30, fmaf(T11, dx31, T12 * dx32));
        float dX2 = fmaf(T20, dx30, T22 * dx32);

        xtx += dX0; xty += dX1; xtz += dX2;

        float xi0 = xix + fmaf(g00, dX0, fmaf(g01, dX1, g02 * dX2));
        float xi1 = xiy + fmaf(g10, dX0, fmaf(g11, dX1, g12 * dX2));
        float xi2 = xiz + fmaf(g20, dX0, fmaf(g21, dX1, g22 * dX2));

        float ri = sqrtf(fmaf(xi0, xi0, fmaf(xi1, xi1, xi2 * xi2)));
        bool outb = ri > RB;
        float n0 = xi0 / ri, n1 = xi1 / ri, n2 = xi2 / ri;
        float coef = 2.0f * (ri - RB);

        xix = outb ? fmaf(-coef, n0, xi0) : xi0;
        xiy = outb ? fmaf(-coef, n1, xi1) : xi1;
        xiz = outb ? fmaf(-coef, n2, xi2) : xi2;

        float mm0 = fmaf(n0, g00, fmaf(n1, g10, n2 * g20));
        float mm1 = fmaf(n0, g01, fmaf(n1, g11, n2 * g21));
        float mm2 = fmaf(n0, g02, fmaf(n1, g12, n2 * g22));
        float tn0 = 2.0f * n0, tn1 = 2.0f * n1, tn2 = 2.0f * n2;
        g00 = outb ? fmaf(-tn0, mm0, g00) : g00;
        g01 = outb ? fmaf(-tn0, mm1, g01) : g01;
        g02 = outb ? fmaf(-tn0, mm2, g02) : g02;
        g10 = outb ? fmaf(-tn1, mm0, g10) : g10;
        g11 = outb ? fmaf(-tn1, mm1, g11) : g11;
        g12 = outb ? fmaf(-tn1, mm2, g12) : g12;
        g20 = outb ? fmaf(-tn2, mm0, g20) : g20;
        g21 = outb ? fmaf(-tn2, mm1, g21) : g21;
        g22 = outb ? fmaf(-tn2, mm2, g22) : g22;

        dBcur = dBnext;
    }

    float u_rel = fmaf(xix, xix, fmaf(xiy, xiy, xiz * xiz));
    if (g16 == 0) {
        out[p] = u_pre;
        out[NB + p] = u_rel;
    }
}

// ------------------- fallback (R3 kernel, unpacked weights) -------------------
__global__ __launch_bounds__(256, 4) void sde_ref(
    const float* __restrict__ xt0,
    const float* __restrict__ dBt,
    const float* __restrict__ W0u, const float* __restrict__ b0u,
    const float* __restrict__ W1u, const float* __restrict__ b1u,
    const float* __restrict__ W2u, const float* __restrict__ b2u,
    const float* __restrict__ Wg0, const float* __restrict__ bg0,
    const float* __restrict__ Wg1, const float* __restrict__ bg1,
    const float* __restrict__ Wg2, const float* __restrict__ bg2,
    float* __restrict__ out)
{
    const int tid  = threadIdx.x;
    const int lane = tid & 63;
    const int wv   = tid >> 6;
    const int g16  = (lane >> 4) & 3;
    const int l15  = lane & 15;
    const int p    = blockIdx.x * 64 + wv * 16 + l15;

    float xtx = xt0[p * 3 + 0];
    float xty = xt0[p * 3 + 1];
    float xtz = xt0[p * 3 + 2];
    float xix = xtx, xiy = xty, xiz = xtz;
    float g00 = 1.f, g01 = 0.f, g02 = 0.f;
    float g10 = 0.f, g11 = 1.f, g12 = 0.f;
    float g20 = 0.f, g21 = 0.f, g22 = 1.f;

    float u_pre;
    {
        f32x4 acc[4];
#pragma unroll
        for (int I = 0; I < 4; I++) acc[I] = (f32x4){0.f, 0.f, 0.f, 0.f};
        mlp_h2_unpacked(xtx, xty, xtz, W0u, b0u, W1u, lane, acc);
        float pj = 0.f;
#pragma unroll
        for (int I = 0; I < 4; I++) {
            float4 wv2 = *(const float4*)(W2u + I * 16 + g16 * 4);
            float4 cv  = *(const float4*)(b1u + I * 16 + g16 * 4);
            pj = fmaf(tanh_fast(acc[I][0] + cv.x), wv2.x, pj);
            pj = fmaf(tanh_fast(acc[I][1] + cv.y), wv2.y, pj);
            pj = fmaf(tanh_fast(acc[I][2] + cv.z), wv2.z, pj);
            pj = fmaf(tanh_fast(acc[I][3] + cv.w), wv2.w, pj);
        }
        pj += __shfl_xor(pj, 16, 64);
        pj += __shfl_xor(pj, 32, 64);
        u_pre = pj + b2u[0];
    }

#pragma unroll 1
    for (int t = 0; t < NSTEP; t++) {
        const float* w0 = Wg0 + (size_t)t * 3 * HD;
        const float* c0 = bg0 + (size_t)t * HD;
        const float* c1 = bg1 + (size_t)t * HD;
        const float* w2 = Wg2 + (size_t)t * HD * 3;
        const float* c2 = bg2 + (size_t)t * 3;

        float r = sqrtf(fmaf(xtx, xtx, fmaf(xty, xty, xtz * xtz)));
        float uu = xtz / r;
        uu = fminf(fmaxf(uu, -0.999999f), 0.999999f);
        float ca = sqrtf((1.0f - uu) * (1.0f + uu));
        float sa = -uu;
        float rho = sqrtf(fmaf(xtx, xtx, xty * xty));
        float cp = (rho > 0.0f) ? (xtx / rho) : 1.0f;
        float sp = (rho > 0.0f) ? (xty / rho) : 0.0f;
        float T00 = cp * ca, T01 = -sp, T02 = cp * sa;
        float T10 = sp * ca, T11 = cp,  T12 = sp * sa;
        float T20 = -sa,               T22 = ca;

        f32x4 acc[4];
#pragma unroll
        for (int I = 0; I < 4; I++) acc[I] = (f32x4){0.f, 0.f, 0.f, 0.f};
        mlp_h2_unpacked(xix, xiy, xiz, w0, c0, Wg1 + (size_t)t * HD * HD, lane, acc);

        float pj0 = 0.f, pj1 = 0.f, pj2 = 0.f;
#pragma unroll
        for (int I = 0; I < 4; I++) {
            const float* wp = w2 + 3 * (I * 16 + g16 * 4);
            float4 wa = *(const float4*)(wp);
            float4 wb = *(const float4*)(wp + 4);
            float4 wc = *(const float4*)(wp + 8);
            float4 cv = *(const float4*)(c1 + I * 16 + g16 * 4);
            float th0 = tanh_fast(acc[I][0] + cv.x);
            float th1 = tanh_fast(acc[I][1] + cv.y);
            float th2 = tanh_fast(acc[I][2] + cv.z);
            float th3 = tanh_fast(acc[I][3] + cv.w);
            pj0 = fmaf(th0, wa.x, pj0); pj1 = fmaf(th0, wa.y, pj1); pj2 = fmaf(th0, wa.z, pj2);
            pj0 = fmaf(th1, wa.w, pj0); pj1 = fmaf(th1, wb.x, pj1); pj2 = fmaf(th1, wb.y, pj2);
            pj0 = fmaf(th2, wb.z, pj0); pj1 = fmaf(th2, wb.w, pj1); pj2 = fmaf(th2, wc.x, pj2);
            pj0 = fmaf(th3, wc.y, pj0); pj1 = fmaf(th3, wc.z, pj1); pj2 = fmaf(th3, wc.w, pj2);
        }
        pj0 += __shfl_xor(pj0, 16, 64); pj0 += __shfl_xor(pj0, 32, 64);
        pj1 += __shfl_xor(pj1, 16, 64); pj1 += __shfl_xor(pj1, 32, 64);
        pj2 += __shfl_xor(pj2, 16, 64); pj2 += __shfl_xor(pj2, 32, 64);
        float gv0 = pj0 + c2[0];
        float gv1 = pj1 + c2[1];
        float gv2 = pj2 + c2[2];

        float M01 = fmaf(-sp, g00, cp * g01);
        float M11 = fmaf(-sp, g10, cp * g11);
        float M21 = fmaf(-sp, g20, cp * g21);
        float M02 = fmaf(g00, T02, fmaf(g01, T12, g02 * T22));
        float M12 = fmaf(g10, T02, fmaf(g11, T12, g12 * T22));
        float M22 = fmaf(g20, T02, fmaf(g21, T12, g22 * T22));
        float v1 = fmaf(gv0, M01, fmaf(gv1, M11, gv2 * M21));
        float v2 = fmaf(gv0, M02, fmaf(gv1, M12, gv2 * M22));

        const float2 dB = *(const float2*)(dBt + ((size_t)t * NB + p) * 2);
        float dB0 = dB.x, dB1 = dB.y;
        u_pre += fmaf(v1, dB1, -v2 * dB0);

        float s0d, c0d, s1d, c1d;
        __sincosf(dB0, &s0d, &c0d);
        __sincosf(dB1, &s1d, &c1d);
        float dx30 = fmaf(c0d, c1d, -1.0f);
        float dx31 = c0d * s1d;
        float dx32 = -s0d;

        float dX0 = fmaf(T00, dx30, fmaf(T01, dx31, T02 * dx32));
        float dX1 = fmaf(T10, dx30, fmaf(T11, dx31, T12 * dx32));
        float dX2 = fmaf(T20, dx30, T22 * dx32);

        xtx += dX0; xty += dX1; xtz += dX2;

        float xi0 = xix + fmaf(g00, dX0, fmaf(g01, dX1, g02 * dX2));
        float xi1 = xiy + fmaf(g10, dX0, fmaf(g11, dX1, g12 * dX2));
        float xi2 = xiz + fmaf(g20, dX0, fmaf(g21, dX1, g22 * dX2));

        float ri = sqrtf(fmaf(xi0, xi0, fmaf(xi1, xi1, xi2 * xi2)));
        bool outb = ri > RB;
        float n0 = xi0 / ri, n1 = xi1 / ri, n2 = xi2 / ri;
        float coef = 2.0f * (ri - RB);

        xix = outb ? fmaf(-coef, n0, xi0) : xi0;
        xiy = outb ? fmaf(-coef, n1, xi1) : xi1;
        xiz = outb ? fmaf(-coef, n2, xi2) : xi2;

        float mm0 = fmaf(n0, g00, fmaf(n1, g10, n2 * g20));
        float mm1 = fmaf(n0, g01, fmaf(n1, g11, n2 * g21));
        float mm2 = fmaf(n0, g02, fmaf(n1, g12, n2 * g22));
        float tn0 = 2.0f * n0, tn1 = 2.0f * n1, tn2 = 2.0f * n2;
        g00 = outb ? fmaf(-tn0, mm0, g00) : g00;
        g01 = outb ? fmaf(-tn0, mm1, g01) : g01;
        g02 = outb ? fmaf(-tn0, mm2, g02) : g02;
        g10 = outb ? fmaf(-tn1, mm0, g10) : g10;
        g11 = outb ? fmaf(-tn1, mm1, g11) : g11;
        g12 = outb ? fmaf(-tn1, mm2, g12) : g12;
        g20 = outb ? fmaf(-tn2, mm0, g20) : g20;
        g21 = outb ? fmaf(-tn2, mm1, g21) : g21;
        g22 = outb ? fmaf(-tn2, mm2, g22) : g22;
    }

    float u_rel = fmaf(xix, xix, fmaf(xiy, xiy, xiz * xiz));
    if (g16 == 0) {
        out[p] = u_pre;
        out[NB + p] = u_rel;
    }
}

extern "C" void kernel_launch(void* const* d_in, const int* in_sizes, int n_in,
                              void* d_out, int out_size, void* d_ws, size_t ws_size,
                              hipStream_t stream) {
    const float* xt0 = (const float*)d_in[0];
    const float* dBt = (const float*)d_in[1];
    const float* W0u = (const float*)d_in[2];
    const float* b0u = (const float*)d_in[3];
    const float* W1u = (const float*)d_in[4];
    const float* b1u = (const float*)d_in[5];
    const float* W2u = (const float*)d_in[6];
    const float* b2u = (const float*)d_in[7];
    const float* Wg0 = (const float*)d_in[8];
    const float* bg0 = (const float*)d_in[9];
    const float* Wg1 = (const float*)d_in[10];
    const float* bg1 = (const float*)d_in[11];
    const float* Wg2 = (const float*)d_in[12];
    const float* bg2 = (const float*)d_in[13];
    float* out = (float*)d_out;

    const size_t needed = (size_t)NSTEP * 2 * 4 * 64 * sizeof(uint4);  // 1 MB
    dim3 grid(NB * 4 / 256), block(256);
    if (ws_size >= needed && d_ws != nullptr) {
        hipLaunchKernelGGL(prep_kernel, dim3(256), dim3(256), 0, stream, Wg1, (uint4*)d_ws);
        hipLaunchKernelGGL(sde_fast, grid, block, 0, stream,
                           xt0, dBt, W0u, b0u, W1u, b1u, W2u, b2u,
                           Wg0, bg0, Wg1, bg1, Wg2, bg2, (const uint4*)d_ws, out);
    } else {
        hipLaunchKernelGGL(sde_ref, grid, block, 0, stream,
                           xt0, dBt, W0u, b0u, W1u, b1u, W2u, b2u,
                           Wg0, bg0, Wg1, bg1, Wg2, bg2, out);
    }
}

// Round 6
// 646.654 us; speedup vs baseline: 1.2215x; 1.1531x over previous
//
#include <hip/hip_runtime.h>

#define NB 65536
#define NSTEP 128
#define HD 64
#define RB 1.05f

typedef __bf16 bf16x8 __attribute__((ext_vector_type(8)));
typedef float f32x4 __attribute__((ext_vector_type(4)));
typedef unsigned int uint;
typedef unsigned short ushort;

// tanh(x) = 1 - 2/(1+e^{2x})
__device__ __forceinline__ float tanh_fast(float x) {
    float e2 = __expf(2.0f * x);
    return 1.0f - 2.0f * __builtin_amdgcn_rcpf(1.0f + e2);
}

// paired tanh: one v_rcp serves two tanh.  1/(1+ea) = rcp((1+ea)(1+eb))*(1+eb).
// Overflow of the product degrades gracefully to the correct +/-1 saturation.
__device__ __forceinline__ void tanh2(float xa, float xb, float& ta, float& tb) {
    float ea = __expf(2.0f * xa);
    float eb = __expf(2.0f * xb);
    float a1 = 1.0f + ea;
    float b1 = 1.0f + eb;
    float rp = __builtin_amdgcn_rcpf(a1 * b1);
    ta = fmaf(-2.0f * b1, rp, 1.0f);
    tb = fmaf(-2.0f * a1, rp, 1.0f);
}

// small-angle sincos (|x| <= ~0.55): deg-5 sin (err ~x^7/5040), deg-6 cos (err ~x^8/40320)
__device__ __forceinline__ void sincos_small(float x, float& s, float& c) {
    float x2 = x * x;
    s = fmaf(x2, fmaf(x2, 8.3333333e-3f, -0.16666667f), 1.0f) * x;
    c = fmaf(x2, fmaf(x2, fmaf(x2, -1.3888889e-3f, 4.1666668e-2f), -0.5f), 1.0f);
}

// pack two f32 -> (bf16(b)<<16)|bf16(a), truncation, single v_perm_b32
__device__ __forceinline__ uint pack_bf16_trunc(float a, float b) {
    return __builtin_amdgcn_perm(__float_as_uint(b), __float_as_uint(a), 0x07060302u);
}

__device__ __forceinline__ ushort bf16_rne(float f) {
    uint u = __float_as_uint(f);
    u += 0x7fffu + ((u >> 16) & 1u);
    return (ushort)(u >> 16);
}

// Pack Wg1 (N x 64 x 64 f32) into bf16 A-fragments for mfma_f32_16x16x32_bf16.
// A = W1^T (A[row][k] = W1[k][row]).  lane holds A[row = I*16 + (lane&15)]
// [k = kk*32 + (lane>>4)*8 + e].  blob: wsA[((t*2+kk)*4+I)*64 + lane]
__global__ __launch_bounds__(256) void prep_kernel(const float* __restrict__ Wg1,
                                                   uint4* __restrict__ wsA) {
    int tid  = blockIdx.x * 256 + threadIdx.x;
    int lane = tid & 63;
    int I    = (tid >> 6) & 3;
    int kk   = (tid >> 8) & 1;
    int t    = tid >> 9;
    int row  = I * 16 + (lane & 15);
    int k0   = kk * 32 + ((lane >> 4) & 3) * 8;
    const float* src = Wg1 + ((size_t)t * HD + k0) * HD + row;
    ushort o[8];
#pragma unroll
    for (int e = 0; e < 8; e++) o[e] = bf16_rne(src[(size_t)e * HD]);
    uint4 v;
    v.x = (uint)o[0] | ((uint)o[1] << 16);
    v.y = (uint)o[2] | ((uint)o[3] << 16);
    v.z = (uint)o[4] | ((uint)o[5] << 16);
    v.w = (uint)o[6] | ((uint)o[7] << 16);
    wsA[tid] = v;
}

// --------- unpacked helper (u_pre0 prologue and the fallback kernel) ----------
__device__ __forceinline__ void mlp_h2_unpacked(float xx, float xy, float xz,
                                                const float* __restrict__ w0,
                                                const float* __restrict__ c0,
                                                const float* __restrict__ w1,
                                                int lane, f32x4* acc) {
    const int g16 = (lane >> 4) & 3;
    const int l15 = lane & 15;
#pragma unroll
    for (int kk = 0; kk < 2; kk++) {
        bf16x8 af[4];
#pragma unroll
        for (int I = 0; I < 4; I++) {
            uint pk[4];
#pragma unroll
            for (int ep = 0; ep < 4; ep++) {
                float f0 = w1[(kk * 32 + g16 * 8 + 2 * ep + 0) * HD + I * 16 + l15];
                float f1 = w1[(kk * 32 + g16 * 8 + 2 * ep + 1) * HD + I * 16 + l15];
                pk[ep] = (uint)bf16_rne(f0) | ((uint)bf16_rne(f1) << 16);
            }
            uint4 v; v.x = pk[0]; v.y = pk[1]; v.z = pk[2]; v.w = pk[3];
            af[I] = __builtin_bit_cast(bf16x8, v);
        }
        const float* wk = w0 + kk * 32 + g16 * 8;
        float4 wxa = *(const float4*)(wk);
        float4 wxb = *(const float4*)(wk + 4);
        float4 wya = *(const float4*)(wk + HD);
        float4 wyb = *(const float4*)(wk + HD + 4);
        float4 wza = *(const float4*)(wk + 2 * HD);
        float4 wzb = *(const float4*)(wk + 2 * HD + 4);
        const float* ck = c0 + kk * 32 + g16 * 8;
        float4 cva = *(const float4*)(ck);
        float4 cvb = *(const float4*)(ck + 4);
        float p0 = fmaf(xx, wxa.x, fmaf(xy, wya.x, fmaf(xz, wza.x, cva.x)));
        float p1 = fmaf(xx, wxa.y, fmaf(xy, wya.y, fmaf(xz, wza.y, cva.y)));
        float p2 = fmaf(xx, wxa.z, fmaf(xy, wya.z, fmaf(xz, wza.z, cva.z)));
        float p3 = fmaf(xx, wxa.w, fmaf(xy, wya.w, fmaf(xz, wza.w, cva.w)));
        float p4 = fmaf(xx, wxb.x, fmaf(xy, wyb.x, fmaf(xz, wzb.x, cvb.x)));
        float p5 = fmaf(xx, wxb.y, fmaf(xy, wyb.y, fmaf(xz, wzb.y, cvb.y)));
        float p6 = fmaf(xx, wxb.z, fmaf(xy, wyb.z, fmaf(xz, wzb.z, cvb.z)));
        float p7 = fmaf(xx, wxb.w, fmaf(xy, wyb.w, fmaf(xz, wzb.w, cvb.w)));
        uint4 bv;
        bv.x = pack_bf16_trunc(tanh_fast(p0), tanh_fast(p1));
        bv.y = pack_bf16_trunc(tanh_fast(p2), tanh_fast(p3));
        bv.z = pack_bf16_trunc(tanh_fast(p4), tanh_fast(p5));
        bv.w = pack_bf16_trunc(tanh_fast(p6), tanh_fast(p7));
        bf16x8 bf = __builtin_bit_cast(bf16x8, bv);
#pragma unroll
        for (int I = 0; I < 4; I++)
            acc[I] = __builtin_amdgcn_mfma_f32_16x16x32_bf16(af[I], bf, acc[I], 0, 0, 0);
    }
}

// ------------------------------ fast path (R3 structure + trans cuts) ------------------------------
__global__ __launch_bounds__(256, 4) void sde_fast(
    const float* __restrict__ xt0,
    const float* __restrict__ dBt,
    const float* __restrict__ W0u, const float* __restrict__ b0u,
    const float* __restrict__ W1u, const float* __restrict__ b1u,
    const float* __restrict__ W2u, const float* __restrict__ b2u,
    const float* __restrict__ Wg0, const float* __restrict__ bg0,
    const float* __restrict__ Wg1, const float* __restrict__ bg1,
    const float* __restrict__ Wg2, const float* __restrict__ bg2,
    const uint4* __restrict__ wsA,
    float* __restrict__ out)
{
    const int tid  = threadIdx.x;
    const int lane = tid & 63;
    const int wv   = tid >> 6;
    const int g16  = (lane >> 4) & 3;
    const int l15  = lane & 15;
    const int p    = blockIdx.x * 64 + wv * 16 + l15;   // particle (4 lanes share)

    float xtx = xt0[p * 3 + 0];
    float xty = xt0[p * 3 + 1];
    float xtz = xt0[p * 3 + 2];
    float xix = xtx, xiy = xty, xiz = xtz;
    float g00 = 1.f, g01 = 0.f, g02 = 0.f;
    float g10 = 0.f, g11 = 1.f, g12 = 0.f;
    float g20 = 0.f, g21 = 0.f, g22 = 1.f;

    // ---- u_pre0 (once; unpacked path) ----
    float u_pre;
    {
        f32x4 acc[4];
#pragma unroll
        for (int I = 0; I < 4; I++) acc[I] = (f32x4){0.f, 0.f, 0.f, 0.f};
        mlp_h2_unpacked(xtx, xty, xtz, W0u, b0u, W1u, lane, acc);
        float pj = 0.f;
#pragma unroll
        for (int I = 0; I < 4; I++) {
            float4 wv2 = *(const float4*)(W2u + I * 16 + g16 * 4);
            float4 cv  = *(const float4*)(b1u + I * 16 + g16 * 4);
            pj = fmaf(tanh_fast(acc[I][0] + cv.x), wv2.x, pj);
            pj = fmaf(tanh_fast(acc[I][1] + cv.y), wv2.y, pj);
            pj = fmaf(tanh_fast(acc[I][2] + cv.z), wv2.z, pj);
            pj = fmaf(tanh_fast(acc[I][3] + cv.w), wv2.w, pj);
        }
        pj += __shfl_xor(pj, 16, 64);
        pj += __shfl_xor(pj, 32, 64);
        u_pre = pj + b2u[0];
    }

#pragma unroll 1
    for (int t = 0; t < NSTEP; t++) {
        const float* w0 = Wg0 + (size_t)t * 3 * HD;
        const float* c0 = bg0 + (size_t)t * HD;
        const float* c1 = bg1 + (size_t)t * HD;
        const float* w2 = Wg2 + (size_t)t * HD * 3;
        const float* c2 = bg2 + (size_t)t * 3;

        // --- geometry via rsqrt (no divisions) ---
        float d  = fmaf(xtx, xtx, fmaf(xty, xty, xtz * xtz));
        float rs = __builtin_amdgcn_rsqf(d);                 // 1/r
        float uu = xtz * rs;
        uu = fminf(fmaxf(uu, -0.999999f), 0.999999f);
        float ca = sqrtf((1.0f - uu) * (1.0f + uu));
        float sa = -uu;
        float rho2 = fmaf(xtx, xtx, xty * xty);
        bool hasrho = rho2 > 0.0f;
        float rr = __builtin_amdgcn_rsqf(rho2);              // 1/rho (inf if rho2==0)
        float cp = hasrho ? (xtx * rr) : 1.0f;
        float sp = hasrho ? (xty * rr) : 0.0f;
        float T00 = cp * ca, T01 = -sp, T02 = cp * sa;
        float T10 = sp * ca, T11 = cp,  T12 = sp * sa;
        float T20 = -sa,               T22 = ca;   // T21 = 0

        // --- layer 1 + MFMA (A-frags loaded at use site, as in R3) ---
        const uint4* apk = wsA + (size_t)t * 512;
        f32x4 acc[4];
#pragma unroll
        for (int I = 0; I < 4; I++) acc[I] = (f32x4){0.f, 0.f, 0.f, 0.f};
#pragma unroll
        for (int kk = 0; kk < 2; kk++) {
            bf16x8 af[4];
            const uint4* bp = apk + kk * 256 + lane;
#pragma unroll
            for (int I = 0; I < 4; I++) af[I] = __builtin_bit_cast(bf16x8, bp[I * 64]);

            const float* wk = w0 + kk * 32 + g16 * 8;
            float4 wxa = *(const float4*)(wk);
            float4 wxb = *(const float4*)(wk + 4);
            float4 wya = *(const float4*)(wk + HD);
            float4 wyb = *(const float4*)(wk + HD + 4);
            float4 wza = *(const float4*)(wk + 2 * HD);
            float4 wzb = *(const float4*)(wk + 2 * HD + 4);
            const float* ck = c0 + kk * 32 + g16 * 8;
            float4 cva = *(const float4*)(ck);
            float4 cvb = *(const float4*)(ck + 4);
            float p0 = fmaf(xix, wxa.x, fmaf(xiy, wya.x, fmaf(xiz, wza.x, cva.x)));
            float p1 = fmaf(xix, wxa.y, fmaf(xiy, wya.y, fmaf(xiz, wza.y, cva.y)));
            float p2 = fmaf(xix, wxa.z, fmaf(xiy, wya.z, fmaf(xiz, wza.z, cva.z)));
            float p3 = fmaf(xix, wxa.w, fmaf(xiy, wya.w, fmaf(xiz, wza.w, cva.w)));
            float p4 = fmaf(xix, wxb.x, fmaf(xiy, wyb.x, fmaf(xiz, wzb.x, cvb.x)));
            float p5 = fmaf(xix, wxb.y, fmaf(xiy, wyb.y, fmaf(xiz, wzb.y, cvb.y)));
            float p6 = fmaf(xix, wxb.z, fmaf(xiy, wyb.z, fmaf(xiz, wzb.z, cvb.z)));
            float p7 = fmaf(xix, wxb.w, fmaf(xiy, wyb.w, fmaf(xiz, wzb.w, cvb.w)));
            float t0, t1, t2, t3, t4, t5, t6, t7;
            tanh2(p0, p1, t0, t1);
            tanh2(p2, p3, t2, t3);
            tanh2(p4, p5, t4, t5);
            tanh2(p6, p7, t6, t7);
            uint4 bv;
            bv.x = pack_bf16_trunc(t0, t1);
            bv.y = pack_bf16_trunc(t2, t3);
            bv.z = pack_bf16_trunc(t4, t5);
            bv.w = pack_bf16_trunc(t6, t7);
            bf16x8 bf = __builtin_bit_cast(bf16x8, bv);
#pragma unroll
            for (int I = 0; I < 4; I++)
                acc[I] = __builtin_amdgcn_mfma_f32_16x16x32_bf16(af[I], bf, acc[I], 0, 0, 0);
        }

        // --- layer 3 (paired tanh) ---
        float pj0 = 0.f, pj1 = 0.f, pj2 = 0.f;
#pragma unroll
        for (int I = 0; I < 4; I++) {
            const float* wp = w2 + 3 * (I * 16 + g16 * 4);
            float4 wa = *(const float4*)(wp);
            float4 wb = *(const float4*)(wp + 4);
            float4 wc = *(const float4*)(wp + 8);
            float4 cv = *(const float4*)(c1 + I * 16 + g16 * 4);
            float th0, th1, th2, th3;
            tanh2(acc[I][0] + cv.x, acc[I][1] + cv.y, th0, th1);
            tanh2(acc[I][2] + cv.z, acc[I][3] + cv.w, th2, th3);
            pj0 = fmaf(th0, wa.x, pj0); pj1 = fmaf(th0, wa.y, pj1); pj2 = fmaf(th0, wa.z, pj2);
            pj0 = fmaf(th1, wa.w, pj0); pj1 = fmaf(th1, wb.x, pj1); pj2 = fmaf(th1, wb.y, pj2);
            pj0 = fmaf(th2, wb.z, pj0); pj1 = fmaf(th2, wb.w, pj1); pj2 = fmaf(th2, wc.x, pj2);
            pj0 = fmaf(th3, wc.y, pj0); pj1 = fmaf(th3, wc.z, pj1); pj2 = fmaf(th3, wc.w, pj2);
        }
        pj0 += __shfl_xor(pj0, 16, 64); pj0 += __shfl_xor(pj0, 32, 64);
        pj1 += __shfl_xor(pj1, 16, 64); pj1 += __shfl_xor(pj1, 32, 64);
        pj2 += __shfl_xor(pj2, 16, 64); pj2 += __shfl_xor(pj2, 32, 64);
        float gv0 = pj0 + c2[0];
        float gv1 = pj1 + c2[1];
        float gv2 = pj2 + c2[2];

        // --- v = g @ (gt @ Ti), columns 1,2 only ---
        float M01 = fmaf(-sp, g00, cp * g01);
        float M11 = fmaf(-sp, g10, cp * g11);
        float M21 = fmaf(-sp, g20, cp * g21);
        float M02 = fmaf(g00, T02, fmaf(g01, T12, g02 * T22));
        float M12 = fmaf(g10, T02, fmaf(g11, T12, g12 * T22));
        float M22 = fmaf(g20, T02, fmaf(g21, T12, g22 * T22));
        float v1 = fmaf(gv0, M01, fmaf(gv1, M11, gv2 * M21));
        float v2 = fmaf(gv0, M02, fmaf(gv1, M12, gv2 * M22));

        const float2 dB = *(const float2*)(dBt + ((size_t)t * NB + p) * 2);
        float dB0 = dB.x, dB1 = dB.y;
        u_pre += fmaf(v1, dB1, -v2 * dB0);

        // --- dX3 / dX (small-angle Taylor sincos; |dB| <= ~0.5) ---
        float s0d, c0d, s1d, c1d;
        sincos_small(dB0, s0d, c0d);
        sincos_small(dB1, s1d, c1d);
        float dx30 = fmaf(c0d, c1d, -1.0f);
        float dx31 = c0d * s1d;
        float dx32 = -s0d;

        float dX0 = fmaf(T00, dx30, fmaf(T01, dx31, T02 * dx32));
        float dX1 = fmaf(T10, dx30, fmaf(T11, dx31, T12 * dx32));
        float dX2 = fmaf(T20, dx30, T22 * dx32);

        xtx += dX0; xty += dX1; xtz += dX2;

        float xi0 = xix + fmaf(g00, dX0, fmaf(g01, dX1, g02 * dX2));
        float xi1 = xiy + fmaf(g10, dX0, fmaf(g11, dX1, g12 * dX2));
        float xi2 = xiz + fmaf(g20, dX0, fmaf(g21, dX1, g22 * dX2));

        // --- reflection via rsqrt ---
        float ri2 = fmaf(xi0, xi0, fmaf(xi1, xi1, xi2 * xi2));
        float rs2 = __builtin_amdgcn_rsqf(ri2);
        float ri  = ri2 * rs2;                 // sqrt(ri2)
        bool outb = ri > RB;
        float n0 = xi0 * rs2, n1 = xi1 * rs2, n2 = xi2 * rs2;
        float coef = 2.0f * (ri - RB);

        xix = outb ? fmaf(-coef, n0, xi0) : xi0;
        xiy = outb ? fmaf(-coef, n1, xi1) : xi1;
        xiz = outb ? fmaf(-coef, n2, xi2) : xi2;

        float mm0 = fmaf(n0, g00, fmaf(n1, g10, n2 * g20));
        float mm1 = fmaf(n0, g01, fmaf(n1, g11, n2 * g21));
        float mm2 = fmaf(n0, g02, fmaf(n1, g12, n2 * g22));
        float tn0 = 2.0f * n0, tn1 = 2.0f * n1, tn2 = 2.0f * n2;
        g00 = outb ? fmaf(-tn0, mm0, g00) : g00;
        g01 = outb ? fmaf(-tn0, mm1, g01) : g01;
        g02 = outb ? fmaf(-tn0, mm2, g02) : g02;
        g10 = outb ? fmaf(-tn1, mm0, g10) : g10;
        g11 = outb ? fmaf(-tn1, mm1, g11) : g11;
        g12 = outb ? fmaf(-tn1, mm2, g12) : g12;
        g20 = outb ? fmaf(-tn2, mm0, g20) : g20;
        g21 = outb ? fmaf(-tn2, mm1, g21) : g21;
        g22 = outb ? fmaf(-tn2, mm2, g22) : g22;
    }

    float u_rel = fmaf(xix, xix, fmaf(xiy, xiy, xiz * xiz));
    if (g16 == 0) {
        out[p] = u_pre;
        out[NB + p] = u_rel;
    }
}

// ------------------- fallback (R3 kernel, unpacked weights) -------------------
__global__ __launch_bounds__(256, 4) void sde_ref(
    const float* __restrict__ xt0,
    const float* __restrict__ dBt,
    const float* __restrict__ W0u, const float* __restrict__ b0u,
    const float* __restrict__ W1u, const float* __restrict__ b1u,
    const float* __restrict__ W2u, const float* __restrict__ b2u,
    const float* __restrict__ Wg0, const float* __restrict__ bg0,
    const float* __restrict__ Wg1, const float* __restrict__ bg1,
    const float* __restrict__ Wg2, const float* __restrict__ bg2,
    float* __restrict__ out)
{
    const int tid  = threadIdx.x;
    const int lane = tid & 63;
    const int wv   = tid >> 6;
    const int g16  = (lane >> 4) & 3;
    const int l15  = lane & 15;
    const int p    = blockIdx.x * 64 + wv * 16 + l15;

    float xtx = xt0[p * 3 + 0];
    float xty = xt0[p * 3 + 1];
    float xtz = xt0[p * 3 + 2];
    float xix = xtx, xiy = xty, xiz = xtz;
    float g00 = 1.f, g01 = 0.f, g02 = 0.f;
    float g10 = 0.f, g11 = 1.f, g12 = 0.f;
    float g20 = 0.f, g21 = 0.f, g22 = 1.f;

    float u_pre;
    {
        f32x4 acc[4];
#pragma unroll
        for (int I = 0; I < 4; I++) acc[I] = (f32x4){0.f, 0.f, 0.f, 0.f};
        mlp_h2_unpacked(xtx, xty, xtz, W0u, b0u, W1u, lane, acc);
        float pj = 0.f;
#pragma unroll
        for (int I = 0; I < 4; I++) {
            float4 wv2 = *(const float4*)(W2u + I * 16 + g16 * 4);
            float4 cv  = *(const float4*)(b1u + I * 16 + g16 * 4);
            pj = fmaf(tanh_fast(acc[I][0] + cv.x), wv2.x, pj);
            pj = fmaf(tanh_fast(acc[I][1] + cv.y), wv2.y, pj);
            pj = fmaf(tanh_fast(acc[I][2] + cv.z), wv2.z, pj);
            pj = fmaf(tanh_fast(acc[I][3] + cv.w), wv2.w, pj);
        }
        pj += __shfl_xor(pj, 16, 64);
        pj += __shfl_xor(pj, 32, 64);
        u_pre = pj + b2u[0];
    }

#pragma unroll 1
    for (int t = 0; t < NSTEP; t++) {
        const float* w0 = Wg0 + (size_t)t * 3 * HD;
        const float* c0 = bg0 + (size_t)t * HD;
        const float* c1 = bg1 + (size_t)t * HD;
        const float* w2 = Wg2 + (size_t)t * HD * 3;
        const float* c2 = bg2 + (size_t)t * 3;

        float r = sqrtf(fmaf(xtx, xtx, fmaf(xty, xty, xtz * xtz)));
        float uu = xtz / r;
        uu = fminf(fmaxf(uu, -0.999999f), 0.999999f);
        float ca = sqrtf((1.0f - uu) * (1.0f + uu));
        float sa = -uu;
        float rho = sqrtf(fmaf(xtx, xtx, xty * xty));
        float cp = (rho > 0.0f) ? (xtx / rho) : 1.0f;
        float sp = (rho > 0.0f) ? (xty / rho) : 0.0f;
        float T00 = cp * ca, T01 = -sp, T02 = cp * sa;
        float T10 = sp * ca, T11 = cp,  T12 = sp * sa;
        float T20 = -sa,               T22 = ca;

        f32x4 acc[4];
#pragma unroll
        for (int I = 0; I < 4; I++) acc[I] = (f32x4){0.f, 0.f, 0.f, 0.f};
        mlp_h2_unpacked(xix, xiy, xiz, w0, c0, Wg1 + (size_t)t * HD * HD, lane, acc);

        float pj0 = 0.f, pj1 = 0.f, pj2 = 0.f;
#pragma unroll
        for (int I = 0; I < 4; I++) {
            const float* wp = w2 + 3 * (I * 16 + g16 * 4);
            float4 wa = *(const float4*)(wp);
            float4 wb = *(const float4*)(wp + 4);
            float4 wc = *(const float4*)(wp + 8);
            float4 cv = *(const float4*)(c1 + I * 16 + g16 * 4);
            float th0 = tanh_fast(acc[I][0] + cv.x);
            float th1 = tanh_fast(acc[I][1] + cv.y);
            float th2 = tanh_fast(acc[I][2] + cv.z);
            float th3 = tanh_fast(acc[I][3] + cv.w);
            pj0 = fmaf(th0, wa.x, pj0); pj1 = fmaf(th0, wa.y, pj1); pj2 = fmaf(th0, wa.z, pj2);
            pj0 = fmaf(th1, wa.w, pj0); pj1 = fmaf(th1, wb.x, pj1); pj2 = fmaf(th1, wb.y, pj2);
            pj0 = fmaf(th2, wb.z, pj0); pj1 = fmaf(th2, wb.w, pj1); pj2 = fmaf(th2, wc.x, pj2);
            pj0 = fmaf(th3, wc.y, pj0); pj1 = fmaf(th3, wc.z, pj1); pj2 = fmaf(th3, wc.w, pj2);
        }
        pj0 += __shfl_xor(pj0, 16, 64); pj0 += __shfl_xor(pj0, 32, 64);
        pj1 += __shfl_xor(pj1, 16, 64); pj1 += __shfl_xor(pj1, 32, 64);
        pj2 += __shfl_xor(pj2, 16, 64); pj2 += __shfl_xor(pj2, 32, 64);
        float gv0 = pj0 + c2[0];
        float gv1 = pj1 + c2[1];
        float gv2 = pj2 + c2[2];

        float M01 = fmaf(-sp, g00, cp * g01);
        float M11 = fmaf(-sp, g10, cp * g11);
        float M21 = fmaf(-sp, g20, cp * g21);
        float M02 = fmaf(g00, T02, fmaf(g01, T12, g02 * T22));
        float M12 = fmaf(g10, T02, fmaf(g11, T12, g12 * T22));
        float M22 = fmaf(g20, T02, fmaf(g21, T12, g22 * T22));
        float v1 = fmaf(gv0, M01, fmaf(gv1, M11, gv2 * M21));
        float v2 = fmaf(gv0, M02, fmaf(gv1, M12, gv2 * M22));

        const float2 dB = *(const float2*)(dBt + ((size_t)t * NB + p) * 2);
        float dB0 = dB.x, dB1 = dB.y;
        u_pre += fmaf(v1, dB1, -v2 * dB0);

        float s0d, c0d, s1d, c1d;
        __sincosf(dB0, &s0d, &c0d);
        __sincosf(dB1, &s1d, &c1d);
        float dx30 = fmaf(c0d, c1d, -1.0f);
        float dx31 = c0d * s1d;
        float dx32 = -s0d;

        float dX0 = fmaf(T00, dx30, fmaf(T01, dx31, T02 * dx32));
        float dX1 = fmaf(T10, dx30, fmaf(T11, dx31, T12 * dx32));
        float dX2 = fmaf(T20, dx30, T22 * dx32);

        xtx += dX0; xty += dX1; xtz += dX2;

        float xi0 = xix + fmaf(g00, dX0, fmaf(g01, dX1, g02 * dX2));
        float xi1 = xiy + fmaf(g10, dX0, fmaf(g11, dX1, g12 * dX2));
        float xi2 = xiz + fmaf(g20, dX0, fmaf(g21, dX1, g22 * dX2));

        float ri = sqrtf(fmaf(xi0, xi0, fmaf(xi1, xi1, xi2 * xi2)));
        bool outb = ri > RB;
        float n0 = xi0 / ri, n1 = xi1 / ri, n2 = xi2 / ri;
        float coef = 2.0f * (ri - RB);

        xix = outb ? fmaf(-coef, n0, xi0) : xi0;
        xiy = outb ? fmaf(-coef, n1, xi1) : xi1;
        xiz = outb ? fmaf(-coef, n2, xi2) : xi2;

        float mm0 = fmaf(n0, g00, fmaf(n1, g10, n2 * g20));
        float mm1 = fmaf(n0, g01, fmaf(n1, g11, n2 * g21));
        float mm2 = fmaf(n0, g02, fmaf(n1, g12, n2 * g22));
        float tn0 = 2.0f * n0, tn1 = 2.0f * n1, tn2 = 2.0f * n2;
        g00 = outb ? fmaf(-tn0, mm0, g00) : g00;
        g01 = outb ? fmaf(-tn0, mm1, g01) : g01;
        g02 = outb ? fmaf(-tn0, mm2, g02) : g02;
        g10 = outb ? fmaf(-tn1, mm0, g10) : g10;
        g11 = outb ? fmaf(-tn1, mm1, g11) : g11;
        g12 = outb ? fmaf(-tn1, mm2, g12) : g12;
        g20 = outb ? fmaf(-tn2, mm0, g20) : g20;
        g21 = outb ? fmaf(-tn2, mm1, g21) : g21;
        g22 = outb ? fmaf(-tn2, mm2, g22) : g22;
    }

    float u_rel = fmaf(xix, xix, fmaf(xiy, xiy, xiz * xiz));
    if (g16 == 0) {
        out[p] = u_pre;
        out[NB + p] = u_rel;
    }
}

extern "C" void kernel_launch(void* const* d_in, const int* in_sizes, int n_in,
                              void* d_out, int out_size, void* d_ws, size_t ws_size,
                              hipStream_t stream) {
    const float* xt0 = (const float*)d_in[0];
    const float* dBt = (const float*)d_in[1];
    const float* W0u = (const float*)d_in[2];
    const float* b0u = (const float*)d_in[3];
    const float* W1u = (const float*)d_in[4];
    const float* b1u = (const float*)d_in[5];
    const float* W2u = (const float*)d_in[6];
    const float* b2u = (const float*)d_in[7];
    const float* Wg0 = (const float*)d_in[8];
    const float* bg0 = (const float*)d_in[9];
    const float* Wg1 = (const float*)d_in[10];
    const float* bg1 = (const float*)d_in[11];
    const float* Wg2 = (const float*)d_in[12];
    const float* bg2 = (const float*)d_in[13];
    float* out = (float*)d_out;

    const size_t needed = (size_t)NSTEP * 2 * 4 * 64 * sizeof(uint4);  // 1 MB
    dim3 grid(NB * 4 / 256), block(256);
    if (ws_size >= needed && d_ws != nullptr) {
        hipLaunchKernelGGL(prep_kernel, dim3(256), dim3(256), 0, stream, Wg1, (uint4*)d_ws);
        hipLaunchKernelGGL(sde_fast, grid, block, 0, stream,
                           xt0, dBt, W0u, b0u, W1u, b1u, W2u, b2u,
                           Wg0, bg0, Wg1, bg1, Wg2, bg2, (const uint4*)d_ws, out);
    } else {
        hipLaunchKernelGGL(sde_ref, grid, block, 0, stream,
                           xt0, dBt, W0u, b0u, W1u, b1u, W2u, b2u,
                           Wg0, bg0, Wg1, bg1, Wg2, bg2, out);
    }
}

// Round 7
// 546.306 us; speedup vs baseline: 1.4459x; 1.1837x over previous
//
#include <hip/hip_runtime.h>

#define NB 65536
#define NSTEP 128
#define HD 64
#define RB 1.05f

typedef __bf16 bf16x8 __attribute__((ext_vector_type(8)));
typedef float f32x4 __attribute__((ext_vector_type(4)));
typedef unsigned int uint;
typedef unsigned short ushort;

// tanh(x) = 1 - 2/(1+e^{2x})
__device__ __forceinline__ float tanh_fast(float x) {
    float e2 = __expf(2.0f * x);
    return 1.0f - 2.0f * __builtin_amdgcn_rcpf(1.0f + e2);
}

// paired tanh: one v_rcp serves two tanh.
__device__ __forceinline__ void tanh2(float xa, float xb, float& ta, float& tb) {
    float ea = __expf(2.0f * xa);
    float eb = __expf(2.0f * xb);
    float a1 = 1.0f + ea;
    float b1 = 1.0f + eb;
    float rp = __builtin_amdgcn_rcpf(a1 * b1);
    ta = fmaf(-2.0f * b1, rp, 1.0f);
    tb = fmaf(-2.0f * a1, rp, 1.0f);
}

// small-angle sincos (|x| <= ~0.55)
__device__ __forceinline__ void sincos_small(float x, float& s, float& c) {
    float x2 = x * x;
    s = fmaf(x2, fmaf(x2, 8.3333333e-3f, -0.16666667f), 1.0f) * x;
    c = fmaf(x2, fmaf(x2, fmaf(x2, -1.3888889e-3f, 4.1666668e-2f), -0.5f), 1.0f);
}

__device__ __forceinline__ uint pack_bf16_trunc(float a, float b) {
    return __builtin_amdgcn_perm(__float_as_uint(b), __float_as_uint(a), 0x07060302u);
}

__device__ __forceinline__ ushort bf16_rne(float f) {
    uint u = __float_as_uint(f);
    u += 0x7fffu + ((u >> 16) & 1u);
    return (ushort)(u >> 16);
}

// logical h2 row placed at C position (I, s, j):  pi = (I&1)*4 + (I>>1)*32 + s*8 + j
// (bijection on 0..63; makes tanh(C) directly usable as the GEMM-2 B fragment)

// ---- prep 1: A1 fragments = W1^T, rows permuted by pi --------------------------
__global__ __launch_bounds__(256) void prep_a1(const float* __restrict__ Wg1,
                                               uint4* __restrict__ wsA1) {
    int tid  = blockIdx.x * 256 + threadIdx.x;   // ((t*2+kk)*4+I)*64 + lane
    int lane = tid & 63;
    int I    = (tid >> 6) & 3;
    int kk   = (tid >> 8) & 1;
    int t    = tid >> 9;
    int rA   = lane & 15;
    int s    = rA >> 2;
    int j    = rA & 3;
    int lrow = (I & 1) * 4 + (I >> 1) * 32 + s * 8 + j;   // pi(I,s,j)
    int k0   = kk * 32 + ((lane >> 4) & 3) * 8;
    const float* src = Wg1 + ((size_t)t * HD + k0) * HD + lrow;
    ushort o[8];
#pragma unroll
    for (int e = 0; e < 8; e++) o[e] = bf16_rne(src[(size_t)e * HD]);
    uint4 v;
    v.x = (uint)o[0] | ((uint)o[1] << 16);
    v.y = (uint)o[2] | ((uint)o[3] << 16);
    v.z = (uint)o[4] | ((uint)o[5] << 16);
    v.w = (uint)o[6] | ((uint)o[7] << 16);
    wsA1[tid] = v;
}

// ---- prep 2: A2 fragments = W2^T (rows 0..2 of 16, rest zero) ------------------
__global__ __launch_bounds__(256) void prep_a2(const float* __restrict__ Wg2,
                                               uint4* __restrict__ wsA2) {
    int tid  = blockIdx.x * 256 + threadIdx.x;   // (t*2+kk)*64 + lane
    int lane = tid & 63;
    int kk   = (tid >> 6) & 1;
    int t    = tid >> 7;
    int row  = lane & 15;
    int k0   = kk * 32 + ((lane >> 4) & 3) * 8;
    ushort o[8];
#pragma unroll
    for (int e = 0; e < 8; e++) {
        float v = (row < 3) ? Wg2[(size_t)t * HD * 3 + (size_t)(k0 + e) * 3 + row] : 0.0f;
        o[e] = bf16_rne(v);
    }
    uint4 v;
    v.x = (uint)o[0] | ((uint)o[1] << 16);
    v.y = (uint)o[2] | ((uint)o[3] << 16);
    v.z = (uint)o[4] | ((uint)o[5] << 16);
    v.w = (uint)o[6] | ((uint)o[7] << 16);
    wsA2[tid] = v;
}

// ---- prep 3: c1 permuted by pi -------------------------------------------------
__global__ __launch_bounds__(256) void prep_c1(const float* __restrict__ bg1,
                                               float* __restrict__ c1p) {
    int tid = blockIdx.x * 256 + threadIdx.x;    // t*64 + r
    int r   = tid & 63;
    int t   = tid >> 6;
    int pi  = ((r >> 4) & 1) * 4 + ((r >> 5) & 1) * 32 + ((r >> 2) & 3) * 8 + (r & 3);
    c1p[tid] = bg1[t * HD + pi];
}

// --------- unpacked helper (u_pre0 prologue and the fallback kernel) ----------
__device__ __forceinline__ void mlp_h2_unpacked(float xx, float xy, float xz,
                                                const float* __restrict__ w0,
                                                const float* __restrict__ c0,
                                                const float* __restrict__ w1,
                                                int lane, f32x4* acc) {
    const int g16 = (lane >> 4) & 3;
    const int l15 = lane & 15;
#pragma unroll
    for (int kk = 0; kk < 2; kk++) {
        bf16x8 af[4];
#pragma unroll
        for (int I = 0; I < 4; I++) {
            uint pk[4];
#pragma unroll
            for (int ep = 0; ep < 4; ep++) {
                float f0 = w1[(kk * 32 + g16 * 8 + 2 * ep + 0) * HD + I * 16 + l15];
                float f1 = w1[(kk * 32 + g16 * 8 + 2 * ep + 1) * HD + I * 16 + l15];
                pk[ep] = (uint)bf16_rne(f0) | ((uint)bf16_rne(f1) << 16);
            }
            uint4 v; v.x = pk[0]; v.y = pk[1]; v.z = pk[2]; v.w = pk[3];
            af[I] = __builtin_bit_cast(bf16x8, v);
        }
        const float* wk = w0 + kk * 32 + g16 * 8;
        float4 wxa = *(const float4*)(wk);
        float4 wxb = *(const float4*)(wk + 4);
        float4 wya = *(const float4*)(wk + HD);
        float4 wyb = *(const float4*)(wk + HD + 4);
        float4 wza = *(const float4*)(wk + 2 * HD);
        float4 wzb = *(const float4*)(wk + 2 * HD + 4);
        const float* ck = c0 + kk * 32 + g16 * 8;
        float4 cva = *(const float4*)(ck);
        float4 cvb = *(const float4*)(ck + 4);
        float p0 = fmaf(xx, wxa.x, fmaf(xy, wya.x, fmaf(xz, wza.x, cva.x)));
        float p1 = fmaf(xx, wxa.y, fmaf(xy, wya.y, fmaf(xz, wza.y, cva.y)));
        float p2 = fmaf(xx, wxa.z, fmaf(xy, wya.z, fmaf(xz, wza.z, cva.z)));
        float p3 = fmaf(xx, wxa.w, fmaf(xy, wya.w, fmaf(xz, wza.w, cva.w)));
        float p4 = fmaf(xx, wxb.x, fmaf(xy, wyb.x, fmaf(xz, wzb.x, cvb.x)));
        float p5 = fmaf(xx, wxb.y, fmaf(xy, wyb.y, fmaf(xz, wzb.y, cvb.y)));
        float p6 = fmaf(xx, wxb.z, fmaf(xy, wyb.z, fmaf(xz, wzb.z, cvb.z)));
        float p7 = fmaf(xx, wxb.w, fmaf(xy, wyb.w, fmaf(xz, wzb.w, cvb.w)));
        uint4 bv;
        bv.x = pack_bf16_trunc(tanh_fast(p0), tanh_fast(p1));
        bv.y = pack_bf16_trunc(tanh_fast(p2), tanh_fast(p3));
        bv.z = pack_bf16_trunc(tanh_fast(p4), tanh_fast(p5));
        bv.w = pack_bf16_trunc(tanh_fast(p6), tanh_fast(p7));
        bf16x8 bf = __builtin_bit_cast(bf16x8, bv);
#pragma unroll
        for (int I = 0; I < 4; I++)
            acc[I] = __builtin_amdgcn_mfma_f32_16x16x32_bf16(af[I], bf, acc[I], 0, 0, 0);
    }
}

// ------------------------------ fast path ------------------------------
__global__ __launch_bounds__(256, 4) void sde_fast(
    const float* __restrict__ xt0,
    const float* __restrict__ dBt,
    const float* __restrict__ W0u, const float* __restrict__ b0u,
    const float* __restrict__ W1u, const float* __restrict__ b1u,
    const float* __restrict__ W2u, const float* __restrict__ b2u,
    const float* __restrict__ Wg0, const float* __restrict__ bg0,
    const float* __restrict__ Wg1, const float* __restrict__ bg1,
    const float* __restrict__ Wg2, const float* __restrict__ bg2,
    const uint4* __restrict__ wsA1, const uint4* __restrict__ wsA2,
    const float* __restrict__ c1p,
    float* __restrict__ out)
{
    const int tid  = threadIdx.x;
    const int lane = tid & 63;
    const int wv   = tid >> 6;
    const int g16  = (lane >> 4) & 3;
    const int l15  = lane & 15;
    const int p    = blockIdx.x * 64 + wv * 16 + l15;   // particle (4 lanes share)

    float xtx = xt0[p * 3 + 0];
    float xty = xt0[p * 3 + 1];
    float xtz = xt0[p * 3 + 2];
    float xix = xtx, xiy = xty, xiz = xtz;
    float g00 = 1.f, g01 = 0.f, g02 = 0.f;
    float g10 = 0.f, g11 = 1.f, g12 = 0.f;
    float g20 = 0.f, g21 = 0.f, g22 = 1.f;

    // ---- u_pre0 (once; unpacked path) ----
    float u_pre;
    {
        f32x4 acc[4];
#pragma unroll
        for (int I = 0; I < 4; I++) acc[I] = (f32x4){0.f, 0.f, 0.f, 0.f};
        mlp_h2_unpacked(xtx, xty, xtz, W0u, b0u, W1u, lane, acc);
        float pj = 0.f;
#pragma unroll
        for (int I = 0; I < 4; I++) {
            float4 wv2 = *(const float4*)(W2u + I * 16 + g16 * 4);
            float4 cv  = *(const float4*)(b1u + I * 16 + g16 * 4);
            pj = fmaf(tanh_fast(acc[I][0] + cv.x), wv2.x, pj);
            pj = fmaf(tanh_fast(acc[I][1] + cv.y), wv2.y, pj);
            pj = fmaf(tanh_fast(acc[I][2] + cv.z), wv2.z, pj);
            pj = fmaf(tanh_fast(acc[I][3] + cv.w), wv2.w, pj);
        }
        pj += __shfl_xor(pj, 16, 64);
        pj += __shfl_xor(pj, 32, 64);
        u_pre = pj + b2u[0];
    }

#pragma unroll 1
    for (int t = 0; t < NSTEP; t++) {
        const float* w0 = Wg0 + (size_t)t * 3 * HD;
        const float* c0 = bg0 + (size_t)t * HD;
        const float* c2 = bg2 + (size_t)t * 3;

        // --- geometry via rsqrt ---
        float d  = fmaf(xtx, xtx, fmaf(xty, xty, xtz * xtz));
        float rs = __builtin_amdgcn_rsqf(d);
        float uu = xtz * rs;
        uu = fminf(fmaxf(uu, -0.999999f), 0.999999f);
        float ca = sqrtf((1.0f - uu) * (1.0f + uu));
        float sa = -uu;
        float rho2 = fmaf(xtx, xtx, xty * xty);
        bool hasrho = rho2 > 0.0f;
        float rr = __builtin_amdgcn_rsqf(rho2);
        float cp = hasrho ? (xtx * rr) : 1.0f;
        float sp = hasrho ? (xty * rr) : 0.0f;
        float T00 = cp * ca, T01 = -sp, T02 = cp * sa;
        float T10 = sp * ca, T11 = cp,  T12 = sp * sa;
        float T20 = -sa,               T22 = ca;   // T21 = 0

        // --- layer 1 + GEMM-1 (pi-permuted A rows) ---
        const uint4* apk = wsA1 + (size_t)t * 512;
        f32x4 acc[4];
#pragma unroll
        for (int I = 0; I < 4; I++) acc[I] = (f32x4){0.f, 0.f, 0.f, 0.f};
#pragma unroll
        for (int kk = 0; kk < 2; kk++) {
            bf16x8 af[4];
            const uint4* bp = apk + kk * 256 + lane;
#pragma unroll
            for (int I = 0; I < 4; I++) af[I] = __builtin_bit_cast(bf16x8, bp[I * 64]);

            const float* wk = w0 + kk * 32 + g16 * 8;
            float4 wxa = *(const float4*)(wk);
            float4 wxb = *(const float4*)(wk + 4);
            float4 wya = *(const float4*)(wk + HD);
            float4 wyb = *(const float4*)(wk + HD + 4);
            float4 wza = *(const float4*)(wk + 2 * HD);
            float4 wzb = *(const float4*)(wk + 2 * HD + 4);
            const float* ck = c0 + kk * 32 + g16 * 8;
            float4 cva = *(const float4*)(ck);
            float4 cvb = *(const float4*)(ck + 4);
            float p0 = fmaf(xix, wxa.x, fmaf(xiy, wya.x, fmaf(xiz, wza.x, cva.x)));
            float p1 = fmaf(xix, wxa.y, fmaf(xiy, wya.y, fmaf(xiz, wza.y, cva.y)));
            float p2 = fmaf(xix, wxa.z, fmaf(xiy, wya.z, fmaf(xiz, wza.z, cva.z)));
            float p3 = fmaf(xix, wxa.w, fmaf(xiy, wya.w, fmaf(xiz, wza.w, cva.w)));
            float p4 = fmaf(xix, wxb.x, fmaf(xiy, wyb.x, fmaf(xiz, wzb.x, cvb.x)));
            float p5 = fmaf(xix, wxb.y, fmaf(xiy, wyb.y, fmaf(xiz, wzb.y, cvb.y)));
            float p6 = fmaf(xix, wxb.z, fmaf(xiy, wyb.z, fmaf(xiz, wzb.z, cvb.z)));
            float p7 = fmaf(xix, wxb.w, fmaf(xiy, wyb.w, fmaf(xiz, wzb.w, cvb.w)));
            float t0, t1, t2, t3, t4, t5, t6, t7;
            tanh2(p0, p1, t0, t1);
            tanh2(p2, p3, t2, t3);
            tanh2(p4, p5, t4, t5);
            tanh2(p6, p7, t6, t7);
            uint4 bv;
            bv.x = pack_bf16_trunc(t0, t1);
            bv.y = pack_bf16_trunc(t2, t3);
            bv.z = pack_bf16_trunc(t4, t5);
            bv.w = pack_bf16_trunc(t6, t7);
            bf16x8 bf = __builtin_bit_cast(bf16x8, bv);
#pragma unroll
            for (int I = 0; I < 4; I++)
                acc[I] = __builtin_amdgcn_mfma_f32_16x16x32_bf16(af[I], bf, acc[I], 0, 0, 0);
        }

        // --- layer 3 via GEMM-2: g = tanh(h2)^T @ W2 ---
        const float* c1p_t = c1p + (size_t)t * HD;
        const uint4* a2p = wsA2 + (size_t)t * 128 + lane;
        f32x4 acc2 = (f32x4){0.f, 0.f, 0.f, 0.f};
#pragma unroll
        for (int half = 0; half < 2; half++) {
            float4 cv0 = *(const float4*)(c1p_t + (2 * half + 0) * 16 + g16 * 4);
            float4 cv1 = *(const float4*)(c1p_t + (2 * half + 1) * 16 + g16 * 4);
            float t0, t1, t2, t3, t4, t5, t6, t7;
            tanh2(acc[2 * half + 0][0] + cv0.x, acc[2 * half + 0][1] + cv0.y, t0, t1);
            tanh2(acc[2 * half + 0][2] + cv0.z, acc[2 * half + 0][3] + cv0.w, t2, t3);
            tanh2(acc[2 * half + 1][0] + cv1.x, acc[2 * half + 1][1] + cv1.y, t4, t5);
            tanh2(acc[2 * half + 1][2] + cv1.z, acc[2 * half + 1][3] + cv1.w, t6, t7);
            uint4 bv;
            bv.x = pack_bf16_trunc(t0, t1);
            bv.y = pack_bf16_trunc(t2, t3);
            bv.z = pack_bf16_trunc(t4, t5);
            bv.w = pack_bf16_trunc(t6, t7);
            bf16x8 bf = __builtin_bit_cast(bf16x8, bv);
            bf16x8 a2 = __builtin_bit_cast(bf16x8, a2p[half * 64]);
            acc2 = __builtin_amdgcn_mfma_f32_16x16x32_bf16(a2, bf, acc2, 0, 0, 0);
        }
        // gv lives in lane l15 (k-slice 0), regs 0..2; broadcast to the particle's 4 lanes
        float gv0 = __shfl(acc2[0], l15, 64) + c2[0];
        float gv1 = __shfl(acc2[1], l15, 64) + c2[1];
        float gv2 = __shfl(acc2[2], l15, 64) + c2[2];

        // --- v = g @ (gt @ Ti), columns 1,2 only ---
        float M01 = fmaf(-sp, g00, cp * g01);
        float M11 = fmaf(-sp, g10, cp * g11);
        float M21 = fmaf(-sp, g20, cp * g21);
        float M02 = fmaf(g00, T02, fmaf(g01, T12, g02 * T22));
        float M12 = fmaf(g10, T02, fmaf(g11, T12, g12 * T22));
        float M22 = fmaf(g20, T02, fmaf(g21, T12, g22 * T22));
        float v1 = fmaf(gv0, M01, fmaf(gv1, M11, gv2 * M21));
        float v2 = fmaf(gv0, M02, fmaf(gv1, M12, gv2 * M22));

        const float2 dB = *(const float2*)(dBt + ((size_t)t * NB + p) * 2);
        float dB0 = dB.x, dB1 = dB.y;
        u_pre += fmaf(v1, dB1, -v2 * dB0);

        // --- dX3 / dX ---
        float s0d, c0d, s1d, c1d;
        sincos_small(dB0, s0d, c0d);
        sincos_small(dB1, s1d, c1d);
        float dx30 = fmaf(c0d, c1d, -1.0f);
        float dx31 = c0d * s1d;
        float dx32 = -s0d;

        float dX0 = fmaf(T00, dx30, fmaf(T01, dx31, T02 * dx32));
        float dX1 = fmaf(T10, dx30, fmaf(T11, dx31, T12 * dx32));
        float dX2 = fmaf(T20, dx30, T22 * dx32);

        xtx += dX0; xty += dX1; xtz += dX2;

        float xi0 = xix + fmaf(g00, dX0, fmaf(g01, dX1, g02 * dX2));
        float xi1 = xiy + fmaf(g10, dX0, fmaf(g11, dX1, g12 * dX2));
        float xi2 = xiz + fmaf(g20, dX0, fmaf(g21, dX1, g22 * dX2));

        float ri2 = fmaf(xi0, xi0, fmaf(xi1, xi1, xi2 * xi2));
        float rs2 = __builtin_amdgcn_rsqf(ri2);
        float ri  = ri2 * rs2;
        bool outb = ri > RB;
        float n0 = xi0 * rs2, n1 = xi1 * rs2, n2 = xi2 * rs2;
        float coef = 2.0f * (ri - RB);

        xix = outb ? fmaf(-coef, n0, xi0) : xi0;
        xiy = outb ? fmaf(-coef, n1, xi1) : xi1;
        xiz = outb ? fmaf(-coef, n2, xi2) : xi2;

        float mm0 = fmaf(n0, g00, fmaf(n1, g10, n2 * g20));
        float mm1 = fmaf(n0, g01, fmaf(n1, g11, n2 * g21));
        float mm2 = fmaf(n0, g02, fmaf(n1, g12, n2 * g22));
        float tn0 = 2.0f * n0, tn1 = 2.0f * n1, tn2 = 2.0f * n2;
        g00 = outb ? fmaf(-tn0, mm0, g00) : g00;
        g01 = outb ? fmaf(-tn0, mm1, g01) : g01;
        g02 = outb ? fmaf(-tn0, mm2, g02) : g02;
        g10 = outb ? fmaf(-tn1, mm0, g10) : g10;
        g11 = outb ? fmaf(-tn1, mm1, g11) : g11;
        g12 = outb ? fmaf(-tn1, mm2, g12) : g12;
        g20 = outb ? fmaf(-tn2, mm0, g20) : g20;
        g21 = outb ? fmaf(-tn2, mm1, g21) : g21;
        g22 = outb ? fmaf(-tn2, mm2, g22) : g22;
    }

    float u_rel = fmaf(xix, xix, fmaf(xiy, xiy, xiz * xiz));
    if (g16 == 0) {
        out[p] = u_pre;
        out[NB + p] = u_rel;
    }
}

// ------------------- fallback (R3 kernel, unpacked weights) -------------------
__global__ __launch_bounds__(256, 4) void sde_ref(
    const float* __restrict__ xt0,
    const float* __restrict__ dBt,
    const float* __restrict__ W0u, const float* __restrict__ b0u,
    const float* __restrict__ W1u, const float* __restrict__ b1u,
    const float* __restrict__ W2u, const float* __restrict__ b2u,
    const float* __restrict__ Wg0, const float* __restrict__ bg0,
    const float* __restrict__ Wg1, const float* __restrict__ bg1,
    const float* __restrict__ Wg2, const float* __restrict__ bg2,
    float* __restrict__ out)
{
    const int tid  = threadIdx.x;
    const int lane = tid & 63;
    const int wv   = tid >> 6;
    const int g16  = (lane >> 4) & 3;
    const int l15  = lane & 15;
    const int p    = blockIdx.x * 64 + wv * 16 + l15;

    float xtx = xt0[p * 3 + 0];
    float xty = xt0[p * 3 + 1];
    float xtz = xt0[p * 3 + 2];
    float xix = xtx, xiy = xty, xiz = xtz;
    float g00 = 1.f, g01 = 0.f, g02 = 0.f;
    float g10 = 0.f, g11 = 1.f, g12 = 0.f;
    float g20 = 0.f, g21 = 0.f, g22 = 1.f;

    float u_pre;
    {
        f32x4 acc[4];
#pragma unroll
        for (int I = 0; I < 4; I++) acc[I] = (f32x4){0.f, 0.f, 0.f, 0.f};
        mlp_h2_unpacked(xtx, xty, xtz, W0u, b0u, W1u, lane, acc);
        float pj = 0.f;
#pragma unroll
        for (int I = 0; I < 4; I++) {
            float4 wv2 = *(const float4*)(W2u + I * 16 + g16 * 4);
            float4 cv  = *(const float4*)(b1u + I * 16 + g16 * 4);
            pj = fmaf(tanh_fast(acc[I][0] + cv.x), wv2.x, pj);
            pj = fmaf(tanh_fast(acc[I][1] + cv.y), wv2.y, pj);
            pj = fmaf(tanh_fast(acc[I][2] + cv.z), wv2.z, pj);
            pj = fmaf(tanh_fast(acc[I][3] + cv.w), wv2.w, pj);
        }
        pj += __shfl_xor(pj, 16, 64);
        pj += __shfl_xor(pj, 32, 64);
        u_pre = pj + b2u[0];
    }

#pragma unroll 1
    for (int t = 0; t < NSTEP; t++) {
        const float* w0 = Wg0 + (size_t)t * 3 * HD;
        const float* c0 = bg0 + (size_t)t * HD;
        const float* c1 = bg1 + (size_t)t * HD;
        const float* w2 = Wg2 + (size_t)t * HD * 3;
        const float* c2 = bg2 + (size_t)t * 3;

        float r = sqrtf(fmaf(xtx, xtx, fmaf(xty, xty, xtz * xtz)));
        float uu = xtz / r;
        uu = fminf(fmaxf(uu, -0.999999f), 0.999999f);
        float ca = sqrtf((1.0f - uu) * (1.0f + uu));
        float sa = -uu;
        float rho = sqrtf(fmaf(xtx, xtx, xty * xty));
        float cp = (rho > 0.0f) ? (xtx / rho) : 1.0f;
        float sp = (rho > 0.0f) ? (xty / rho) : 0.0f;
        float T00 = cp * ca, T01 = -sp, T02 = cp * sa;
        float T10 = sp * ca, T11 = cp,  T12 = sp * sa;
        float T20 = -sa,               T22 = ca;

        f32x4 acc[4];
#pragma unroll
        for (int I = 0; I < 4; I++) acc[I] = (f32x4){0.f, 0.f, 0.f, 0.f};
        mlp_h2_unpacked(xix, xiy, xiz, w0, c0, Wg1 + (size_t)t * HD * HD, lane, acc);

        float pj0 = 0.f, pj1 = 0.f, pj2 = 0.f;
#pragma unroll
        for (int I = 0; I < 4; I++) {
            const float* wp = w2 + 3 * (I * 16 + g16 * 4);
            float4 wa = *(const float4*)(wp);
            float4 wb = *(const float4*)(wp + 4);
            float4 wc = *(const float4*)(wp + 8);
            float4 cv = *(const float4*)(c1 + I * 16 + g16 * 4);
            float th0 = tanh_fast(acc[I][0] + cv.x);
            float th1 = tanh_fast(acc[I][1] + cv.y);
            float th2 = tanh_fast(acc[I][2] + cv.z);
            float th3 = tanh_fast(acc[I][3] + cv.w);
            pj0 = fmaf(th0, wa.x, pj0); pj1 = fmaf(th0, wa.y, pj1); pj2 = fmaf(th0, wa.z, pj2);
            pj0 = fmaf(th1, wa.w, pj0); pj1 = fmaf(th1, wb.x, pj1); pj2 = fmaf(th1, wb.y, pj2);
            pj0 = fmaf(th2, wb.z, pj0); pj1 = fmaf(th2, wb.w, pj1); pj2 = fmaf(th2, wc.x, pj2);
            pj0 = fmaf(th3, wc.y, pj0); pj1 = fmaf(th3, wc.z, pj1); pj2 = fmaf(th3, wc.w, pj2);
        }
        pj0 += __shfl_xor(pj0, 16, 64); pj0 += __shfl_xor(pj0, 32, 64);
        pj1 += __shfl_xor(pj1, 16, 64); pj1 += __shfl_xor(pj1, 32, 64);
        pj2 += __shfl_xor(pj2, 16, 64); pj2 += __shfl_xor(pj2, 32, 64);
        float gv0 = pj0 + c2[0];
        float gv1 = pj1 + c2[1];
        float gv2 = pj2 + c2[2];

        float M01 = fmaf(-sp, g00, cp * g01);
        float M11 = fmaf(-sp, g10, cp * g11);
        float M21 = fmaf(-sp, g20, cp * g21);
        float M02 = fmaf(g00, T02, fmaf(g01, T12, g02 * T22));
        float M12 = fmaf(g10, T02, fmaf(g11, T12, g12 * T22));
        float M22 = fmaf(g20, T02, fmaf(g21, T12, g22 * T22));
        float v1 = fmaf(gv0, M01, fmaf(gv1, M11, gv2 * M21));
        float v2 = fmaf(gv0, M02, fmaf(gv1, M12, gv2 * M22));

        const float2 dB = *(const float2*)(dBt + ((size_t)t * NB + p) * 2);
        float dB0 = dB.x, dB1 = dB.y;
        u_pre += fmaf(v1, dB1, -v2 * dB0);

        float s0d, c0d, s1d, c1d;
        __sincosf(dB0, &s0d, &c0d);
        __sincosf(dB1, &s1d, &c1d);
        float dx30 = fmaf(c0d, c1d, -1.0f);
        float dx31 = c0d * s1d;
        float dx32 = -s0d;

        float dX0 = fmaf(T00, dx30, fmaf(T01, dx31, T02 * dx32));
        float dX1 = fmaf(T10, dx30, fmaf(T11, dx31, T12 * dx32));
        float dX2 = fmaf(T20, dx30, T22 * dx32);

        xtx += dX0; xty += dX1; xtz += dX2;

        float xi0 = xix + fmaf(g00, dX0, fmaf(g01, dX1, g02 * dX2));
        float xi1 = xiy + fmaf(g10, dX0, fmaf(g11, dX1, g12 * dX2));
        float xi2 = xiz + fmaf(g20, dX0, fmaf(g21, dX1, g22 * dX2));

        float ri = sqrtf(fmaf(xi0, xi0, fmaf(xi1, xi1, xi2 * xi2)));
        bool outb = ri > RB;
        float n0 = xi0 / ri, n1 = xi1 / ri, n2 = xi2 / ri;
        float coef = 2.0f * (ri - RB);

        xix = outb ? fmaf(-coef, n0, xi0) : xi0;
        xiy = outb ? fmaf(-coef, n1, xi1) : xi1;
        xiz = outb ? fmaf(-coef, n2, xi2) : xi2;

        float mm0 = fmaf(n0, g00, fmaf(n1, g10, n2 * g20));
        float mm1 = fmaf(n0, g01, fmaf(n1, g11, n2 * g21));
        float mm2 = fmaf(n0, g02, fmaf(n1, g12, n2 * g22));
        float tn0 = 2.0f * n0, tn1 = 2.0f * n1, tn2 = 2.0f * n2;
        g00 = outb ? fmaf(-tn0, mm0, g00) : g00;
        g01 = outb ? fmaf(-tn0, mm1, g01) : g01;
        g02 = outb ? fmaf(-tn0, mm2, g02) : g02;
        g10 = outb ? fmaf(-tn1, mm0, g10) : g10;
        g11 = outb ? fmaf(-tn1, mm1, g11) : g11;
        g12 = outb ? fmaf(-tn1, mm2, g12) : g12;
        g20 = outb ? fmaf(-tn2, mm0, g20) : g20;
        g21 = outb ? fmaf(-tn2, mm1, g21) : g21;
        g22 = outb ? fmaf(-tn2, mm2, g22) : g22;
    }

    float u_rel = fmaf(xix, xix, fmaf(xiy, xiy, xiz * xiz));
    if (g16 == 0) {
        out[p] = u_pre;
        out[NB + p] = u_rel;
    }
}

extern "C" void kernel_launch(void* const* d_in, const int* in_sizes, int n_in,
                              void* d_out, int out_size, void* d_ws, size_t ws_size,
                              hipStream_t stream) {
    const float* xt0 = (const float*)d_in[0];
    const float* dBt = (const float*)d_in[1];
    const float* W0u = (const float*)d_in[2];
    const float* b0u = (const float*)d_in[3];
    const float* W1u = (const float*)d_in[4];
    const float* b1u = (const float*)d_in[5];
    const float* W2u = (const float*)d_in[6];
    const float* b2u = (const float*)d_in[7];
    const float* Wg0 = (const float*)d_in[8];
    const float* bg0 = (const float*)d_in[9];
    const float* Wg1 = (const float*)d_in[10];
    const float* bg1 = (const float*)d_in[11];
    const float* Wg2 = (const float*)d_in[12];
    const float* bg2 = (const float*)d_in[13];
    float* out = (float*)d_out;

    const size_t szA1 = (size_t)NSTEP * 2 * 4 * 64 * sizeof(uint4);   // 1 MB
    const size_t szA2 = (size_t)NSTEP * 2 * 64 * sizeof(uint4);       // 256 KB
    const size_t szC1 = (size_t)NSTEP * HD * sizeof(float);           // 32 KB
    dim3 grid(NB * 4 / 256), block(256);
    if (ws_size >= szA1 + szA2 + szC1 && d_ws != nullptr) {
        uint4* wsA1 = (uint4*)d_ws;
        uint4* wsA2 = (uint4*)((char*)d_ws + szA1);
        float* c1p  = (float*)((char*)d_ws + szA1 + szA2);
        hipLaunchKernelGGL(prep_a1, dim3(256), dim3(256), 0, stream, Wg1, wsA1);
        hipLaunchKernelGGL(prep_a2, dim3(64), dim3(256), 0, stream, Wg2, wsA2);
        hipLaunchKernelGGL(prep_c1, dim3(32), dim3(256), 0, stream, bg1, c1p);
        hipLaunchKernelGGL(sde_fast, grid, block, 0, stream,
                           xt0, dBt, W0u, b0u, W1u, b1u, W2u, b2u,
                           Wg0, bg0, Wg1, bg1, Wg2, bg2,
                           (const uint4*)wsA1, (const uint4*)wsA2, (const float*)c1p, out);
    } else {
        hipLaunchKernelGGL(sde_ref, grid, block, 0, stream,
                           xt0, dBt, W0u, b0u, W1u, b1u, W2u, b2u,
                           Wg0, bg0, Wg1, bg1, Wg2, bg2, out);
    }
}

// Round 8
// 490.479 us; speedup vs baseline: 1.6105x; 1.1138x over previous
//
#include <hip/hip_runtime.h>

#define NB 65536
#define NSTEP 128
#define HD 64
#define RB 1.05f
#define TBLK 928          // uint4 per time-step in the ws blob
#define OFF_A1 0          // 512 uint4 : W1^T frags (pi-permuted rows), [kk*4+I]*64+lane
#define OFF_A0 512        // 256 uint4 : W0^T frags (h1idx-permuted rows), I*64+lane
#define OFF_A2 768        // 128 uint4 : W2^T frags (rows 0..2, rest 0), half*64+lane
#define OFF_CB 896        // 32 uint4  : c0p (64 f32) then c1p (64 f32), pi-permuted

typedef __bf16 bf16x8 __attribute__((ext_vector_type(8)));
typedef float f32x4 __attribute__((ext_vector_type(4)));
typedef unsigned int uint;
typedef unsigned short ushort;

// tanh(x) = 1 - 2/(1+e^{2x})
__device__ __forceinline__ float tanh_fast(float x) {
    float e2 = __expf(2.0f * x);
    return 1.0f - 2.0f * __builtin_amdgcn_rcpf(1.0f + e2);
}

// paired tanh: one v_rcp serves two tanh.
__device__ __forceinline__ void tanh2(float xa, float xb, float& ta, float& tb) {
    float ea = __expf(2.0f * xa);
    float eb = __expf(2.0f * xb);
    float a1 = 1.0f + ea;
    float b1 = 1.0f + eb;
    float rp = __builtin_amdgcn_rcpf(a1 * b1);
    ta = fmaf(-2.0f * b1, rp, 1.0f);
    tb = fmaf(-2.0f * a1, rp, 1.0f);
}

// small-angle sincos (|x| <= ~0.55)
__device__ __forceinline__ void sincos_small(float x, float& s, float& c) {
    float x2 = x * x;
    s = fmaf(x2, fmaf(x2, 8.3333333e-3f, -0.16666667f), 1.0f) * x;
    c = fmaf(x2, fmaf(x2, fmaf(x2, -1.3888889e-3f, 4.1666668e-2f), -0.5f), 1.0f);
}

__device__ __forceinline__ uint pack_bf16_trunc(float a, float b) {
    return __builtin_amdgcn_perm(__float_as_uint(b), __float_as_uint(a), 0x07060302u);
}

__device__ __forceinline__ ushort bf16_rne(float f) {
    uint u = __float_as_uint(f);
    u += 0x7fffu + ((u >> 16) & 1u);
    return (ushort)(u >> 16);
}

// pi(I,s,j) == h1idx(I,s,j) = (I>>1)*32 + s*8 + (I&1)*4 + j   (bijection on 0..63)
// GEMM-0 C slot (I, row g16*4+j, col p) carries h1pre[pi]; tanh of it is exactly
// GEMM-1's B-frag slot k = kk*32+g16*8+e (kk=I>>1, e=(I&1)*4+j).  Same pi makes
// tanh(GEMM-1 C) the GEMM-2 B operand (R7, verified).

// ---- prep: A1 = W1^T with pi-permuted rows ----
__global__ __launch_bounds__(256) void prep_a1(const float* __restrict__ Wg1,
                                               uint4* __restrict__ wsB) {
    int tid  = blockIdx.x * 256 + threadIdx.x;
    int lane = tid & 63;
    int I    = (tid >> 6) & 3;
    int kk   = (tid >> 8) & 1;
    int t    = tid >> 9;
    int rA   = lane & 15;
    int lrow = (I & 1) * 4 + (I >> 1) * 32 + (rA >> 2) * 8 + (rA & 3);
    int k0   = kk * 32 + ((lane >> 4) & 3) * 8;
    const float* src = Wg1 + ((size_t)t * HD + k0) * HD + lrow;
    ushort o[8];
#pragma unroll
    for (int e = 0; e < 8; e++) o[e] = bf16_rne(src[(size_t)e * HD]);
    uint4 v;
    v.x = (uint)o[0] | ((uint)o[1] << 16);
    v.y = (uint)o[2] | ((uint)o[3] << 16);
    v.z = (uint)o[4] | ((uint)o[5] << 16);
    v.w = (uint)o[6] | ((uint)o[7] << 16);
    wsB[(size_t)t * TBLK + OFF_A1 + (kk * 4 + I) * 64 + lane] = v;
}

// ---- prep: A0 = W0^T with h1idx-permuted rows (K=32, only k<3 nonzero) ----
__global__ __launch_bounds__(256) void prep_a0(const float* __restrict__ Wg0,
                                               uint4* __restrict__ wsB) {
    int tid  = blockIdx.x * 256 + threadIdx.x;
    int lane = tid & 63;
    int I    = (tid >> 6) & 3;
    int t    = tid >> 8;
    int m    = lane & 15;
    int kg   = (lane >> 4) & 3;
    int h    = (I >> 1) * 32 + (m >> 2) * 8 + (I & 1) * 4 + (m & 3);
    ushort o[8];
#pragma unroll
    for (int e = 0; e < 8; e++) {
        int k = kg * 8 + e;
        float v = (k < 3) ? Wg0[((size_t)t * 3 + k) * HD + h] : 0.0f;
        o[e] = bf16_rne(v);
    }
    uint4 v;
    v.x = (uint)o[0] | ((uint)o[1] << 16);
    v.y = (uint)o[2] | ((uint)o[3] << 16);
    v.z = (uint)o[4] | ((uint)o[5] << 16);
    v.w = (uint)o[6] | ((uint)o[7] << 16);
    wsB[(size_t)t * TBLK + OFF_A0 + I * 64 + lane] = v;
}

// ---- prep: A2 = W2^T (rows 0..2 of 16, rest zero) ----
__global__ __launch_bounds__(256) void prep_a2(const float* __restrict__ Wg2,
                                               uint4* __restrict__ wsB) {
    int tid  = blockIdx.x * 256 + threadIdx.x;
    int lane = tid & 63;
    int kk   = (tid >> 6) & 1;
    int t    = tid >> 7;
    int row  = lane & 15;
    int k0   = kk * 32 + ((lane >> 4) & 3) * 8;
    ushort o[8];
#pragma unroll
    for (int e = 0; e < 8; e++) {
        float v = (row < 3) ? Wg2[(size_t)t * HD * 3 + (size_t)(k0 + e) * 3 + row] : 0.0f;
        o[e] = bf16_rne(v);
    }
    uint4 v;
    v.x = (uint)o[0] | ((uint)o[1] << 16);
    v.y = (uint)o[2] | ((uint)o[3] << 16);
    v.z = (uint)o[4] | ((uint)o[5] << 16);
    v.w = (uint)o[6] | ((uint)o[7] << 16);
    wsB[(size_t)t * TBLK + OFF_A2 + kk * 64 + lane] = v;
}

// ---- prep: pi-permuted biases (c0p then c1p) ----
__global__ __launch_bounds__(256) void prep_bias(const float* __restrict__ bg0,
                                                 const float* __restrict__ bg1,
                                                 uint4* __restrict__ wsB) {
    int tid = blockIdx.x * 256 + threadIdx.x;   // t*128 + i
    int i   = tid & 127;
    int t   = tid >> 7;
    int r   = i & 63;
    int pi  = ((r >> 4) & 1) * 4 + ((r >> 5) & 1) * 32 + ((r >> 2) & 3) * 8 + (r & 3);
    float* dst = (float*)(wsB + (size_t)t * TBLK + OFF_CB);
    dst[i] = (i < 64) ? bg0[t * HD + pi] : bg1[t * HD + pi];
}

// --------- unpacked helper (u_pre0 prologue and the fallback kernel) ----------
__device__ __forceinline__ void mlp_h2_unpacked(float xx, float xy, float xz,
                                                const float* __restrict__ w0,
                                                const float* __restrict__ c0,
                                                const float* __restrict__ w1,
                                                int lane, f32x4* acc) {
    const int g16 = (lane >> 4) & 3;
    const int l15 = lane & 15;
#pragma unroll
    for (int kk = 0; kk < 2; kk++) {
        bf16x8 af[4];
#pragma unroll
        for (int I = 0; I < 4; I++) {
            uint pk[4];
#pragma unroll
            for (int ep = 0; ep < 4; ep++) {
                float f0 = w1[(kk * 32 + g16 * 8 + 2 * ep + 0) * HD + I * 16 + l15];
                float f1 = w1[(kk * 32 + g16 * 8 + 2 * ep + 1) * HD + I * 16 + l15];
                pk[ep] = (uint)bf16_rne(f0) | ((uint)bf16_rne(f1) << 16);
            }
            uint4 v; v.x = pk[0]; v.y = pk[1]; v.z = pk[2]; v.w = pk[3];
            af[I] = __builtin_bit_cast(bf16x8, v);
        }
        const float* wk = w0 + kk * 32 + g16 * 8;
        float4 wxa = *(const float4*)(wk);
        float4 wxb = *(const float4*)(wk + 4);
        float4 wya = *(const float4*)(wk + HD);
        float4 wyb = *(const float4*)(wk + HD + 4);
        float4 wza = *(const float4*)(wk + 2 * HD);
        float4 wzb = *(const float4*)(wk + 2 * HD + 4);
        const float* ck = c0 + kk * 32 + g16 * 8;
        float4 cva = *(const float4*)(ck);
        float4 cvb = *(const float4*)(ck + 4);
        float p0 = fmaf(xx, wxa.x, fmaf(xy, wya.x, fmaf(xz, wza.x, cva.x)));
        float p1 = fmaf(xx, wxa.y, fmaf(xy, wya.y, fmaf(xz, wza.y, cva.y)));
        float p2 = fmaf(xx, wxa.z, fmaf(xy, wya.z, fmaf(xz, wza.z, cva.z)));
        float p3 = fmaf(xx, wxa.w, fmaf(xy, wya.w, fmaf(xz, wza.w, cva.w)));
        float p4 = fmaf(xx, wxb.x, fmaf(xy, wyb.x, fmaf(xz, wzb.x, cvb.x)));
        float p5 = fmaf(xx, wxb.y, fmaf(xy, wyb.y, fmaf(xz, wzb.y, cvb.y)));
        float p6 = fmaf(xx, wxb.z, fmaf(xy, wyb.z, fmaf(xz, wzb.z, cvb.z)));
        float p7 = fmaf(xx, wxb.w, fmaf(xy, wyb.w, fmaf(xz, wzb.w, cvb.w)));
        uint4 bv;
        bv.x = pack_bf16_trunc(tanh_fast(p0), tanh_fast(p1));
        bv.y = pack_bf16_trunc(tanh_fast(p2), tanh_fast(p3));
        bv.z = pack_bf16_trunc(tanh_fast(p4), tanh_fast(p5));
        bv.w = pack_bf16_trunc(tanh_fast(p6), tanh_fast(p7));
        bf16x8 bf = __builtin_bit_cast(bf16x8, bv);
#pragma unroll
        for (int I = 0; I < 4; I++)
            acc[I] = __builtin_amdgcn_mfma_f32_16x16x32_bf16(af[I], bf, acc[I], 0, 0, 0);
    }
}

// ------------------------------ fast path ------------------------------
__global__ __launch_bounds__(256, 4) void sde_fast(
    const float* __restrict__ xt0,
    const float* __restrict__ dBt,
    const float* __restrict__ W0u, const float* __restrict__ b0u,
    const float* __restrict__ W1u, const float* __restrict__ b1u,
    const float* __restrict__ W2u, const float* __restrict__ b2u,
    const float* __restrict__ bg2,
    const uint4* __restrict__ wsB,
    float* __restrict__ out)
{
    const int tid  = threadIdx.x;
    const int lane = tid & 63;
    const int wv   = tid >> 6;
    const int g16  = (lane >> 4) & 3;
    const int l15  = lane & 15;
    const int p    = blockIdx.x * 64 + wv * 16 + l15;   // particle (4 lanes share)

    float xtx = xt0[p * 3 + 0];
    float xty = xt0[p * 3 + 1];
    float xtz = xt0[p * 3 + 2];
    float xix = xtx, xiy = xty, xiz = xtz;
    float g00 = 1.f, g01 = 0.f, g02 = 0.f;
    float g10 = 0.f, g11 = 1.f, g12 = 0.f;
    float g20 = 0.f, g21 = 0.f, g22 = 1.f;

    // ---- u_pre0 (once; unpacked path) ----
    float u_pre;
    {
        f32x4 acc[4];
#pragma unroll
        for (int I = 0; I < 4; I++) acc[I] = (f32x4){0.f, 0.f, 0.f, 0.f};
        mlp_h2_unpacked(xtx, xty, xtz, W0u, b0u, W1u, lane, acc);
        float pj = 0.f;
#pragma unroll
        for (int I = 0; I < 4; I++) {
            float4 wv2 = *(const float4*)(W2u + I * 16 + g16 * 4);
            float4 cv  = *(const float4*)(b1u + I * 16 + g16 * 4);
            pj = fmaf(tanh_fast(acc[I][0] + cv.x), wv2.x, pj);
            pj = fmaf(tanh_fast(acc[I][1] + cv.y), wv2.y, pj);
            pj = fmaf(tanh_fast(acc[I][2] + cv.z), wv2.z, pj);
            pj = fmaf(tanh_fast(acc[I][3] + cv.w), wv2.w, pj);
        }
        pj += __shfl_xor(pj, 16, 64);
        pj += __shfl_xor(pj, 32, 64);
        u_pre = pj + b2u[0];
    }

#pragma unroll 1
    for (int t = 0; t < NSTEP; t++) {
        const uint4* blob_t = wsB + (size_t)t * TBLK;
        const float* c0p_t  = (const float*)(blob_t + OFF_CB);
        const float* c1p_t  = c0p_t + 64;
        const float* c2     = bg2 + (size_t)t * 3;

        // --- geometry via rsqrt; ca = rho/r (no sqrt) ---
        float d  = fmaf(xtx, xtx, fmaf(xty, xty, xtz * xtz));
        float rs = __builtin_amdgcn_rsqf(d);
        float uu = xtz * rs;
        uu = fminf(fmaxf(uu, -0.999999f), 0.999999f);
        float sa = -uu;
        float rho2 = fmaf(xtx, xtx, xty * xty);
        bool hasrho = rho2 > 0.0f;
        float rr = __builtin_amdgcn_rsqf(rho2);
        float cp = hasrho ? (xtx * rr) : 1.0f;
        float sp = hasrho ? (xty * rr) : 0.0f;
        float ca = hasrho ? (rho2 * rr * rs) : 1.4142135e-3f;
        float T00 = cp * ca, T01 = -sp, T02 = cp * sa;
        float T10 = sp * ca, T11 = cp,  T12 = sp * sa;
        float T20 = -sa,               T22 = ca;   // T21 = 0

        // --- GEMM-0: h1pre = x @ W0 (+c0 via C-in), rows pre-permuted ---
        uint4 b0v;
        b0v.x = pack_bf16_trunc(xix, xiy);
        b0v.y = pack_bf16_trunc(xiz, 0.0f);
        b0v.z = 0u; b0v.w = 0u;
        bf16x8 b0 = __builtin_bit_cast(bf16x8, b0v);
        f32x4 acc0[4];
#pragma unroll
        for (int I = 0; I < 4; I++) {
            float4 cv = *(const float4*)(c0p_t + I * 16 + g16 * 4);
            acc0[I] = (f32x4){cv.x, cv.y, cv.z, cv.w};
        }
#pragma unroll
        for (int I = 0; I < 4; I++) {
            bf16x8 a0 = __builtin_bit_cast(bf16x8, blob_t[OFF_A0 + I * 64 + lane]);
            acc0[I] = __builtin_amdgcn_mfma_f32_16x16x32_bf16(a0, b0, acc0[I], 0, 0, 0);
        }

        // --- GEMM-1: h2pre = h1 @ W1 (+c1 via C-in); tanh(acc0) is the B operand ---
        f32x4 acc[4];
#pragma unroll
        for (int I = 0; I < 4; I++) {
            float4 cv = *(const float4*)(c1p_t + I * 16 + g16 * 4);
            acc[I] = (f32x4){cv.x, cv.y, cv.z, cv.w};
        }
#pragma unroll
        for (int kk = 0; kk < 2; kk++) {
            float t0, t1, t2, t3, t4, t5, t6, t7;
            tanh2(acc0[kk * 2 + 0][0], acc0[kk * 2 + 0][1], t0, t1);
            tanh2(acc0[kk * 2 + 0][2], acc0[kk * 2 + 0][3], t2, t3);
            tanh2(acc0[kk * 2 + 1][0], acc0[kk * 2 + 1][1], t4, t5);
            tanh2(acc0[kk * 2 + 1][2], acc0[kk * 2 + 1][3], t6, t7);
            uint4 bv;
            bv.x = pack_bf16_trunc(t0, t1);
            bv.y = pack_bf16_trunc(t2, t3);
            bv.z = pack_bf16_trunc(t4, t5);
            bv.w = pack_bf16_trunc(t6, t7);
            bf16x8 bf = __builtin_bit_cast(bf16x8, bv);
#pragma unroll
            for (int I = 0; I < 4; I++) {
                bf16x8 af = __builtin_bit_cast(bf16x8, blob_t[OFF_A1 + (kk * 4 + I) * 64 + lane]);
                acc[I] = __builtin_amdgcn_mfma_f32_16x16x32_bf16(af, bf, acc[I], 0, 0, 0);
            }
        }

        // --- GEMM-2: g = tanh(h2)^T @ W2 ---
        f32x4 acc2 = (f32x4){0.f, 0.f, 0.f, 0.f};
#pragma unroll
        for (int half = 0; half < 2; half++) {
            float t0, t1, t2, t3, t4, t5, t6, t7;
            tanh2(acc[2 * half + 0][0], acc[2 * half + 0][1], t0, t1);
            tanh2(acc[2 * half + 0][2], acc[2 * half + 0][3], t2, t3);
            tanh2(acc[2 * half + 1][0], acc[2 * half + 1][1], t4, t5);
            tanh2(acc[2 * half + 1][2], acc[2 * half + 1][3], t6, t7);
            uint4 bv;
            bv.x = pack_bf16_trunc(t0, t1);
            bv.y = pack_bf16_trunc(t2, t3);
            bv.z = pack_bf16_trunc(t4, t5);
            bv.w = pack_bf16_trunc(t6, t7);
            bf16x8 bf = __builtin_bit_cast(bf16x8, bv);
            bf16x8 a2 = __builtin_bit_cast(bf16x8, blob_t[OFF_A2 + half * 64 + lane]);
            acc2 = __builtin_amdgcn_mfma_f32_16x16x32_bf16(a2, bf, acc2, 0, 0, 0);
        }
        float gv0 = __shfl(acc2[0], l15, 64) + c2[0];
        float gv1 = __shfl(acc2[1], l15, 64) + c2[1];
        float gv2 = __shfl(acc2[2], l15, 64) + c2[2];

        // --- v = g @ (gt @ Ti), columns 1,2 only ---
        float M01 = fmaf(-sp, g00, cp * g01);
        float M11 = fmaf(-sp, g10, cp * g11);
        float M21 = fmaf(-sp, g20, cp * g21);
        float M02 = fmaf(g00, T02, fmaf(g01, T12, g02 * T22));
        float M12 = fmaf(g10, T02, fmaf(g11, T12, g12 * T22));
        float M22 = fmaf(g20, T02, fmaf(g21, T12, g22 * T22));
        float v1 = fmaf(gv0, M01, fmaf(gv1, M11, gv2 * M21));
        float v2 = fmaf(gv0, M02, fmaf(gv1, M12, gv2 * M22));

        const float2 dB = *(const float2*)(dBt + ((size_t)t * NB + p) * 2);
        float dB0 = dB.x, dB1 = dB.y;
        u_pre += fmaf(v1, dB1, -v2 * dB0);

        // --- dX3 / dX ---
        float s0d, c0d, s1d, c1d;
        sincos_small(dB0, s0d, c0d);
        sincos_small(dB1, s1d, c1d);
        float dx30 = fmaf(c0d, c1d, -1.0f);
        float dx31 = c0d * s1d;
        float dx32 = -s0d;

        float dX0 = fmaf(T00, dx30, fmaf(T01, dx31, T02 * dx32));
        float dX1 = fmaf(T10, dx30, fmaf(T11, dx31, T12 * dx32));
        float dX2 = fmaf(T20, dx30, T22 * dx32);

        xtx += dX0; xty += dX1; xtz += dX2;

        float xi0 = xix + fmaf(g00, dX0, fmaf(g01, dX1, g02 * dX2));
        float xi1 = xiy + fmaf(g10, dX0, fmaf(g11, dX1, g12 * dX2));
        float xi2 = xiz + fmaf(g20, dX0, fmaf(g21, dX1, g22 * dX2));

        float ri2 = fmaf(xi0, xi0, fmaf(xi1, xi1, xi2 * xi2));
        float rs2 = __builtin_amdgcn_rsqf(ri2);
        float ri  = ri2 * rs2;
        bool outb = ri > RB;
        float n0 = xi0 * rs2, n1 = xi1 * rs2, n2 = xi2 * rs2;
        float coef = 2.0f * (ri - RB);

        xix = outb ? fmaf(-coef, n0, xi0) : xi0;
        xiy = outb ? fmaf(-coef, n1, xi1) : xi1;
        xiz = outb ? fmaf(-coef, n2, xi2) : xi2;

        float mm0 = fmaf(n0, g00, fmaf(n1, g10, n2 * g20));
        float mm1 = fmaf(n0, g01, fmaf(n1, g11, n2 * g21));
        float mm2 = fmaf(n0, g02, fmaf(n1, g12, n2 * g22));
        float tn0 = 2.0f * n0, tn1 = 2.0f * n1, tn2 = 2.0f * n2;
        g00 = outb ? fmaf(-tn0, mm0, g00) : g00;
        g01 = outb ? fmaf(-tn0, mm1, g01) : g01;
        g02 = outb ? fmaf(-tn0, mm2, g02) : g02;
        g10 = outb ? fmaf(-tn1, mm0, g10) : g10;
        g11 = outb ? fmaf(-tn1, mm1, g11) : g11;
        g12 = outb ? fmaf(-tn1, mm2, g12) : g12;
        g20 = outb ? fmaf(-tn2, mm0, g20) : g20;
        g21 = outb ? fmaf(-tn2, mm1, g21) : g21;
        g22 = outb ? fmaf(-tn2, mm2, g22) : g22;
    }

    float u_rel = fmaf(xix, xix, fmaf(xiy, xiy, xiz * xiz));
    if (g16 == 0) {
        out[p] = u_pre;
        out[NB + p] = u_rel;
    }
}

// ------------------- fallback (R3-style kernel, unpacked weights) -------------------
__global__ __launch_bounds__(256, 4) void sde_ref(
    const float* __restrict__ xt0,
    const float* __restrict__ dBt,
    const float* __restrict__ W0u, const float* __restrict__ b0u,
    const float* __restrict__ W1u, const float* __restrict__ b1u,
    const float* __restrict__ W2u, const float* __restrict__ b2u,
    const float* __restrict__ Wg0, const float* __restrict__ bg0,
    const float* __restrict__ Wg1, const float* __restrict__ bg1,
    const float* __restrict__ Wg2, const float* __restrict__ bg2,
    float* __restrict__ out)
{
    const int tid  = threadIdx.x;
    const int lane = tid & 63;
    const int wv   = tid >> 6;
    const int g16  = (lane >> 4) & 3;
    const int l15  = lane & 15;
    const int p    = blockIdx.x * 64 + wv * 16 + l15;

    float xtx = xt0[p * 3 + 0];
    float xty = xt0[p * 3 + 1];
    float xtz = xt0[p * 3 + 2];
    float xix = xtx, xiy = xty, xiz = xtz;
    float g00 = 1.f, g01 = 0.f, g02 = 0.f;
    float g10 = 0.f, g11 = 1.f, g12 = 0.f;
    float g20 = 0.f, g21 = 0.f, g22 = 1.f;

    float u_pre;
    {
        f32x4 acc[4];
#pragma unroll
        for (int I = 0; I < 4; I++) acc[I] = (f32x4){0.f, 0.f, 0.f, 0.f};
        mlp_h2_unpacked(xtx, xty, xtz, W0u, b0u, W1u, lane, acc);
        float pj = 0.f;
#pragma unroll
        for (int I = 0; I < 4; I++) {
            float4 wv2 = *(const float4*)(W2u + I * 16 + g16 * 4);
            float4 cv  = *(const float4*)(b1u + I * 16 + g16 * 4);
            pj = fmaf(tanh_fast(acc[I][0] + cv.x), wv2.x, pj);
            pj = fmaf(tanh_fast(acc[I][1] + cv.y), wv2.y, pj);
            pj = fmaf(tanh_fast(acc[I][2] + cv.z), wv2.z, pj);
            pj = fmaf(tanh_fast(acc[I][3] + cv.w), wv2.w, pj);
        }
        pj += __shfl_xor(pj, 16, 64);
        pj += __shfl_xor(pj, 32, 64);
        u_pre = pj + b2u[0];
    }

#pragma unroll 1
    for (int t = 0; t < NSTEP; t++) {
        const float* w0 = Wg0 + (size_t)t * 3 * HD;
        const float* c0 = bg0 + (size_t)t * HD;
        const float* c1 = bg1 + (size_t)t * HD;
        const float* w2 = Wg2 + (size_t)t * HD * 3;
        const float* c2 = bg2 + (size_t)t * 3;

        float r = sqrtf(fmaf(xtx, xtx, fmaf(xty, xty, xtz * xtz)));
        float uu = xtz / r;
        uu = fminf(fmaxf(uu, -0.999999f), 0.999999f);
        float ca = sqrtf((1.0f - uu) * (1.0f + uu));
        float sa = -uu;
        float rho = sqrtf(fmaf(xtx, xtx, xty * xty));
        float cp = (rho > 0.0f) ? (xtx / rho) : 1.0f;
        float sp = (rho > 0.0f) ? (xty / rho) : 0.0f;
        float T00 = cp * ca, T01 = -sp, T02 = cp * sa;
        float T10 = sp * ca, T11 = cp,  T12 = sp * sa;
        float T20 = -sa,               T22 = ca;

        f32x4 acc[4];
#pragma unroll
        for (int I = 0; I < 4; I++) acc[I] = (f32x4){0.f, 0.f, 0.f, 0.f};
        mlp_h2_unpacked(xix, xiy, xiz, w0, c0, Wg1 + (size_t)t * HD * HD, lane, acc);

        float pj0 = 0.f, pj1 = 0.f, pj2 = 0.f;
#pragma unroll
        for (int I = 0; I < 4; I++) {
            const float* wp = w2 + 3 * (I * 16 + g16 * 4);
            float4 wa = *(const float4*)(wp);
            float4 wb = *(const float4*)(wp + 4);
            float4 wc = *(const float4*)(wp + 8);
            float4 cv = *(const float4*)(c1 + I * 16 + g16 * 4);
            float th0 = tanh_fast(acc[I][0] + cv.x);
            float th1 = tanh_fast(acc[I][1] + cv.y);
            float th2 = tanh_fast(acc[I][2] + cv.z);
            float th3 = tanh_fast(acc[I][3] + cv.w);
            pj0 = fmaf(th0, wa.x, pj0); pj1 = fmaf(th0, wa.y, pj1); pj2 = fmaf(th0, wa.z, pj2);
            pj0 = fmaf(th1, wa.w, pj0); pj1 = fmaf(th1, wb.x, pj1); pj2 = fmaf(th1, wb.y, pj2);
            pj0 = fmaf(th2, wb.z, pj0); pj1 = fmaf(th2, wb.w, pj1); pj2 = fmaf(th2, wc.x, pj2);
            pj0 = fmaf(th3, wc.y, pj0); pj1 = fmaf(th3, wc.z, pj1); pj2 = fmaf(th3, wc.w, pj2);
        }
        pj0 += __shfl_xor(pj0, 16, 64); pj0 += __shfl_xor(pj0, 32, 64);
        pj1 += __shfl_xor(pj1, 16, 64); pj1 += __shfl_xor(pj1, 32, 64);
        pj2 += __shfl_xor(pj2, 16, 64); pj2 += __shfl_xor(pj2, 32, 64);
        float gv0 = pj0 + c2[0];
        float gv1 = pj1 + c2[1];
        float gv2 = pj2 + c2[2];

        float M01 = fmaf(-sp, g00, cp * g01);
        float M11 = fmaf(-sp, g10, cp * g11);
        float M21 = fmaf(-sp, g20, cp * g21);
        float M02 = fmaf(g00, T02, fmaf(g01, T12, g02 * T22));
        float M12 = fmaf(g10, T02, fmaf(g11, T12, g12 * T22));
        float M22 = fmaf(g20, T02, fmaf(g21, T12, g22 * T22));
        float v1 = fmaf(gv0, M01, fmaf(gv1, M11, gv2 * M21));
        float v2 = fmaf(gv0, M02, fmaf(gv1, M12, gv2 * M22));

        const float2 dB = *(const float2*)(dBt + ((size_t)t * NB + p) * 2);
        float dB0 = dB.x, dB1 = dB.y;
        u_pre += fmaf(v1, dB1, -v2 * dB0);

        float s0d, c0d, s1d, c1d;
        __sincosf(dB0, &s0d, &c0d);
        __sincosf(dB1, &s1d, &c1d);
        float dx30 = fmaf(c0d, c1d, -1.0f);
        float dx31 = c0d * s1d;
        float dx32 = -s0d;

        float dX0 = fmaf(T00, dx30, fmaf(T01, dx31, T02 * dx32));
        float dX1 = fmaf(T10, dx30, fmaf(T11, dx31, T12 * dx32));
        float dX2 = fmaf(T20, dx30, T22 * dx32);

        xtx += dX0; xty += dX1; xtz += dX2;

        float xi0 = xix + fmaf(g00, dX0, fmaf(g01, dX1, g02 * dX2));
        float xi1 = xiy + fmaf(g10, dX0, fmaf(g11, dX1, g12 * dX2));
        float xi2 = xiz + fmaf(g20, dX0, fmaf(g21, dX1, g22 * dX2));

        float ri = sqrtf(fmaf(xi0, xi0, fmaf(xi1, xi1, xi2 * xi2)));
        bool outb = ri > RB;
        float n0 = xi0 / ri, n1 = xi1 / ri, n2 = xi2 / ri;
        float coef = 2.0f * (ri - RB);

        xix = outb ? fmaf(-coef, n0, xi0) : xi0;
        xiy = outb ? fmaf(-coef, n1, xi1) : xi1;
        xiz = outb ? fmaf(-coef, n2, xi2) : xi2;

        float mm0 = fmaf(n0, g00, fmaf(n1, g10, n2 * g20));
        float mm1 = fmaf(n0, g01, fmaf(n1, g11, n2 * g21));
        float mm2 = fmaf(n0, g02, fmaf(n1, g12, n2 * g22));
        float tn0 = 2.0f * n0, tn1 = 2.0f * n1, tn2 = 2.0f * n2;
        g00 = outb ? fmaf(-tn0, mm0, g00) : g00;
        g01 = outb ? fmaf(-tn0, mm1, g01) : g01;
        g02 = outb ? fmaf(-tn0, mm2, g02) : g02;
        g10 = outb ? fmaf(-tn1, mm0, g10) : g10;
        g11 = outb ? fmaf(-tn1, mm1, g11) : g11;
        g12 = outb ? fmaf(-tn1, mm2, g12) : g12;
        g20 = outb ? fmaf(-tn2, mm0, g20) : g20;
        g21 = outb ? fmaf(-tn2, mm1, g21) : g21;
        g22 = outb ? fmaf(-tn2, mm2, g22) : g22;
    }

    float u_rel = fmaf(xix, xix, fmaf(xiy, xiy, xiz * xiz));
    if (g16 == 0) {
        out[p] = u_pre;
        out[NB + p] = u_rel;
    }
}

extern "C" void kernel_launch(void* const* d_in, const int* in_sizes, int n_in,
                              void* d_out, int out_size, void* d_ws, size_t ws_size,
                              hipStream_t stream) {
    const float* xt0 = (const float*)d_in[0];
    const float* dBt = (const float*)d_in[1];
    const float* W0u = (const float*)d_in[2];
    const float* b0u = (const float*)d_in[3];
    const float* W1u = (const float*)d_in[4];
    const float* b1u = (const float*)d_in[5];
    const float* W2u = (const float*)d_in[6];
    const float* b2u = (const float*)d_in[7];
    const float* Wg0 = (const float*)d_in[8];
    const float* bg0 = (const float*)d_in[9];
    const float* Wg1 = (const float*)d_in[10];
    const float* bg1 = (const float*)d_in[11];
    const float* Wg2 = (const float*)d_in[12];
    const float* bg2 = (const float*)d_in[13];
    float* out = (float*)d_out;

    const size_t needed = (size_t)NSTEP * TBLK * sizeof(uint4);   // ~1.86 MB
    dim3 grid(NB * 4 / 256), block(256);
    if (ws_size >= needed && d_ws != nullptr) {
        uint4* wsB = (uint4*)d_ws;
        hipLaunchKernelGGL(prep_a1,  dim3(256), dim3(256), 0, stream, Wg1, wsB);
        hipLaunchKernelGGL(prep_a0,  dim3(128), dim3(256), 0, stream, Wg0, wsB);
        hipLaunchKernelGGL(prep_a2,  dim3(64),  dim3(256), 0, stream, Wg2, wsB);
        hipLaunchKernelGGL(prep_bias, dim3(64), dim3(256), 0, stream, bg0, bg1, wsB);
        hipLaunchKernelGGL(sde_fast, grid, block, 0, stream,
                           xt0, dBt, W0u, b0u, W1u, b1u, W2u, b2u,
                           bg2, (const uint4*)wsB, out);
    } else {
        hipLaunchKernelGGL(sde_ref, grid, block, 0, stream,
                           xt0, dBt, W0u, b0u, W1u, b1u, W2u, b2u,
                           Wg0, bg0, Wg1, bg1, Wg2, bg2, out);
    }
}

// Round 9
// 415.857 us; speedup vs baseline: 1.8995x; 1.1794x over previous
//
#include <hip/hip_runtime.h>

#define NB 65536
#define NSTEP 128
#define HD 64
#define RB 1.05f
#define SCALE 2.8853900817779268f   // 2*log2(e)
#define TBLK 928          // uint4 per time-step in the ws blob
#define OFF_A1 0          // 512 uint4 : SCALE*W1^T frags (pi-permuted rows)
#define OFF_A0 512        // 256 uint4 : SCALE*[W0^T; c0] frags (h1idx-permuted rows, c0 at k=3)
#define OFF_A2 768        // 128 uint4 : W2^T frags (rows 0..2, rest 0)
#define OFF_CB 896        // 32 uint4  : SCALE*c1 (64 f32, pi-permuted)

typedef __bf16 bf16x8 __attribute__((ext_vector_type(8)));
typedef float f32x4 __attribute__((ext_vector_type(4)));
typedef unsigned int uint;
typedef unsigned short ushort;

extern "C" __device__ float __ocml_native_exp2_f32(float);
#if __has_builtin(__builtin_amdgcn_exp2f)
#define EXP2(x) __builtin_amdgcn_exp2f(x)
#else
#define EXP2(x) __ocml_native_exp2_f32(x)
#endif

// tanh(x) = 1 - 2/(1+e^{2x})   (unscaled input; prologue/fallback only)
__device__ __forceinline__ float tanh_fast(float x) {
    float e2 = __expf(2.0f * x);
    return 1.0f - 2.0f * __builtin_amdgcn_rcpf(1.0f + e2);
}

// paired tanh on PRE-SCALED inputs z = 2*log2(e)*x; one v_rcp serves two tanh.
__device__ __forceinline__ void tanh2s(float za, float zb, float& ta, float& tb) {
    float ea = EXP2(za);
    float eb = EXP2(zb);
    float a1 = 1.0f + ea;
    float b1 = 1.0f + eb;
    float rp = __builtin_amdgcn_rcpf(a1 * b1);
    ta = fmaf(-2.0f * b1, rp, 1.0f);
    tb = fmaf(-2.0f * a1, rp, 1.0f);
}

// small-angle sincos (|x| <= ~0.55)
__device__ __forceinline__ void sincos_small(float x, float& s, float& c) {
    float x2 = x * x;
    s = fmaf(x2, fmaf(x2, 8.3333333e-3f, -0.16666667f), 1.0f) * x;
    c = fmaf(x2, fmaf(x2, fmaf(x2, -1.3888889e-3f, 4.1666668e-2f), -0.5f), 1.0f);
}

__device__ __forceinline__ uint pack_bf16_trunc(float a, float b) {
    return __builtin_amdgcn_perm(__float_as_uint(b), __float_as_uint(a), 0x07060302u);
}

__device__ __forceinline__ ushort bf16_rne(float f) {
    uint u = __float_as_uint(f);
    u += 0x7fffu + ((u >> 16) & 1u);
    return (ushort)(u >> 16);
}

// pi(I,s,j) == h1idx = (I>>1)*32 + s*8 + (I&1)*4 + j  (bijection on 0..63).
// GEMM-0 C slot (I, row, col) carries SCALE*h1pre[pi]; tanh2s of it is exactly
// GEMM-1's B-frag slot; same pi makes tanh2s(GEMM-1 C) the GEMM-2 B operand.

// ---- prep: A1 = SCALE*W1^T with pi-permuted rows ----
__global__ __launch_bounds__(256) void prep_a1(const float* __restrict__ Wg1,
                                               uint4* __restrict__ wsB) {
    int tid  = blockIdx.x * 256 + threadIdx.x;
    int lane = tid & 63;
    int I    = (tid >> 6) & 3;
    int kk   = (tid >> 8) & 1;
    int t    = tid >> 9;
    int rA   = lane & 15;
    int lrow = (I & 1) * 4 + (I >> 1) * 32 + (rA >> 2) * 8 + (rA & 3);
    int k0   = kk * 32 + ((lane >> 4) & 3) * 8;
    const float* src = Wg1 + ((size_t)t * HD + k0) * HD + lrow;
    ushort o[8];
#pragma unroll
    for (int e = 0; e < 8; e++) o[e] = bf16_rne(src[(size_t)e * HD] * SCALE);
    uint4 v;
    v.x = (uint)o[0] | ((uint)o[1] << 16);
    v.y = (uint)o[2] | ((uint)o[3] << 16);
    v.z = (uint)o[4] | ((uint)o[5] << 16);
    v.w = (uint)o[6] | ((uint)o[7] << 16);
    wsB[(size_t)t * TBLK + OFF_A1 + (kk * 4 + I) * 64 + lane] = v;
}

// ---- prep: A0 = SCALE*W0^T (h1idx-permuted rows); row k=3 holds SCALE*c0 ----
__global__ __launch_bounds__(256) void prep_a0(const float* __restrict__ Wg0,
                                               const float* __restrict__ bg0,
                                               uint4* __restrict__ wsB) {
    int tid  = blockIdx.x * 256 + threadIdx.x;
    int lane = tid & 63;
    int I    = (tid >> 6) & 3;
    int t    = tid >> 8;
    int m    = lane & 15;
    int kg   = (lane >> 4) & 3;
    int h    = (I >> 1) * 32 + (m >> 2) * 8 + (I & 1) * 4 + (m & 3);
    ushort o[8];
#pragma unroll
    for (int e = 0; e < 8; e++) {
        int k = kg * 8 + e;
        float v;
        if (k < 3)       v = SCALE * Wg0[((size_t)t * 3 + k) * HD + h];
        else if (k == 3) v = SCALE * bg0[(size_t)t * HD + h];
        else             v = 0.0f;
        o[e] = bf16_rne(v);
    }
    uint4 v;
    v.x = (uint)o[0] | ((uint)o[1] << 16);
    v.y = (uint)o[2] | ((uint)o[3] << 16);
    v.z = (uint)o[4] | ((uint)o[5] << 16);
    v.w = (uint)o[6] | ((uint)o[7] << 16);
    wsB[(size_t)t * TBLK + OFF_A0 + I * 64 + lane] = v;
}

// ---- prep: A2 = W2^T (rows 0..2 of 16, rest zero; UNSCALED) ----
__global__ __launch_bounds__(256) void prep_a2(const float* __restrict__ Wg2,
                                               uint4* __restrict__ wsB) {
    int tid  = blockIdx.x * 256 + threadIdx.x;
    int lane = tid & 63;
    int kk   = (tid >> 6) & 1;
    int t    = tid >> 7;
    int row  = lane & 15;
    int k0   = kk * 32 + ((lane >> 4) & 3) * 8;
    ushort o[8];
#pragma unroll
    for (int e = 0; e < 8; e++) {
        float v = (row < 3) ? Wg2[(size_t)t * HD * 3 + (size_t)(k0 + e) * 3 + row] : 0.0f;
        o[e] = bf16_rne(v);
    }
    uint4 v;
    v.x = (uint)o[0] | ((uint)o[1] << 16);
    v.y = (uint)o[2] | ((uint)o[3] << 16);
    v.z = (uint)o[4] | ((uint)o[5] << 16);
    v.w = (uint)o[6] | ((uint)o[7] << 16);
    wsB[(size_t)t * TBLK + OFF_A2 + kk * 64 + lane] = v;
}

// ---- prep: SCALE*c1, pi-permuted (64 f32 per step) ----
__global__ __launch_bounds__(256) void prep_bias(const float* __restrict__ bg1,
                                                 uint4* __restrict__ wsB) {
    int tid = blockIdx.x * 256 + threadIdx.x;   // t*128 + i
    int i   = tid & 127;
    int t   = tid >> 7;
    int r   = i & 63;
    int pi  = ((r >> 4) & 1) * 4 + ((r >> 5) & 1) * 32 + ((r >> 2) & 3) * 8 + (r & 3);
    float* dst = (float*)(wsB + (size_t)t * TBLK + OFF_CB);
    dst[i] = (i < 64) ? (SCALE * bg1[(size_t)t * HD + pi]) : 0.0f;
}

// --------- unpacked helper (u_pre0 prologue and the fallback kernel) ----------
__device__ __forceinline__ void mlp_h2_unpacked(float xx, float xy, float xz,
                                                const float* __restrict__ w0,
                                                const float* __restrict__ c0,
                                                const float* __restrict__ w1,
                                                int lane, f32x4* acc) {
    const int g16 = (lane >> 4) & 3;
    const int l15 = lane & 15;
#pragma unroll
    for (int kk = 0; kk < 2; kk++) {
        bf16x8 af[4];
#pragma unroll
        for (int I = 0; I < 4; I++) {
            uint pk[4];
#pragma unroll
            for (int ep = 0; ep < 4; ep++) {
                float f0 = w1[(kk * 32 + g16 * 8 + 2 * ep + 0) * HD + I * 16 + l15];
                float f1 = w1[(kk * 32 + g16 * 8 + 2 * ep + 1) * HD + I * 16 + l15];
                pk[ep] = (uint)bf16_rne(f0) | ((uint)bf16_rne(f1) << 16);
            }
            uint4 v; v.x = pk[0]; v.y = pk[1]; v.z = pk[2]; v.w = pk[3];
            af[I] = __builtin_bit_cast(bf16x8, v);
        }
        const float* wk = w0 + kk * 32 + g16 * 8;
        float4 wxa = *(const float4*)(wk);
        float4 wxb = *(const float4*)(wk + 4);
        float4 wya = *(const float4*)(wk + HD);
        float4 wyb = *(const float4*)(wk + HD + 4);
        float4 wza = *(const float4*)(wk + 2 * HD);
        float4 wzb = *(const float4*)(wk + 2 * HD + 4);
        const float* ck = c0 + kk * 32 + g16 * 8;
        float4 cva = *(const float4*)(ck);
        float4 cvb = *(const float4*)(ck + 4);
        float p0 = fmaf(xx, wxa.x, fmaf(xy, wya.x, fmaf(xz, wza.x, cva.x)));
        float p1 = fmaf(xx, wxa.y, fmaf(xy, wya.y, fmaf(xz, wza.y, cva.y)));
        float p2 = fmaf(xx, wxa.z, fmaf(xy, wya.z, fmaf(xz, wza.z, cva.z)));
        float p3 = fmaf(xx, wxa.w, fmaf(xy, wya.w, fmaf(xz, wza.w, cva.w)));
        float p4 = fmaf(xx, wxb.x, fmaf(xy, wyb.x, fmaf(xz, wzb.x, cvb.x)));
        float p5 = fmaf(xx, wxb.y, fmaf(xy, wyb.y, fmaf(xz, wzb.y, cvb.y)));
        float p6 = fmaf(xx, wxb.z, fmaf(xy, wyb.z, fmaf(xz, wzb.z, cvb.z)));
        float p7 = fmaf(xx, wxb.w, fmaf(xy, wyb.w, fmaf(xz, wzb.w, cvb.w)));
        uint4 bv;
        bv.x = pack_bf16_trunc(tanh_fast(p0), tanh_fast(p1));
        bv.y = pack_bf16_trunc(tanh_fast(p2), tanh_fast(p3));
        bv.z = pack_bf16_trunc(tanh_fast(p4), tanh_fast(p5));
        bv.w = pack_bf16_trunc(tanh_fast(p6), tanh_fast(p7));
        bf16x8 bf = __builtin_bit_cast(bf16x8, bv);
#pragma unroll
        for (int I = 0; I < 4; I++)
            acc[I] = __builtin_amdgcn_mfma_f32_16x16x32_bf16(af[I], bf, acc[I], 0, 0, 0);
    }
}

// ------------------------------ fast path ------------------------------
__global__ __launch_bounds__(256, 4) void sde_fast(
    const float* __restrict__ xt0,
    const float* __restrict__ dBt,
    const float* __restrict__ W0u, const float* __restrict__ b0u,
    const float* __restrict__ W1u, const float* __restrict__ b1u,
    const float* __restrict__ W2u, const float* __restrict__ b2u,
    const float* __restrict__ bg2,
    const uint4* __restrict__ wsB,
    float* __restrict__ out)
{
    const int tid  = threadIdx.x;
    const int lane = tid & 63;
    const int wv   = tid >> 6;
    const int g16  = (lane >> 4) & 3;
    const int l15  = lane & 15;
    const int p    = blockIdx.x * 64 + wv * 16 + l15;   // particle (4 lanes share)

    float xtx = xt0[p * 3 + 0];
    float xty = xt0[p * 3 + 1];
    float xtz = xt0[p * 3 + 2];
    float xix = xtx, xiy = xty, xiz = xtz;
    float g00 = 1.f, g01 = 0.f, g02 = 0.f;
    float g10 = 0.f, g11 = 1.f, g12 = 0.f;
    float g20 = 0.f, g21 = 0.f, g22 = 1.f;

    // ---- u_pre0 (once; unpacked path) ----
    float u_pre;
    {
        f32x4 acc[4];
#pragma unroll
        for (int I = 0; I < 4; I++) acc[I] = (f32x4){0.f, 0.f, 0.f, 0.f};
        mlp_h2_unpacked(xtx, xty, xtz, W0u, b0u, W1u, lane, acc);
        float pj = 0.f;
#pragma unroll
        for (int I = 0; I < 4; I++) {
            float4 wv2 = *(const float4*)(W2u + I * 16 + g16 * 4);
            float4 cv  = *(const float4*)(b1u + I * 16 + g16 * 4);
            pj = fmaf(tanh_fast(acc[I][0] + cv.x), wv2.x, pj);
            pj = fmaf(tanh_fast(acc[I][1] + cv.y), wv2.y, pj);
            pj = fmaf(tanh_fast(acc[I][2] + cv.z), wv2.z, pj);
            pj = fmaf(tanh_fast(acc[I][3] + cv.w), wv2.w, pj);
        }
        pj += __shfl_xor(pj, 16, 64);
        pj += __shfl_xor(pj, 32, 64);
        u_pre = pj + b2u[0];
    }

    const f32x4 zero4 = (f32x4){0.f, 0.f, 0.f, 0.f};

#pragma unroll 1
    for (int t = 0; t < NSTEP; t++) {
        const uint4* blob_t = wsB + (size_t)t * TBLK;
        const float* c1p_t  = (const float*)(blob_t + OFF_CB);
        const float* c2     = bg2 + (size_t)t * 3;

        // --- geometry via rsqrt; ca = rho/r (no sqrt) ---
        float d  = fmaf(xtx, xtx, fmaf(xty, xty, xtz * xtz));
        float rs = __builtin_amdgcn_rsqf(d);
        float uu = xtz * rs;
        uu = fminf(fmaxf(uu, -0.999999f), 0.999999f);
        float sa = -uu;
        float rho2 = fmaf(xtx, xtx, xty * xty);
        bool hasrho = rho2 > 0.0f;
        float rr = __builtin_amdgcn_rsqf(rho2);
        float cp = hasrho ? (xtx * rr) : 1.0f;
        float sp = hasrho ? (xty * rr) : 0.0f;
        float ca = hasrho ? (rho2 * rr * rs) : 1.4142135e-3f;
        float T00 = cp * ca, T01 = -sp, T02 = cp * sa;
        float T10 = sp * ca, T11 = cp,  T12 = sp * sa;
        float T20 = -sa,               T22 = ca;   // T21 = 0

        // --- GEMM-0: SCALE*(x@W0 + c0); c0 rides row k=3, B slot3 = 1.0 ---
        uint4 b0v;
        b0v.x = pack_bf16_trunc(xix, xiy);
        b0v.y = pack_bf16_trunc(xiz, 1.0f);
        b0v.z = 0u; b0v.w = 0u;
        bf16x8 b0 = __builtin_bit_cast(bf16x8, b0v);
        f32x4 acc0[4];
#pragma unroll
        for (int I = 0; I < 4; I++) {
            bf16x8 a0 = __builtin_bit_cast(bf16x8, blob_t[OFF_A0 + I * 64 + lane]);
            acc0[I] = __builtin_amdgcn_mfma_f32_16x16x32_bf16(a0, b0, zero4, 0, 0, 0);
        }

        // --- GEMM-1: SCALE*(h1@W1 + c1); tanh2s(acc0) is the B operand ---
        f32x4 acc[4];
#pragma unroll
        for (int I = 0; I < 4; I++) {
            float4 cv = *(const float4*)(c1p_t + I * 16 + g16 * 4);
            acc[I] = (f32x4){cv.x, cv.y, cv.z, cv.w};
        }
#pragma unroll
        for (int kk = 0; kk < 2; kk++) {
            float t0, t1, t2, t3, t4, t5, t6, t7;
            tanh2s(acc0[kk * 2 + 0][0], acc0[kk * 2 + 0][1], t0, t1);
            tanh2s(acc0[kk * 2 + 0][2], acc0[kk * 2 + 0][3], t2, t3);
            tanh2s(acc0[kk * 2 + 1][0], acc0[kk * 2 + 1][1], t4, t5);
            tanh2s(acc0[kk * 2 + 1][2], acc0[kk * 2 + 1][3], t6, t7);
            uint4 bv;
            bv.x = pack_bf16_trunc(t0, t1);
            bv.y = pack_bf16_trunc(t2, t3);
            bv.z = pack_bf16_trunc(t4, t5);
            bv.w = pack_bf16_trunc(t6, t7);
            bf16x8 bf = __builtin_bit_cast(bf16x8, bv);
#pragma unroll
            for (int I = 0; I < 4; I++) {
                bf16x8 af = __builtin_bit_cast(bf16x8, blob_t[OFF_A1 + (kk * 4 + I) * 64 + lane]);
                acc[I] = __builtin_amdgcn_mfma_f32_16x16x32_bf16(af, bf, acc[I], 0, 0, 0);
            }
        }

        // --- GEMM-2: g = tanh(h2)^T @ W2 (A2 unscaled) ---
        f32x4 acc2 = zero4;
#pragma unroll
        for (int half = 0; half < 2; half++) {
            float t0, t1, t2, t3, t4, t5, t6, t7;
            tanh2s(acc[2 * half + 0][0], acc[2 * half + 0][1], t0, t1);
            tanh2s(acc[2 * half + 0][2], acc[2 * half + 0][3], t2, t3);
            tanh2s(acc[2 * half + 1][0], acc[2 * half + 1][1], t4, t5);
            tanh2s(acc[2 * half + 1][2], acc[2 * half + 1][3], t6, t7);
            uint4 bv;
            bv.x = pack_bf16_trunc(t0, t1);
            bv.y = pack_bf16_trunc(t2, t3);
            bv.z = pack_bf16_trunc(t4, t5);
            bv.w = pack_bf16_trunc(t6, t7);
            bf16x8 bf = __builtin_bit_cast(bf16x8, bv);
            bf16x8 a2 = __builtin_bit_cast(bf16x8, blob_t[OFF_A2 + half * 64 + lane]);
            acc2 = __builtin_amdgcn_mfma_f32_16x16x32_bf16(a2, bf, acc2, 0, 0, 0);
        }
        float gv0 = __shfl(acc2[0], l15, 64) + c2[0];
        float gv1 = __shfl(acc2[1], l15, 64) + c2[1];
        float gv2 = __shfl(acc2[2], l15, 64) + c2[2];

        // --- v = g @ (gt @ Ti), columns 1,2 only ---
        float M01 = fmaf(-sp, g00, cp * g01);
        float M11 = fmaf(-sp, g10, cp * g11);
        float M21 = fmaf(-sp, g20, cp * g21);
        float M02 = fmaf(g00, T02, fmaf(g01, T12, g02 * T22));
        float M12 = fmaf(g10, T02, fmaf(g11, T12, g12 * T22));
        float M22 = fmaf(g20, T02, fmaf(g21, T12, g22 * T22));
        float v1 = fmaf(gv0, M01, fmaf(gv1, M11, gv2 * M21));
        float v2 = fmaf(gv0, M02, fmaf(gv1, M12, gv2 * M22));

        const float2 dB = *(const float2*)(dBt + ((size_t)t * NB + p) * 2);
        float dB0 = dB.x, dB1 = dB.y;
        u_pre += fmaf(v1, dB1, -v2 * dB0);

        // --- dX3 / dX ---
        float s0d, c0d, s1d, c1d;
        sincos_small(dB0, s0d, c0d);
        sincos_small(dB1, s1d, c1d);
        float dx30 = fmaf(c0d, c1d, -1.0f);
        float dx31 = c0d * s1d;
        float dx32 = -s0d;

        float dX0 = fmaf(T00, dx30, fmaf(T01, dx31, T02 * dx32));
        float dX1 = fmaf(T10, dx30, fmaf(T11, dx31, T12 * dx32));
        float dX2 = fmaf(T20, dx30, T22 * dx32);

        xtx += dX0; xty += dX1; xtz += dX2;

        float xi0 = xix + fmaf(g00, dX0, fmaf(g01, dX1, g02 * dX2));
        float xi1 = xiy + fmaf(g10, dX0, fmaf(g11, dX1, g12 * dX2));
        float xi2 = xiz + fmaf(g20, dX0, fmaf(g21, dX1, g22 * dX2));

        // --- reflection: select-free updates (coef and weight gated) ---
        float ri2 = fmaf(xi0, xi0, fmaf(xi1, xi1, xi2 * xi2));
        float rs2 = __builtin_amdgcn_rsqf(ri2);
        float ri  = ri2 * rs2;
        bool outb = ri > RB;
        float n0 = xi0 * rs2, n1 = xi1 * rs2, n2 = xi2 * rs2;
        float coefs = outb ? (2.0f * (ri - RB)) : 0.0f;

        xix = fmaf(-coefs, n0, xi0);
        xiy = fmaf(-coefs, n1, xi1);
        xiz = fmaf(-coefs, n2, xi2);

        float mm0 = fmaf(n0, g00, fmaf(n1, g10, n2 * g20));
        float mm1 = fmaf(n0, g01, fmaf(n1, g11, n2 * g21));
        float mm2 = fmaf(n0, g02, fmaf(n1, g12, n2 * g22));
        float tw  = outb ? 2.0f : 0.0f;
        float tn0 = tw * n0, tn1 = tw * n1, tn2 = tw * n2;
        g00 = fmaf(-tn0, mm0, g00);
        g01 = fmaf(-tn0, mm1, g01);
        g02 = fmaf(-tn0, mm2, g02);
        g10 = fmaf(-tn1, mm0, g10);
        g11 = fmaf(-tn1, mm1, g11);
        g12 = fmaf(-tn1, mm2, g12);
        g20 = fmaf(-tn2, mm0, g20);
        g21 = fmaf(-tn2, mm1, g21);
        g22 = fmaf(-tn2, mm2, g22);
    }

    float u_rel = fmaf(xix, xix, fmaf(xiy, xiy, xiz * xiz));
    if (g16 == 0) {
        out[p] = u_pre;
        out[NB + p] = u_rel;
    }
}

// ------------------- fallback (R3-style kernel, unpacked weights) -------------------
__global__ __launch_bounds__(256, 4) void sde_ref(
    const float* __restrict__ xt0,
    const float* __restrict__ dBt,
    const float* __restrict__ W0u, const float* __restrict__ b0u,
    const float* __restrict__ W1u, const float* __restrict__ b1u,
    const float* __restrict__ W2u, const float* __restrict__ b2u,
    const float* __restrict__ Wg0, const float* __restrict__ bg0,
    const float* __restrict__ Wg1, const float* __restrict__ bg1,
    const float* __restrict__ Wg2, const float* __restrict__ bg2,
    float* __restrict__ out)
{
    const int tid  = threadIdx.x;
    const int lane = tid & 63;
    const int wv   = tid >> 6;
    const int g16  = (lane >> 4) & 3;
    const int l15  = lane & 15;
    const int p    = blockIdx.x * 64 + wv * 16 + l15;

    float xtx = xt0[p * 3 + 0];
    float xty = xt0[p * 3 + 1];
    float xtz = xt0[p * 3 + 2];
    float xix = xtx, xiy = xty, xiz = xtz;
    float g00 = 1.f, g01 = 0.f, g02 = 0.f;
    float g10 = 0.f, g11 = 1.f, g12 = 0.f;
    float g20 = 0.f, g21 = 0.f, g22 = 1.f;

    float u_pre;
    {
        f32x4 acc[4];
#pragma unroll
        for (int I = 0; I < 4; I++) acc[I] = (f32x4){0.f, 0.f, 0.f, 0.f};
        mlp_h2_unpacked(xtx, xty, xtz, W0u, b0u, W1u, lane, acc);
        float pj = 0.f;
#pragma unroll
        for (int I = 0; I < 4; I++) {
            float4 wv2 = *(const float4*)(W2u + I * 16 + g16 * 4);
            float4 cv  = *(const float4*)(b1u + I * 16 + g16 * 4);
            pj = fmaf(tanh_fast(acc[I][0] + cv.x), wv2.x, pj);
            pj = fmaf(tanh_fast(acc[I][1] + cv.y), wv2.y, pj);
            pj = fmaf(tanh_fast(acc[I][2] + cv.z), wv2.z, pj);
            pj = fmaf(tanh_fast(acc[I][3] + cv.w), wv2.w, pj);
        }
        pj += __shfl_xor(pj, 16, 64);
        pj += __shfl_xor(pj, 32, 64);
        u_pre = pj + b2u[0];
    }

#pragma unroll 1
    for (int t = 0; t < NSTEP; t++) {
        const float* w0 = Wg0 + (size_t)t * 3 * HD;
        const float* c0 = bg0 + (size_t)t * HD;
        const float* c1 = bg1 + (size_t)t * HD;
        const float* w2 = Wg2 + (size_t)t * HD * 3;
        const float* c2 = bg2 + (size_t)t * 3;

        float r = sqrtf(fmaf(xtx, xtx, fmaf(xty, xty, xtz * xtz)));
        float uu = xtz / r;
        uu = fminf(fmaxf(uu, -0.999999f), 0.999999f);
        float ca = sqrtf((1.0f - uu) * (1.0f + uu));
        float sa = -uu;
        float rho = sqrtf(fmaf(xtx, xtx, xty * xty));
        float cp = (rho > 0.0f) ? (xtx / rho) : 1.0f;
        float sp = (rho > 0.0f) ? (xty / rho) : 0.0f;
        float T00 = cp * ca, T01 = -sp, T02 = cp * sa;
        float T10 = sp * ca, T11 = cp,  T12 = sp * sa;
        float T20 = -sa,               T22 = ca;

        f32x4 acc[4];
#pragma unroll
        for (int I = 0; I < 4; I++) acc[I] = (f32x4){0.f, 0.f, 0.f, 0.f};
        mlp_h2_unpacked(xix, xiy, xiz, w0, c0, Wg1 + (size_t)t * HD * HD, lane, acc);

        float pj0 = 0.f, pj1 = 0.f, pj2 = 0.f;
#pragma unroll
        for (int I = 0; I < 4; I++) {
            const float* wp = w2 + 3 * (I * 16 + g16 * 4);
            float4 wa = *(const float4*)(wp);
            float4 wb = *(const float4*)(wp + 4);
            float4 wc = *(const float4*)(wp + 8);
            float4 cv = *(const float4*)(c1 + I * 16 + g16 * 4);
            float th0 = tanh_fast(acc[I][0] + cv.x);
            float th1 = tanh_fast(acc[I][1] + cv.y);
            float th2 = tanh_fast(acc[I][2] + cv.z);
            float th3 = tanh_fast(acc[I][3] + cv.w);
            pj0 = fmaf(th0, wa.x, pj0); pj1 = fmaf(th0, wa.y, pj1); pj2 = fmaf(th0, wa.z, pj2);
            pj0 = fmaf(th1, wa.w, pj0); pj1 = fmaf(th1, wb.x, pj1); pj2 = fmaf(th1, wb.y, pj2);
            pj0 = fmaf(th2, wb.z, pj0); pj1 = fmaf(th2, wb.w, pj1); pj2 = fmaf(th2, wc.x, pj2);
            pj0 = fmaf(th3, wc.y, pj0); pj1 = fmaf(th3, wc.z, pj1); pj2 = fmaf(th3, wc.w, pj2);
        }
        pj0 += __shfl_xor(pj0, 16, 64); pj0 += __shfl_xor(pj0, 32, 64);
        pj1 += __shfl_xor(pj1, 16, 64); pj1 += __shfl_xor(pj1, 32, 64);
        pj2 += __shfl_xor(pj2, 16, 64); pj2 += __shfl_xor(pj2, 32, 64);
        float gv0 = pj0 + c2[0];
        float gv1 = pj1 + c2[1];
        float gv2 = pj2 + c2[2];

        float M01 = fmaf(-sp, g00, cp * g01);
        float M11 = fmaf(-sp, g10, cp * g11);
        float M21 = fmaf(-sp, g20, cp * g21);
        float M02 = fmaf(g00, T02, fmaf(g01, T12, g02 * T22));
        float M12 = fmaf(g10, T02, fmaf(g11, T12, g12 * T22));
        float M22 = fmaf(g20, T02, fmaf(g21, T12, g22 * T22));
        float v1 = fmaf(gv0, M01, fmaf(gv1, M11, gv2 * M21));
        float v2 = fmaf(gv0, M02, fmaf(gv1, M12, gv2 * M22));

        const float2 dB = *(const float2*)(dBt + ((size_t)t * NB + p) * 2);
        float dB0 = dB.x, dB1 = dB.y;
        u_pre += fmaf(v1, dB1, -v2 * dB0);

        float s0d, c0d, s1d, c1d;
        __sincosf(dB0, &s0d, &c0d);
        __sincosf(dB1, &s1d, &c1d);
        float dx30 = fmaf(c0d, c1d, -1.0f);
        float dx31 = c0d * s1d;
        float dx32 = -s0d;

        float dX0 = fmaf(T00, dx30, fmaf(T01, dx31, T02 * dx32));
        float dX1 = fmaf(T10, dx30, fmaf(T11, dx31, T12 * dx32));
        float dX2 = fmaf(T20, dx30, T22 * dx32);

        xtx += dX0; xty += dX1; xtz += dX2;

        float xi0 = xix + fmaf(g00, dX0, fmaf(g01, dX1, g02 * dX2));
        float xi1 = xiy + fmaf(g10, dX0, fmaf(g11, dX1, g12 * dX2));
        float xi2 = xiz + fmaf(g20, dX0, fmaf(g21, dX1, g22 * dX2));

        float ri = sqrtf(fmaf(xi0, xi0, fmaf(xi1, xi1, xi2 * xi2)));
        bool outb = ri > RB;
        float n0 = xi0 / ri, n1 = xi1 / ri, n2 = xi2 / ri;
        float coef = 2.0f * (ri - RB);

        xix = outb ? fmaf(-coef, n0, xi0) : xi0;
        xiy = outb ? fmaf(-coef, n1, xi1) : xi1;
        xiz = outb ? fmaf(-coef, n2, xi2) : xi2;

        float mm0 = fmaf(n0, g00, fmaf(n1, g10, n2 * g20));
        float mm1 = fmaf(n0, g01, fmaf(n1, g11, n2 * g21));
        float mm2 = fmaf(n0, g02, fmaf(n1, g12, n2 * g22));
        float tn0 = 2.0f * n0, tn1 = 2.0f * n1, tn2 = 2.0f * n2;
        g00 = outb ? fmaf(-tn0, mm0, g00) : g00;
        g01 = outb ? fmaf(-tn0, mm1, g01) : g01;
        g02 = outb ? fmaf(-tn0, mm2, g02) : g02;
        g10 = outb ? fmaf(-tn1, mm0, g10) : g10;
        g11 = outb ? fmaf(-tn1, mm1, g11) : g11;
        g12 = outb ? fmaf(-tn1, mm2, g12) : g12;
        g20 = outb ? fmaf(-tn2, mm0, g20) : g20;
        g21 = outb ? fmaf(-tn2, mm1, g21) : g21;
        g22 = outb ? fmaf(-tn2, mm2, g22) : g22;
    }

    float u_rel = fmaf(xix, xix, fmaf(xiy, xiy, xiz * xiz));
    if (g16 == 0) {
        out[p] = u_pre;
        out[NB + p] = u_rel;
    }
}

extern "C" void kernel_launch(void* const* d_in, const int* in_sizes, int n_in,
                              void* d_out, int out_size, void* d_ws, size_t ws_size,
                              hipStream_t stream) {
    const float* xt0 = (const float*)d_in[0];
    const float* dBt = (const float*)d_in[1];
    const float* W0u = (const float*)d_in[2];
    const float* b0u = (const float*)d_in[3];
    const float* W1u = (const float*)d_in[4];
    const float* b1u = (const float*)d_in[5];
    const float* W2u = (const float*)d_in[6];
    const float* b2u = (const float*)d_in[7];
    const float* Wg0 = (const float*)d_in[8];
    const float* bg0 = (const float*)d_in[9];
    const float* Wg1 = (const float*)d_in[10];
    const float* bg1 = (const float*)d_in[11];
    const float* Wg2 = (const float*)d_in[12];
    const float* bg2 = (const float*)d_in[13];
    float* out = (float*)d_out;

    const size_t needed = (size_t)NSTEP * TBLK * sizeof(uint4);   // ~1.86 MB
    dim3 grid(NB * 4 / 256), block(256);
    if (ws_size >= needed && d_ws != nullptr) {
        uint4* wsB = (uint4*)d_ws;
        hipLaunchKernelGGL(prep_a1,  dim3(256), dim3(256), 0, stream, Wg1, wsB);
        hipLaunchKernelGGL(prep_a0,  dim3(128), dim3(256), 0, stream, Wg0, bg0, wsB);
        hipLaunchKernelGGL(prep_a2,  dim3(64),  dim3(256), 0, stream, Wg2, wsB);
        hipLaunchKernelGGL(prep_bias, dim3(64), dim3(256), 0, stream, bg1, wsB);
        hipLaunchKernelGGL(sde_fast, grid, block, 0, stream,
                           xt0, dBt, W0u, b0u, W1u, b1u, W2u, b2u,
                           bg2, (const uint4*)wsB, out);
    } else {
        hipLaunchKernelGGL(sde_ref, grid, block, 0, stream,
                           xt0, dBt, W0u, b0u, W1u, b1u, W2u, b2u,
                           Wg0, bg0, Wg1, bg1, Wg2, bg2, out);
    }
}

// Round 10
// 385.112 us; speedup vs baseline: 2.0511x; 1.0798x over previous
//
#include <hip/hip_runtime.h>

#define NB 65536
#define NSTEP 128
#define HD 64
#define RB 1.05f
#define SCALE 2.8853900817779268f   // 2*log2(e)
#define TBLK 928          // uint4 per time-step in the ws blob (slots 0..NSTEP; slot NSTEP = u-weights)
#define OFF_A1 0          // 512 uint4 : SCALE*W1^T frags (pi-permuted rows)
#define OFF_A0 512        // 256 uint4 : SCALE*[W0^T; c0] frags (h1idx-permuted rows, c0 at k=3)
#define OFF_A2 768        // 128 uint4 : W2^T frags, ROW-REPLICATED (row 4q+j = W2 col j; j<3)
#define OFF_CB 896        // 32 uint4  : SCALE*c1 (64 f32, pi-permuted)

typedef __bf16 bf16x8 __attribute__((ext_vector_type(8)));
typedef float f32x4 __attribute__((ext_vector_type(4)));
typedef unsigned int uint;
typedef unsigned short ushort;

extern "C" __device__ float __ocml_native_exp2_f32(float);
#if __has_builtin(__builtin_amdgcn_exp2f)
#define EXP2(x) __builtin_amdgcn_exp2f(x)
#else
#define EXP2(x) __ocml_native_exp2_f32(x)
#endif

__device__ __forceinline__ float tanh_fast(float x) {
    float e2 = __expf(2.0f * x);
    return 1.0f - 2.0f * __builtin_amdgcn_rcpf(1.0f + e2);
}

// paired tanh on PRE-SCALED inputs z = 2*log2(e)*x; one v_rcp serves two tanh.
__device__ __forceinline__ void tanh2s(float za, float zb, float& ta, float& tb) {
    float ea = EXP2(za);
    float eb = EXP2(zb);
    float a1 = 1.0f + ea;
    float b1 = 1.0f + eb;
    float rp = __builtin_amdgcn_rcpf(a1 * b1);
    ta = fmaf(-2.0f * b1, rp, 1.0f);
    tb = fmaf(-2.0f * a1, rp, 1.0f);
}

__device__ __forceinline__ void sincos_small(float x, float& s, float& c) {
    float x2 = x * x;
    s = fmaf(x2, fmaf(x2, 8.3333333e-3f, -0.16666667f), 1.0f) * x;
    c = fmaf(x2, fmaf(x2, fmaf(x2, -1.3888889e-3f, 4.1666668e-2f), -0.5f), 1.0f);
}

__device__ __forceinline__ uint pack_bf16_trunc(float a, float b) {
    return __builtin_amdgcn_perm(__float_as_uint(b), __float_as_uint(a), 0x07060302u);
}

__device__ __forceinline__ ushort bf16_rne(float f) {
    uint u = __float_as_uint(f);
    u += 0x7fffu + ((u >> 16) & 1u);
    return (ushort)(u >> 16);
}

// pi(I,s,j) == h1idx = (I>>1)*32 + s*8 + (I&1)*4 + j  (bijection on 0..63)

// ---- prep: A1 = SCALE*W1^T with pi-permuted rows (slot NSTEP = W1u) ----
__global__ __launch_bounds__(256) void prep_a1(const float* __restrict__ Wg1,
                                               const float* __restrict__ W1u,
                                               uint4* __restrict__ wsB) {
    int tid  = blockIdx.x * 256 + threadIdx.x;
    int lane = tid & 63;
    int I    = (tid >> 6) & 3;
    int kk   = (tid >> 8) & 1;
    int t    = tid >> 9;
    if (t > NSTEP) return;
    int rA   = lane & 15;
    int lrow = (I & 1) * 4 + (I >> 1) * 32 + (rA >> 2) * 8 + (rA & 3);
    int k0   = kk * 32 + ((lane >> 4) & 3) * 8;
    const float* base = (t < NSTEP) ? (Wg1 + (size_t)t * HD * HD) : W1u;
    const float* src  = base + (size_t)k0 * HD + lrow;
    ushort o[8];
#pragma unroll
    for (int e = 0; e < 8; e++) o[e] = bf16_rne(src[(size_t)e * HD] * SCALE);
    uint4 v;
    v.x = (uint)o[0] | ((uint)o[1] << 16);
    v.y = (uint)o[2] | ((uint)o[3] << 16);
    v.z = (uint)o[4] | ((uint)o[5] << 16);
    v.w = (uint)o[6] | ((uint)o[7] << 16);
    wsB[(size_t)t * TBLK + OFF_A1 + (kk * 4 + I) * 64 + lane] = v;
}

// ---- prep: A0 = SCALE*W0^T (h1idx-permuted rows); row k=3 holds SCALE*c0 ----
__global__ __launch_bounds__(256) void prep_a0(const float* __restrict__ Wg0,
                                               const float* __restrict__ bg0,
                                               const float* __restrict__ W0u,
                                               const float* __restrict__ b0u,
                                               uint4* __restrict__ wsB) {
    int tid  = blockIdx.x * 256 + threadIdx.x;
    int lane = tid & 63;
    int I    = (tid >> 6) & 3;
    int t    = tid >> 8;
    if (t > NSTEP) return;
    int m    = lane & 15;
    int kg   = (lane >> 4) & 3;
    int h    = (I >> 1) * 32 + (m >> 2) * 8 + (I & 1) * 4 + (m & 3);
    ushort o[8];
#pragma unroll
    for (int e = 0; e < 8; e++) {
        int k = kg * 8 + e;
        float v = 0.0f;
        if (k < 3)       v = SCALE * ((t < NSTEP) ? Wg0[((size_t)t * 3 + k) * HD + h]
                                                  : W0u[(size_t)k * HD + h]);
        else if (k == 3) v = SCALE * ((t < NSTEP) ? bg0[(size_t)t * HD + h] : b0u[h]);
        o[e] = bf16_rne(v);
    }
    uint4 v;
    v.x = (uint)o[0] | ((uint)o[1] << 16);
    v.y = (uint)o[2] | ((uint)o[3] << 16);
    v.z = (uint)o[4] | ((uint)o[5] << 16);
    v.w = (uint)o[6] | ((uint)o[7] << 16);
    wsB[(size_t)t * TBLK + OFF_A0 + I * 64 + lane] = v;
}

// ---- prep: A2 = W2^T ROW-REPLICATED (row 4q+j holds W2 col j; slot NSTEP = W2u at j=0) ----
__global__ __launch_bounds__(256) void prep_a2(const float* __restrict__ Wg2,
                                               const float* __restrict__ W2u,
                                               uint4* __restrict__ wsB) {
    int tid  = blockIdx.x * 256 + threadIdx.x;
    int lane = tid & 63;
    int kk   = (tid >> 6) & 1;
    int t    = tid >> 7;
    if (t > NSTEP) return;
    int row  = lane & 15;
    int j    = row & 3;
    int k0   = kk * 32 + ((lane >> 4) & 3) * 8;
    ushort o[8];
#pragma unroll
    for (int e = 0; e < 8; e++) {
        float v = 0.0f;
        if (j < 3) {
            if (t < NSTEP) v = Wg2[(size_t)t * HD * 3 + (size_t)(k0 + e) * 3 + j];
            else           v = (j == 0) ? W2u[k0 + e] : 0.0f;
        }
        o[e] = bf16_rne(v);
    }
    uint4 v;
    v.x = (uint)o[0] | ((uint)o[1] << 16);
    v.y = (uint)o[2] | ((uint)o[3] << 16);
    v.z = (uint)o[4] | ((uint)o[5] << 16);
    v.w = (uint)o[6] | ((uint)o[7] << 16);
    wsB[(size_t)t * TBLK + OFF_A2 + kk * 64 + lane] = v;
}

// ---- prep: SCALE*c1, pi-permuted (slot NSTEP = b1u) ----
__global__ __launch_bounds__(256) void prep_bias(const float* __restrict__ bg1,
                                                 const float* __restrict__ b1u,
                                                 uint4* __restrict__ wsB) {
    int tid = blockIdx.x * 256 + threadIdx.x;   // t*128 + i
    int i   = tid & 127;
    int t   = tid >> 7;
    if (t > NSTEP) return;
    int r   = i & 63;
    int pi  = ((r >> 4) & 1) * 4 + ((r >> 5) & 1) * 32 + ((r >> 2) & 3) * 8 + (r & 3);
    float* dst = (float*)(wsB + (size_t)t * TBLK + OFF_CB);
    float v = 0.0f;
    if (i < 64) v = SCALE * ((t < NSTEP) ? bg1[(size_t)t * HD + pi] : b1u[pi]);
    dst[i] = v;
}

// ---- the 3-GEMM MLP chain (R9 machinery); returns acc2 with gv_j in regs 0..2 of EVERY lane ----
__device__ __forceinline__ f32x4 mlp_chain(float xx, float xy, float xz,
                                           const uint4* __restrict__ blob_t,
                                           int lane, int g16) {
    const f32x4 zero4 = (f32x4){0.f, 0.f, 0.f, 0.f};
    uint4 b0v;
    b0v.x = pack_bf16_trunc(xx, xy);
    b0v.y = pack_bf16_trunc(xz, 1.0f);
    b0v.z = 0u; b0v.w = 0u;
    bf16x8 b0 = __builtin_bit_cast(bf16x8, b0v);

    uint4 a0v0 = {0u,0u,0u,0u}, a0v1 = {0u,0u,0u,0u}, a0v2 = {0u,0u,0u,0u}, a0v3 = {0u,0u,0u,0u};
    if (g16 == 0) {
        a0v0 = blob_t[OFF_A0 + 0 * 64 + lane];
        a0v1 = blob_t[OFF_A0 + 1 * 64 + lane];
        a0v2 = blob_t[OFF_A0 + 2 * 64 + lane];
        a0v3 = blob_t[OFF_A0 + 3 * 64 + lane];
    }
    f32x4 acc0[4];
    acc0[0] = __builtin_amdgcn_mfma_f32_16x16x32_bf16(__builtin_bit_cast(bf16x8, a0v0), b0, zero4, 0, 0, 0);
    acc0[1] = __builtin_amdgcn_mfma_f32_16x16x32_bf16(__builtin_bit_cast(bf16x8, a0v1), b0, zero4, 0, 0, 0);
    acc0[2] = __builtin_amdgcn_mfma_f32_16x16x32_bf16(__builtin_bit_cast(bf16x8, a0v2), b0, zero4, 0, 0, 0);
    acc0[3] = __builtin_amdgcn_mfma_f32_16x16x32_bf16(__builtin_bit_cast(bf16x8, a0v3), b0, zero4, 0, 0, 0);

    const float* c1p_t = (const float*)(blob_t + OFF_CB);
    f32x4 acc[4];
#pragma unroll
    for (int I = 0; I < 4; I++) {
        float4 cv = *(const float4*)(c1p_t + I * 16 + g16 * 4);
        acc[I] = (f32x4){cv.x, cv.y, cv.z, cv.w};
    }
#pragma unroll
    for (int kk = 0; kk < 2; kk++) {
        float t0, t1, t2, t3, t4, t5, t6, t7;
        tanh2s(acc0[kk * 2 + 0][0], acc0[kk * 2 + 0][1], t0, t1);
        tanh2s(acc0[kk * 2 + 0][2], acc0[kk * 2 + 0][3], t2, t3);
        tanh2s(acc0[kk * 2 + 1][0], acc0[kk * 2 + 1][1], t4, t5);
        tanh2s(acc0[kk * 2 + 1][2], acc0[kk * 2 + 1][3], t6, t7);
        uint4 bv;
        bv.x = pack_bf16_trunc(t0, t1);
        bv.y = pack_bf16_trunc(t2, t3);
        bv.z = pack_bf16_trunc(t4, t5);
        bv.w = pack_bf16_trunc(t6, t7);
        bf16x8 bf = __builtin_bit_cast(bf16x8, bv);
#pragma unroll
        for (int I = 0; I < 4; I++) {
            bf16x8 af = __builtin_bit_cast(bf16x8, blob_t[OFF_A1 + (kk * 4 + I) * 64 + lane]);
            acc[I] = __builtin_amdgcn_mfma_f32_16x16x32_bf16(af, bf, acc[I], 0, 0, 0);
        }
    }
    f32x4 acc2 = zero4;
#pragma unroll
    for (int half = 0; half < 2; half++) {
        float t0, t1, t2, t3, t4, t5, t6, t7;
        tanh2s(acc[2 * half + 0][0], acc[2 * half + 0][1], t0, t1);
        tanh2s(acc[2 * half + 0][2], acc[2 * half + 0][3], t2, t3);
        tanh2s(acc[2 * half + 1][0], acc[2 * half + 1][1], t4, t5);
        tanh2s(acc[2 * half + 1][2], acc[2 * half + 1][3], t6, t7);
        uint4 bv;
        bv.x = pack_bf16_trunc(t0, t1);
        bv.y = pack_bf16_trunc(t2, t3);
        bv.z = pack_bf16_trunc(t4, t5);
        bv.w = pack_bf16_trunc(t6, t7);
        bf16x8 bf = __builtin_bit_cast(bf16x8, bv);
        bf16x8 a2 = __builtin_bit_cast(bf16x8, blob_t[OFF_A2 + half * 64 + lane]);
        acc2 = __builtin_amdgcn_mfma_f32_16x16x32_bf16(a2, bf, acc2, 0, 0, 0);
    }
    return acc2;
}

// ---------------- producer: state recurrence only (bit-identical to R9 state path) ----------------
__global__ __launch_bounds__(256) void sde_state(
    const float* __restrict__ xt0, const float* __restrict__ dBt,
    float4* __restrict__ xiw4, float2* __restrict__ w2f,
    float* __restrict__ out)
{
    int p = blockIdx.x * 256 + threadIdx.x;
    float xtx = xt0[p * 3 + 0];
    float xty = xt0[p * 3 + 1];
    float xtz = xt0[p * 3 + 2];
    float xix = xtx, xiy = xty, xiz = xtz;
    float g00 = 1.f, g01 = 0.f, g02 = 0.f;
    float g10 = 0.f, g11 = 1.f, g12 = 0.f;
    float g20 = 0.f, g21 = 0.f, g22 = 1.f;

    float2 dBa = *(const float2*)(dBt + (size_t)p * 2);
    float2 dBb = *(const float2*)(dBt + ((size_t)NB + p) * 2);

#pragma unroll 1
    for (int t = 0; t < NSTEP; t++) {
        float d  = fmaf(xtx, xtx, fmaf(xty, xty, xtz * xtz));
        float rs = __builtin_amdgcn_rsqf(d);
        float uu = xtz * rs;
        uu = fminf(fmaxf(uu, -0.999999f), 0.999999f);
        float sa = -uu;
        float rho2 = fmaf(xtx, xtx, xty * xty);
        bool hasrho = rho2 > 0.0f;
        float rr = __builtin_amdgcn_rsqf(rho2);
        float cp = hasrho ? (xtx * rr) : 1.0f;
        float sp = hasrho ? (xty * rr) : 0.0f;
        float ca = hasrho ? (rho2 * rr * rs) : 1.4142135e-3f;
        float T00 = cp * ca, T01 = -sp, T02 = cp * sa;
        float T10 = sp * ca, T11 = cp,  T12 = sp * sa;
        float T20 = -sa,               T22 = ca;   // T21 = 0

        float M01 = fmaf(-sp, g00, cp * g01);
        float M11 = fmaf(-sp, g10, cp * g11);
        float M21 = fmaf(-sp, g20, cp * g21);
        float M02 = fmaf(g00, T02, fmaf(g01, T12, g02 * T22));
        float M12 = fmaf(g10, T02, fmaf(g11, T12, g12 * T22));
        float M22 = fmaf(g20, T02, fmaf(g21, T12, g22 * T22));

        float dB0 = dBa.x, dB1 = dBa.y;
        float w0 = fmaf(dB1, M01, -(dB0 * M02));
        float w1 = fmaf(dB1, M11, -(dB0 * M12));
        float w2v = fmaf(dB1, M21, -(dB0 * M22));

        xiw4[(size_t)t * NB + p] = make_float4(xix, xiy, xiz, w0);
        w2f[(size_t)t * NB + p]  = make_float2(w1, w2v);

        float s0d, c0d, s1d, c1d;
        sincos_small(dB0, s0d, c0d);
        sincos_small(dB1, s1d, c1d);
        float dx30 = fmaf(c0d, c1d, -1.0f);
        float dx31 = c0d * s1d;
        float dx32 = -s0d;

        float dX0 = fmaf(T00, dx30, fmaf(T01, dx31, T02 * dx32));
        float dX1 = fmaf(T10, dx30, fmaf(T11, dx31, T12 * dx32));
        float dX2 = fmaf(T20, dx30, T22 * dx32);

        xtx += dX0; xty += dX1; xtz += dX2;

        float xi0 = xix + fmaf(g00, dX0, fmaf(g01, dX1, g02 * dX2));
        float xi1 = xiy + fmaf(g10, dX0, fmaf(g11, dX1, g12 * dX2));
        float xi2 = xiz + fmaf(g20, dX0, fmaf(g21, dX1, g22 * dX2));

        float ri2 = fmaf(xi0, xi0, fmaf(xi1, xi1, xi2 * xi2));
        float rs2 = __builtin_amdgcn_rsqf(ri2);
        float ri  = ri2 * rs2;
        bool outb = ri > RB;
        float n0 = xi0 * rs2, n1 = xi1 * rs2, n2 = xi2 * rs2;
        float coefs = outb ? (2.0f * (ri - RB)) : 0.0f;

        xix = fmaf(-coefs, n0, xi0);
        xiy = fmaf(-coefs, n1, xi1);
        xiz = fmaf(-coefs, n2, xi2);

        float mm0 = fmaf(n0, g00, fmaf(n1, g10, n2 * g20));
        float mm1 = fmaf(n0, g01, fmaf(n1, g11, n2 * g21));
        float mm2 = fmaf(n0, g02, fmaf(n1, g12, n2 * g22));
        float tw  = outb ? 2.0f : 0.0f;
        float tn0 = tw * n0, tn1 = tw * n1, tn2 = tw * n2;
        g00 = fmaf(-tn0, mm0, g00);
        g01 = fmaf(-tn0, mm1, g01);
        g02 = fmaf(-tn0, mm2, g02);
        g10 = fmaf(-tn1, mm0, g10);
        g11 = fmaf(-tn1, mm1, g11);
        g12 = fmaf(-tn1, mm2, g12);
        g20 = fmaf(-tn2, mm0, g20);
        g21 = fmaf(-tn2, mm1, g21);
        g22 = fmaf(-tn2, mm2, g22);

        dBa = dBb;
        int tn = (t + 2 < NSTEP) ? (t + 2) : (NSTEP - 1);
        dBb = *(const float2*)(dBt + ((size_t)tn * NB + p) * 2);
    }
    out[NB + p] = fmaf(xix, xix, fmaf(xiy, xiy, xiz * xiz));
}

// ---------------- consumer: MLP over (chunk of 16 steps) x (16 particles/wave) ----------------
__global__ __launch_bounds__(256, 6) void sde_mlp(
    const float* __restrict__ xt0,
    const float4* __restrict__ xiw4, const float2* __restrict__ w2f,
    const uint4* __restrict__ wsB,
    const float* __restrict__ bg2, const float* __restrict__ b2u,
    float* __restrict__ partial)
{
    const int tid  = threadIdx.x;
    const int lane = tid & 63;
    const int wv   = tid >> 6;
    const int g16  = (lane >> 4) & 3;
    const int l15  = lane & 15;
    const int blk  = blockIdx.x;            // 8192 blocks
    const int chunk = blk >> 10;            // 0..7
    const int p    = (blk & 1023) * 64 + wv * 16 + l15;

    float u_loc = 0.0f;
    if (chunk == 0) {
        // u_pre0 via the u-weight slot (t = NSTEP)
        float xx = xt0[p * 3 + 0];
        float xy = xt0[p * 3 + 1];
        float xz = xt0[p * 3 + 2];
        f32x4 a2 = mlp_chain(xx, xy, xz, wsB + (size_t)NSTEP * TBLK, lane, g16);
        u_loc = a2[0] + b2u[0];
    }

#pragma unroll 1
    for (int s = 0; s < 16; s++) {
        int t = chunk * 16 + s;
        float4 xw  = xiw4[(size_t)t * NB + p];
        float2 w12 = w2f[(size_t)t * NB + p];
        f32x4 a2 = mlp_chain(xw.x, xw.y, xw.z, wsB + (size_t)t * TBLK, lane, g16);
        const float* c2 = bg2 + (size_t)t * 3;
        u_loc = fmaf(a2[0] + c2[0], xw.w,  u_loc);
        u_loc = fmaf(a2[1] + c2[1], w12.x, u_loc);
        u_loc = fmaf(a2[2] + c2[2], w12.y, u_loc);
    }
    if (g16 == 0) partial[(size_t)chunk * NB + p] = u_loc;
}

__global__ __launch_bounds__(256) void sde_reduce(const float* __restrict__ partial,
                                                  float* __restrict__ out) {
    int p = blockIdx.x * 256 + threadIdx.x;
    float s = 0.0f;
#pragma unroll
    for (int c = 0; c < 8; c++) s += partial[(size_t)c * NB + p];
    out[p] = s;
}

// --------- unpacked helper (u_pre0 prologue of mid-fallback and sde_ref) ----------
__device__ __forceinline__ void mlp_h2_unpacked(float xx, float xy, float xz,
                                                const float* __restrict__ w0,
                                                const float* __restrict__ c0,
                                                const float* __restrict__ w1,
                                                int lane, f32x4* acc) {
    const int g16 = (lane >> 4) & 3;
    const int l15 = lane & 15;
#pragma unroll
    for (int kk = 0; kk < 2; kk++) {
        bf16x8 af[4];
#pragma unroll
        for (int I = 0; I < 4; I++) {
            uint pk[4];
#pragma unroll
            for (int ep = 0; ep < 4; ep++) {
                float f0 = w1[(kk * 32 + g16 * 8 + 2 * ep + 0) * HD + I * 16 + l15];
                float f1 = w1[(kk * 32 + g16 * 8 + 2 * ep + 1) * HD + I * 16 + l15];
                pk[ep] = (uint)bf16_rne(f0) | ((uint)bf16_rne(f1) << 16);
            }
            uint4 v; v.x = pk[0]; v.y = pk[1]; v.z = pk[2]; v.w = pk[3];
            af[I] = __builtin_bit_cast(bf16x8, v);
        }
        const float* wk = w0 + kk * 32 + g16 * 8;
        float4 wxa = *(const float4*)(wk);
        float4 wxb = *(const float4*)(wk + 4);
        float4 wya = *(const float4*)(wk + HD);
        float4 wyb = *(const float4*)(wk + HD + 4);
        float4 wza = *(const float4*)(wk + 2 * HD);
        float4 wzb = *(const float4*)(wk + 2 * HD + 4);
        const float* ck = c0 + kk * 32 + g16 * 8;
        float4 cva = *(const float4*)(ck);
        float4 cvb = *(const float4*)(ck + 4);
        float p0 = fmaf(xx, wxa.x, fmaf(xy, wya.x, fmaf(xz, wza.x, cva.x)));
        float p1 = fmaf(xx, wxa.y, fmaf(xy, wya.y, fmaf(xz, wza.y, cva.y)));
        float p2 = fmaf(xx, wxa.z, fmaf(xy, wya.z, fmaf(xz, wza.z, cva.z)));
        float p3 = fmaf(xx, wxa.w, fmaf(xy, wya.w, fmaf(xz, wza.w, cva.w)));
        float p4 = fmaf(xx, wxb.x, fmaf(xy, wyb.x, fmaf(xz, wzb.x, cvb.x)));
        float p5 = fmaf(xx, wxb.y, fmaf(xy, wyb.y, fmaf(xz, wzb.y, cvb.y)));
        float p6 = fmaf(xx, wxb.z, fmaf(xy, wyb.z, fmaf(xz, wzb.z, cvb.z)));
        float p7 = fmaf(xx, wxb.w, fmaf(xy, wyb.w, fmaf(xz, wzb.w, cvb.w)));
        uint4 bv;
        bv.x = pack_bf16_trunc(tanh_fast(p0), tanh_fast(p1));
        bv.y = pack_bf16_trunc(tanh_fast(p2), tanh_fast(p3));
        bv.z = pack_bf16_trunc(tanh_fast(p4), tanh_fast(p5));
        bv.w = pack_bf16_trunc(tanh_fast(p6), tanh_fast(p7));
        bf16x8 bf = __builtin_bit_cast(bf16x8, bv);
#pragma unroll
        for (int I = 0; I < 4; I++)
            acc[I] = __builtin_amdgcn_mfma_f32_16x16x32_bf16(af[I], bf, acc[I], 0, 0, 0);
    }
}

// ------------- mid-fallback: R9 monolithic kernel (replicated A2, no shfl) -------------
__global__ __launch_bounds__(256, 4) void sde_fast(
    const float* __restrict__ xt0,
    const float* __restrict__ dBt,
    const float* __restrict__ W0u, const float* __restrict__ b0u,
    const float* __restrict__ W1u, const float* __restrict__ b1u,
    const float* __restrict__ W2u, const float* __restrict__ b2u,
    const float* __restrict__ bg2,
    const uint4* __restrict__ wsB,
    float* __restrict__ out)
{
    const int tid  = threadIdx.x;
    const int lane = tid & 63;
    const int wv   = tid >> 6;
    const int g16  = (lane >> 4) & 3;
    const int l15  = lane & 15;
    const int p    = blockIdx.x * 64 + wv * 16 + l15;

    float xtx = xt0[p * 3 + 0];
    float xty = xt0[p * 3 + 1];
    float xtz = xt0[p * 3 + 2];
    float xix = xtx, xiy = xty, xiz = xtz;
    float g00 = 1.f, g01 = 0.f, g02 = 0.f;
    float g10 = 0.f, g11 = 1.f, g12 = 0.f;
    float g20 = 0.f, g21 = 0.f, g22 = 1.f;

    float u_pre;
    {
        f32x4 acc[4];
#pragma unroll
        for (int I = 0; I < 4; I++) acc[I] = (f32x4){0.f, 0.f, 0.f, 0.f};
        mlp_h2_unpacked(xtx, xty, xtz, W0u, b0u, W1u, lane, acc);
        float pj = 0.f;
#pragma unroll
        for (int I = 0; I < 4; I++) {
            float4 wv2 = *(const float4*)(W2u + I * 16 + g16 * 4);
            float4 cv  = *(const float4*)(b1u + I * 16 + g16 * 4);
            pj = fmaf(tanh_fast(acc[I][0] + cv.x), wv2.x, pj);
            pj = fmaf(tanh_fast(acc[I][1] + cv.y), wv2.y, pj);
            pj = fmaf(tanh_fast(acc[I][2] + cv.z), wv2.z, pj);
            pj = fmaf(tanh_fast(acc[I][3] + cv.w), wv2.w, pj);
        }
        pj += __shfl_xor(pj, 16, 64);
        pj += __shfl_xor(pj, 32, 64);
        u_pre = pj + b2u[0];
    }

#pragma unroll 1
    for (int t = 0; t < NSTEP; t++) {
        const uint4* blob_t = wsB + (size_t)t * TBLK;
        const float* c2     = bg2 + (size_t)t * 3;

        float d  = fmaf(xtx, xtx, fmaf(xty, xty, xtz * xtz));
        float rs = __builtin_amdgcn_rsqf(d);
        float uu = xtz * rs;
        uu = fminf(fmaxf(uu, -0.999999f), 0.999999f);
        float sa = -uu;
        float rho2 = fmaf(xtx, xtx, xty * xty);
        bool hasrho = rho2 > 0.0f;
        float rr = __builtin_amdgcn_rsqf(rho2);
        float cp = hasrho ? (xtx * rr) : 1.0f;
        float sp = hasrho ? (xty * rr) : 0.0f;
        float ca = hasrho ? (rho2 * rr * rs) : 1.4142135e-3f;
        float T00 = cp * ca, T01 = -sp, T02 = cp * sa;
        float T10 = sp * ca, T11 = cp,  T12 = sp * sa;
        float T20 = -sa,               T22 = ca;

        f32x4 a2 = mlp_chain(xix, xiy, xiz, blob_t, lane, g16);
        float gv0 = a2[0] + c2[0];
        float gv1 = a2[1] + c2[1];
        float gv2 = a2[2] + c2[2];

        float M01 = fmaf(-sp, g00, cp * g01);
        float M11 = fmaf(-sp, g10, cp * g11);
        float M21 = fmaf(-sp, g20, cp * g21);
        float M02 = fmaf(g00, T02, fmaf(g01, T12, g02 * T22));
        float M12 = fmaf(g10, T02, fmaf(g11, T12, g12 * T22));
        float M22 = fmaf(g20, T02, fmaf(g21, T12, g22 * T22));
        float v1 = fmaf(gv0, M01, fmaf(gv1, M11, gv2 * M21));
        float v2 = fmaf(gv0, M02, fmaf(gv1, M12, gv2 * M22));

        const float2 dB = *(const float2*)(dBt + ((size_t)t * NB + p) * 2);
        float dB0 = dB.x, dB1 = dB.y;
        u_pre += fmaf(v1, dB1, -v2 * dB0);

        float s0d, c0d, s1d, c1d;
        sincos_small(dB0, s0d, c0d);
        sincos_small(dB1, s1d, c1d);
        float dx30 = fmaf(c0d, c1d, -1.0f);
        float dx31 = c0d * s1d;
        float dx32 = -s0d;

        float dX0 = fmaf(T00, dx30, fmaf(T01, dx31, T02 * dx32));
        float dX1 = fmaf(T10, dx30, fmaf(T11, dx31, T12 * dx32));
        float dX2 = fmaf(T20, dx30, T22 * dx32);

        xtx += dX0; xty += dX1; xtz += dX2;

        float xi0 = xix + fmaf(g00, dX0, fmaf(g01, dX1, g02 * dX2));
        float xi1 = xiy + fmaf(g10, dX0, fmaf(g11, dX1, g12 * dX2));
        float xi2 = xiz + fmaf(g20, dX0, fmaf(g21, dX1, g22 * dX2));

        float ri2 = fmaf(xi0, xi0, fmaf(xi1, xi1, xi2 * xi2));
        float rs2 = __builtin_amdgcn_rsqf(ri2);
        float ri  = ri2 * rs2;
        bool outb = ri > RB;
        float n0 = xi0 * rs2, n1 = xi1 * rs2, n2 = xi2 * rs2;
        float coefs = outb ? (2.0f * (ri - RB)) : 0.0f;

        xix = fmaf(-coefs, n0, xi0);
        xiy = fmaf(-coefs, n1, xi1);
        xiz = fmaf(-coefs, n2, xi2);

        float mm0 = fmaf(n0, g00, fmaf(n1, g10, n2 * g20));
        float mm1 = fmaf(n0, g01, fmaf(n1, g11, n2 * g21));
        float mm2 = fmaf(n0, g02, fmaf(n1, g12, n2 * g22));
        float tw  = outb ? 2.0f : 0.0f;
        float tn0 = tw * n0, tn1 = tw * n1, tn2 = tw * n2;
        g00 = fmaf(-tn0, mm0, g00);
        g01 = fmaf(-tn0, mm1, g01);
        g02 = fmaf(-tn0, mm2, g02);
        g10 = fmaf(-tn1, mm0, g10);
        g11 = fmaf(-tn1, mm1, g11);
        g12 = fmaf(-tn1, mm2, g12);
        g20 = fmaf(-tn2, mm0, g20);
        g21 = fmaf(-tn2, mm1, g21);
        g22 = fmaf(-tn2, mm2, g22);
    }

    float u_rel = fmaf(xix, xix, fmaf(xiy, xiy, xiz * xiz));
    if (g16 == 0) {
        out[p] = u_pre;
        out[NB + p] = u_rel;
    }
}

// ------------------- final fallback (R3-style, unpacked weights) -------------------
__global__ __launch_bounds__(256, 4) void sde_ref(
    const float* __restrict__ xt0,
    const float* __restrict__ dBt,
    const float* __restrict__ W0u, const float* __restrict__ b0u,
    const float* __restrict__ W1u, const float* __restrict__ b1u,
    const float* __restrict__ W2u, const float* __restrict__ b2u,
    const float* __restrict__ Wg0, const float* __restrict__ bg0,
    const float* __restrict__ Wg1, const float* __restrict__ bg1,
    const float* __restrict__ Wg2, const float* __restrict__ bg2,
    float* __restrict__ out)
{
    const int tid  = threadIdx.x;
    const int lane = tid & 63;
    const int wv   = tid >> 6;
    const int g16  = (lane >> 4) & 3;
    const int l15  = lane & 15;
    const int p    = blockIdx.x * 64 + wv * 16 + l15;

    float xtx = xt0[p * 3 + 0];
    float xty = xt0[p * 3 + 1];
    float xtz = xt0[p * 3 + 2];
    float xix = xtx, xiy = xty, xiz = xtz;
    float g00 = 1.f, g01 = 0.f, g02 = 0.f;
    float g10 = 0.f, g11 = 1.f, g12 = 0.f;
    float g20 = 0.f, g21 = 0.f, g22 = 1.f;

    float u_pre;
    {
        f32x4 acc[4];
#pragma unroll
        for (int I = 0; I < 4; I++) acc[I] = (f32x4){0.f, 0.f, 0.f, 0.f};
        mlp_h2_unpacked(xtx, xty, xtz, W0u, b0u, W1u, lane, acc);
        float pj = 0.f;
#pragma unroll
        for (int I = 0; I < 4; I++) {
            float4 wv2 = *(const float4*)(W2u + I * 16 + g16 * 4);
            float4 cv  = *(const float4*)(b1u + I * 16 + g16 * 4);
            pj = fmaf(tanh_fast(acc[I][0] + cv.x), wv2.x, pj);
            pj = fmaf(tanh_fast(acc[I][1] + cv.y), wv2.y, pj);
            pj = fmaf(tanh_fast(acc[I][2] + cv.z), wv2.z, pj);
            pj = fmaf(tanh_fast(acc[I][3] + cv.w), wv2.w, pj);
        }
        pj += __shfl_xor(pj, 16, 64);
        pj += __shfl_xor(pj, 32, 64);
        u_pre = pj + b2u[0];
    }

#pragma unroll 1
    for (int t = 0; t < NSTEP; t++) {
        const float* w0 = Wg0 + (size_t)t * 3 * HD;
        const float* c0 = bg0 + (size_t)t * HD;
        const float* c1 = bg1 + (size_t)t * HD;
        const float* w2 = Wg2 + (size_t)t * HD * 3;
        const float* c2 = bg2 + (size_t)t * 3;

        float r = sqrtf(fmaf(xtx, xtx, fmaf(xty, xty, xtz * xtz)));
        float uu = xtz / r;
        uu = fminf(fmaxf(uu, -0.999999f), 0.999999f);
        float ca = sqrtf((1.0f - uu) * (1.0f + uu));
        float sa = -uu;
        float rho = sqrtf(fmaf(xtx, xtx, xty * xty));
        float cp = (rho > 0.0f) ? (xtx / rho) : 1.0f;
        float sp = (rho > 0.0f) ? (xty / rho) : 0.0f;
        float T00 = cp * ca, T01 = -sp, T02 = cp * sa;
        float T10 = sp * ca, T11 = cp,  T12 = sp * sa;
        float T20 = -sa,               T22 = ca;

        f32x4 acc[4];
#pragma unroll
        for (int I = 0; I < 4; I++) acc[I] = (f32x4){0.f, 0.f, 0.f, 0.f};
        mlp_h2_unpacked(xix, xiy, xiz, w0, c0, Wg1 + (size_t)t * HD * HD, lane, acc);

        float pj0 = 0.f, pj1 = 0.f, pj2 = 0.f;
#pragma unroll
        for (int I = 0; I < 4; I++) {
            const float* wp = w2 + 3 * (I * 16 + g16 * 4);
            float4 wa = *(const float4*)(wp);
            float4 wb = *(const float4*)(wp + 4);
            float4 wc = *(const float4*)(wp + 8);
            float4 cv = *(const float4*)(c1 + I * 16 + g16 * 4);
            float th0 = tanh_fast(acc[I][0] + cv.x);
            float th1 = tanh_fast(acc[I][1] + cv.y);
            float th2 = tanh_fast(acc[I][2] + cv.z);
            float th3 = tanh_fast(acc[I][3] + cv.w);
            pj0 = fmaf(th0, wa.x, pj0); pj1 = fmaf(th0, wa.y, pj1); pj2 = fmaf(th0, wa.z, pj2);
            pj0 = fmaf(th1, wa.w, pj0); pj1 = fmaf(th1, wb.x, pj1); pj2 = fmaf(th1, wb.y, pj2);
            pj0 = fmaf(th2, wb.z, pj0); pj1 = fmaf(th2, wb.w, pj1); pj2 = fmaf(th2, wc.x, pj2);
            pj0 = fmaf(th3, wc.y, pj0); pj1 = fmaf(th3, wc.z, pj1); pj2 = fmaf(th3, wc.w, pj2);
        }
        pj0 += __shfl_xor(pj0, 16, 64); pj0 += __shfl_xor(pj0, 32, 64);
        pj1 += __shfl_xor(pj1, 16, 64); pj1 += __shfl_xor(pj1, 32, 64);
        pj2 += __shfl_xor(pj2, 16, 64); pj2 += __shfl_xor(pj2, 32, 64);
        float gv0 = pj0 + c2[0];
        float gv1 = pj1 + c2[1];
        float gv2 = pj2 + c2[2];

        float M01 = fmaf(-sp, g00, cp * g01);
        float M11 = fmaf(-sp, g10, cp * g11);
        float M21 = fmaf(-sp, g20, cp * g21);
        float M02 = fmaf(g00, T02, fmaf(g01, T12, g02 * T22));
        float M12 = fmaf(g10, T02, fmaf(g11, T12, g12 * T22));
        float M22 = fmaf(g20, T02, fmaf(g21, T12, g22 * T22));
        float v1 = fmaf(gv0, M01, fmaf(gv1, M11, gv2 * M21));
        float v2 = fmaf(gv0, M02, fmaf(gv1, M12, gv2 * M22));

        const float2 dB = *(const float2*)(dBt + ((size_t)t * NB + p) * 2);
        float dB0 = dB.x, dB1 = dB.y;
        u_pre += fmaf(v1, dB1, -v2 * dB0);

        float s0d, c0d, s1d, c1d;
        __sincosf(dB0, &s0d, &c0d);
        __sincosf(dB1, &s1d, &c1d);
        float dx30 = fmaf(c0d, c1d, -1.0f);
        float dx31 = c0d * s1d;
        float dx32 = -s0d;

        float dX0 = fmaf(T00, dx30, fmaf(T01, dx31, T02 * dx32));
        float dX1 = fmaf(T10, dx30, fmaf(T11, dx31, T12 * dx32));
        float dX2 = fmaf(T20, dx30, T22 * dx32);

        xtx += dX0; xty += dX1; xtz += dX2;

        float xi0 = xix + fmaf(g00, dX0, fmaf(g01, dX1, g02 * dX2));
        float xi1 = xiy + fmaf(g10, dX0, fmaf(g11, dX1, g12 * dX2));
        float xi2 = xiz + fmaf(g20, dX0, fmaf(g21, dX1, g22 * dX2));

        float ri = sqrtf(fmaf(xi0, xi0, fmaf(xi1, xi1, xi2 * xi2)));
        bool outb = ri > RB;
        float n0 = xi0 / ri, n1 = xi1 / ri, n2 = xi2 / ri;
        float coef = 2.0f * (ri - RB);

        xix = outb ? fmaf(-coef, n0, xi0) : xi0;
        xiy = outb ? fmaf(-coef, n1, xi1) : xi1;
        xiz = outb ? fmaf(-coef, n2, xi2) : xi2;

        float mm0 = fmaf(n0, g00, fmaf(n1, g10, n2 * g20));
        float mm1 = fmaf(n0, g01, fmaf(n1, g11, n2 * g21));
        float mm2 = fmaf(n0, g02, fmaf(n1, g12, n2 * g22));
        float tn0 = 2.0f * n0, tn1 = 2.0f * n1, tn2 = 2.0f * n2;
        g00 = outb ? fmaf(-tn0, mm0, g00) : g00;
        g01 = outb ? fmaf(-tn0, mm1, g01) : g01;
        g02 = outb ? fmaf(-tn0, mm2, g02) : g02;
        g10 = outb ? fmaf(-tn1, mm0, g10) : g10;
        g11 = outb ? fmaf(-tn1, mm1, g11) : g11;
        g12 = outb ? fmaf(-tn1, mm2, g12) : g12;
        g20 = outb ? fmaf(-tn2, mm0, g20) : g20;
        g21 = outb ? fmaf(-tn2, mm1, g21) : g21;
        g22 = outb ? fmaf(-tn2, mm2, g22) : g22;
    }

    float u_rel = fmaf(xix, xix, fmaf(xiy, xiy, xiz * xiz));
    if (g16 == 0) {
        out[p] = u_pre;
        out[NB + p] = u_rel;
    }
}

extern "C" void kernel_launch(void* const* d_in, const int* in_sizes, int n_in,
                              void* d_out, int out_size, void* d_ws, size_t ws_size,
                              hipStream_t stream) {
    const float* xt0 = (const float*)d_in[0];
    const float* dBt = (const float*)d_in[1];
    const float* W0u = (const float*)d_in[2];
    const float* b0u = (const float*)d_in[3];
    const float* W1u = (const float*)d_in[4];
    const float* b1u = (const float*)d_in[5];
    const float* W2u = (const float*)d_in[6];
    const float* b2u = (const float*)d_in[7];
    const float* Wg0 = (const float*)d_in[8];
    const float* bg0 = (const float*)d_in[9];
    const float* Wg1 = (const float*)d_in[10];
    const float* bg1 = (const float*)d_in[11];
    const float* Wg2 = (const float*)d_in[12];
    const float* bg2 = (const float*)d_in[13];
    float* out = (float*)d_out;

    const size_t SZ_BLOB = (size_t)(NSTEP + 1) * TBLK * sizeof(uint4);  // ~1.87 MB
    const size_t SZ_XIW  = (size_t)NSTEP * NB * sizeof(float4);         // 128 MB
    const size_t SZ_W2   = (size_t)NSTEP * NB * sizeof(float2);         // 64 MB
    const size_t SZ_PART = (size_t)8 * NB * sizeof(float);              // 2 MB

    if (ws_size >= SZ_BLOB + SZ_XIW + SZ_W2 + SZ_PART && d_ws != nullptr) {
        uint4*  wsB     = (uint4*)d_ws;
        float4* xiw4    = (float4*)((char*)d_ws + SZ_BLOB);
        float2* w2f     = (float2*)((char*)d_ws + SZ_BLOB + SZ_XIW);
        float*  partial = (float*)((char*)d_ws + SZ_BLOB + SZ_XIW + SZ_W2);
        hipLaunchKernelGGL(prep_a1,  dim3(258), dim3(256), 0, stream, Wg1, W1u, wsB);
        hipLaunchKernelGGL(prep_a0,  dim3(129), dim3(256), 0, stream, Wg0, bg0, W0u, b0u, wsB);
        hipLaunchKernelGGL(prep_a2,  dim3(65),  dim3(256), 0, stream, Wg2, W2u, wsB);
        hipLaunchKernelGGL(prep_bias, dim3(65), dim3(256), 0, stream, bg1, b1u, wsB);
        hipLaunchKernelGGL(sde_state, dim3(NB / 256), dim3(256), 0, stream,
                           xt0, dBt, xiw4, w2f, out);
        hipLaunchKernelGGL(sde_mlp, dim3(8192), dim3(256), 0, stream,
                           xt0, (const float4*)xiw4, (const float2*)w2f,
                           (const uint4*)wsB, bg2, b2u, partial);
        hipLaunchKernelGGL(sde_reduce, dim3(NB / 256), dim3(256), 0, stream,
                           (const float*)partial, out);
    } else if (ws_size >= SZ_BLOB && d_ws != nullptr) {
        uint4* wsB = (uint4*)d_ws;
        hipLaunchKernelGGL(prep_a1,  dim3(258), dim3(256), 0, stream, Wg1, W1u, wsB);
        hipLaunchKernelGGL(prep_a0,  dim3(129), dim3(256), 0, stream, Wg0, bg0, W0u, b0u, wsB);
        hipLaunchKernelGGL(prep_a2,  dim3(65),  dim3(256), 0, stream, Wg2, W2u, wsB);
        hipLaunchKernelGGL(prep_bias, dim3(65), dim3(256), 0, stream, bg1, b1u, wsB);
        hipLaunchKernelGGL(sde_fast, dim3(NB * 4 / 256), dim3(256), 0, stream,
                           xt0, dBt, W0u, b0u, W1u, b1u, W2u, b2u,
                           bg2, (const uint4*)wsB, out);
    } else {
        hipLaunchKernelGGL(sde_ref, dim3(NB * 4 / 256), dim3(256), 0, stream,
                           xt0, dBt, W0u, b0u, W1u, b1u, W2u, b2u,
                           Wg0, bg0, Wg1, bg1, Wg2, bg2, out);
    }
}

// Round 11
// 352.659 us; speedup vs baseline: 2.2399x; 1.0920x over previous
//
#include <hip/hip_runtime.h>

#define NB 65536
#define NSTEP 128
#define HD 64
#define RB 1.05f
#define SCALE 2.8853900817779268f   // 2*log2(e)
#define TBLK 928          // uint4 per time-step in the ws blob (slots 0..NSTEP; slot NSTEP = u-weights)
#define OFF_A1 0          // 512 uint4 : SCALE*W1^T frags (pi-permuted rows)
#define OFF_A0 512        // 256 uint4 : SCALE*[W0^T; c0] frags (h1idx-permuted rows, c0 at k=3)
#define OFF_A2 768        // 128 uint4 : W2^T frags, ROW-REPLICATED (row 4q+j = W2 col j; j<3)
#define OFF_CB 896        // 32 uint4  : SCALE*c1 (64 f32, pi-permuted)

typedef __bf16 bf16x8 __attribute__((ext_vector_type(8)));
typedef float f32x4 __attribute__((ext_vector_type(4)));
typedef unsigned int uint;
typedef unsigned short ushort;

extern "C" __device__ float __ocml_native_exp2_f32(float);
#if __has_builtin(__builtin_amdgcn_exp2f)
#define EXP2(x) __builtin_amdgcn_exp2f(x)
#else
#define EXP2(x) __ocml_native_exp2_f32(x)
#endif

__device__ __forceinline__ float tanh_fast(float x) {
    float e2 = __expf(2.0f * x);
    return 1.0f - 2.0f * __builtin_amdgcn_rcpf(1.0f + e2);
}

// paired tanh on PRE-SCALED inputs z = 2*log2(e)*x; one v_rcp serves two tanh.
// rpn = -2/(a1*b1) computed once; each result is a single fma (single rounding,
// identical to the previous (-2*b1)*rp form).
__device__ __forceinline__ void tanh2s(float za, float zb, float& ta, float& tb) {
    float ea = EXP2(za);
    float eb = EXP2(zb);
    float a1 = 1.0f + ea;
    float b1 = 1.0f + eb;
    float rpn = -2.0f * __builtin_amdgcn_rcpf(a1 * b1);
    ta = fmaf(b1, rpn, 1.0f);
    tb = fmaf(a1, rpn, 1.0f);
}

__device__ __forceinline__ void sincos_small(float x, float& s, float& c) {
    float x2 = x * x;
    s = fmaf(x2, fmaf(x2, 8.3333333e-3f, -0.16666667f), 1.0f) * x;
    c = fmaf(x2, fmaf(x2, fmaf(x2, -1.3888889e-3f, 4.1666668e-2f), -0.5f), 1.0f);
}

__device__ __forceinline__ uint pack_bf16_trunc(float a, float b) {
    return __builtin_amdgcn_perm(__float_as_uint(b), __float_as_uint(a), 0x07060302u);
}

__device__ __forceinline__ ushort bf16_rne(float f) {
    uint u = __float_as_uint(f);
    u += 0x7fffu + ((u >> 16) & 1u);
    return (ushort)(u >> 16);
}

// pi(I,s,j) == h1idx = (I>>1)*32 + s*8 + (I&1)*4 + j  (bijection on 0..63)

// ---- prep: A1 = SCALE*W1^T with pi-permuted rows (slot NSTEP = W1u) ----
__global__ __launch_bounds__(256) void prep_a1(const float* __restrict__ Wg1,
                                               const float* __restrict__ W1u,
                                               uint4* __restrict__ wsB) {
    int tid  = blockIdx.x * 256 + threadIdx.x;
    int lane = tid & 63;
    int I    = (tid >> 6) & 3;
    int kk   = (tid >> 8) & 1;
    int t    = tid >> 9;
    if (t > NSTEP) return;
    int rA   = lane & 15;
    int lrow = (I & 1) * 4 + (I >> 1) * 32 + (rA >> 2) * 8 + (rA & 3);
    int k0   = kk * 32 + ((lane >> 4) & 3) * 8;
    const float* base = (t < NSTEP) ? (Wg1 + (size_t)t * HD * HD) : W1u;
    const float* src  = base + (size_t)k0 * HD + lrow;
    ushort o[8];
#pragma unroll
    for (int e = 0; e < 8; e++) o[e] = bf16_rne(src[(size_t)e * HD] * SCALE);
    uint4 v;
    v.x = (uint)o[0] | ((uint)o[1] << 16);
    v.y = (uint)o[2] | ((uint)o[3] << 16);
    v.z = (uint)o[4] | ((uint)o[5] << 16);
    v.w = (uint)o[6] | ((uint)o[7] << 16);
    wsB[(size_t)t * TBLK + OFF_A1 + (kk * 4 + I) * 64 + lane] = v;
}

// ---- prep: A0 = SCALE*W0^T (h1idx-permuted rows); row k=3 holds SCALE*c0 ----
__global__ __launch_bounds__(256) void prep_a0(const float* __restrict__ Wg0,
                                               const float* __restrict__ bg0,
                                               const float* __restrict__ W0u,
                                               const float* __restrict__ b0u,
                                               uint4* __restrict__ wsB) {
    int tid  = blockIdx.x * 256 + threadIdx.x;
    int lane = tid & 63;
    int I    = (tid >> 6) & 3;
    int t    = tid >> 8;
    if (t > NSTEP) return;
    int m    = lane & 15;
    int kg   = (lane >> 4) & 3;
    int h    = (I >> 1) * 32 + (m >> 2) * 8 + (I & 1) * 4 + (m & 3);
    ushort o[8];
#pragma unroll
    for (int e = 0; e < 8; e++) {
        int k = kg * 8 + e;
        float v = 0.0f;
        if (k < 3)       v = SCALE * ((t < NSTEP) ? Wg0[((size_t)t * 3 + k) * HD + h]
                                                  : W0u[(size_t)k * HD + h]);
        else if (k == 3) v = SCALE * ((t < NSTEP) ? bg0[(size_t)t * HD + h] : b0u[h]);
        o[e] = bf16_rne(v);
    }
    uint4 v;
    v.x = (uint)o[0] | ((uint)o[1] << 16);
    v.y = (uint)o[2] | ((uint)o[3] << 16);
    v.z = (uint)o[4] | ((uint)o[5] << 16);
    v.w = (uint)o[6] | ((uint)o[7] << 16);
    wsB[(size_t)t * TBLK + OFF_A0 + I * 64 + lane] = v;
}

// ---- prep: A2 = W2^T ROW-REPLICATED (row 4q+j holds W2 col j; slot NSTEP = W2u at j=0) ----
__global__ __launch_bounds__(256) void prep_a2(const float* __restrict__ Wg2,
                                               const float* __restrict__ W2u,
                                               uint4* __restrict__ wsB) {
    int tid  = blockIdx.x * 256 + threadIdx.x;
    int lane = tid & 63;
    int kk   = (tid >> 6) & 1;
    int t    = tid >> 7;
    if (t > NSTEP) return;
    int row  = lane & 15;
    int j    = row & 3;
    int k0   = kk * 32 + ((lane >> 4) & 3) * 8;
    ushort o[8];
#pragma unroll
    for (int e = 0; e < 8; e++) {
        float v = 0.0f;
        if (j < 3) {
            if (t < NSTEP) v = Wg2[(size_t)t * HD * 3 + (size_t)(k0 + e) * 3 + j];
            else           v = (j == 0) ? W2u[k0 + e] : 0.0f;
        }
        o[e] = bf16_rne(v);
    }
    uint4 v;
    v.x = (uint)o[0] | ((uint)o[1] << 16);
    v.y = (uint)o[2] | ((uint)o[3] << 16);
    v.z = (uint)o[4] | ((uint)o[5] << 16);
    v.w = (uint)o[6] | ((uint)o[7] << 16);
    wsB[(size_t)t * TBLK + OFF_A2 + kk * 64 + lane] = v;
}

// ---- prep: SCALE*c1, pi-permuted (slot NSTEP = b1u) ----
__global__ __launch_bounds__(256) void prep_bias(const float* __restrict__ bg1,
                                                 const float* __restrict__ b1u,
                                                 uint4* __restrict__ wsB) {
    int tid = blockIdx.x * 256 + threadIdx.x;   // t*128 + i
    int i   = tid & 127;
    int t   = tid >> 7;
    if (t > NSTEP) return;
    int r   = i & 63;
    int pi  = ((r >> 4) & 1) * 4 + ((r >> 5) & 1) * 32 + ((r >> 2) & 3) * 8 + (r & 3);
    float* dst = (float*)(wsB + (size_t)t * TBLK + OFF_CB);
    float v = 0.0f;
    if (i < 64) v = SCALE * ((t < NSTEP) ? bg1[(size_t)t * HD + pi] : b1u[pi]);
    dst[i] = v;
}

// ---- the 3-GEMM MLP chain; B0 comes in PRE-PACKED (lo = bf16(x,y), hi = bf16(z,1)) ----
__device__ __forceinline__ f32x4 mlp_chain(uint b0lo, uint b0hi,
                                           const uint4* __restrict__ blob_t,
                                           int lane, int g16) {
    const f32x4 zero4 = (f32x4){0.f, 0.f, 0.f, 0.f};
    uint4 b0v;
    b0v.x = b0lo; b0v.y = b0hi; b0v.z = 0u; b0v.w = 0u;
    bf16x8 b0 = __builtin_bit_cast(bf16x8, b0v);

    uint4 a0v0 = {0u,0u,0u,0u}, a0v1 = {0u,0u,0u,0u}, a0v2 = {0u,0u,0u,0u}, a0v3 = {0u,0u,0u,0u};
    if (g16 == 0) {
        a0v0 = blob_t[OFF_A0 + 0 * 64 + lane];
        a0v1 = blob_t[OFF_A0 + 1 * 64 + lane];
        a0v2 = blob_t[OFF_A0 + 2 * 64 + lane];
        a0v3 = blob_t[OFF_A0 + 3 * 64 + lane];
    }
    f32x4 acc0[4];
    acc0[0] = __builtin_amdgcn_mfma_f32_16x16x32_bf16(__builtin_bit_cast(bf16x8, a0v0), b0, zero4, 0, 0, 0);
    acc0[1] = __builtin_amdgcn_mfma_f32_16x16x32_bf16(__builtin_bit_cast(bf16x8, a0v1), b0, zero4, 0, 0, 0);
    acc0[2] = __builtin_amdgcn_mfma_f32_16x16x32_bf16(__builtin_bit_cast(bf16x8, a0v2), b0, zero4, 0, 0, 0);
    acc0[3] = __builtin_amdgcn_mfma_f32_16x16x32_bf16(__builtin_bit_cast(bf16x8, a0v3), b0, zero4, 0, 0, 0);

    const float* c1p_t = (const float*)(blob_t + OFF_CB);
    f32x4 acc[4];
#pragma unroll
    for (int I = 0; I < 4; I++) {
        float4 cv = *(const float4*)(c1p_t + I * 16 + g16 * 4);
        acc[I] = (f32x4){cv.x, cv.y, cv.z, cv.w};
    }
#pragma unroll
    for (int kk = 0; kk < 2; kk++) {
        float t0, t1, t2, t3, t4, t5, t6, t7;
        tanh2s(acc0[kk * 2 + 0][0], acc0[kk * 2 + 0][1], t0, t1);
        tanh2s(acc0[kk * 2 + 0][2], acc0[kk * 2 + 0][3], t2, t3);
        tanh2s(acc0[kk * 2 + 1][0], acc0[kk * 2 + 1][1], t4, t5);
        tanh2s(acc0[kk * 2 + 1][2], acc0[kk * 2 + 1][3], t6, t7);
        uint4 bv;
        bv.x = pack_bf16_trunc(t0, t1);
        bv.y = pack_bf16_trunc(t2, t3);
        bv.z = pack_bf16_trunc(t4, t5);
        bv.w = pack_bf16_trunc(t6, t7);
        bf16x8 bf = __builtin_bit_cast(bf16x8, bv);
#pragma unroll
        for (int I = 0; I < 4; I++) {
            bf16x8 af = __builtin_bit_cast(bf16x8, blob_t[OFF_A1 + (kk * 4 + I) * 64 + lane]);
            acc[I] = __builtin_amdgcn_mfma_f32_16x16x32_bf16(af, bf, acc[I], 0, 0, 0);
        }
    }
    f32x4 acc2 = zero4;
#pragma unroll
    for (int half = 0; half < 2; half++) {
        float t0, t1, t2, t3, t4, t5, t6, t7;
        tanh2s(acc[2 * half + 0][0], acc[2 * half + 0][1], t0, t1);
        tanh2s(acc[2 * half + 0][2], acc[2 * half + 0][3], t2, t3);
        tanh2s(acc[2 * half + 1][0], acc[2 * half + 1][1], t4, t5);
        tanh2s(acc[2 * half + 1][2], acc[2 * half + 1][3], t6, t7);
        uint4 bv;
        bv.x = pack_bf16_trunc(t0, t1);
        bv.y = pack_bf16_trunc(t2, t3);
        bv.z = pack_bf16_trunc(t4, t5);
        bv.w = pack_bf16_trunc(t6, t7);
        bf16x8 bf = __builtin_bit_cast(bf16x8, bv);
        bf16x8 a2 = __builtin_bit_cast(bf16x8, blob_t[OFF_A2 + half * 64 + lane]);
        acc2 = __builtin_amdgcn_mfma_f32_16x16x32_bf16(a2, bf, acc2, 0, 0, 0);
    }
    return acc2;
}

// ---------------- producer: state recurrence only (bit-identical to R10) ----------------
__global__ __launch_bounds__(256) void sde_state(
    const float* __restrict__ xt0, const float* __restrict__ dBt,
    uint4* __restrict__ xiw, float* __restrict__ wz,
    float* __restrict__ out)
{
    int p = blockIdx.x * 256 + threadIdx.x;
    float xtx = xt0[p * 3 + 0];
    float xty = xt0[p * 3 + 1];
    float xtz = xt0[p * 3 + 2];
    float xix = xtx, xiy = xty, xiz = xtz;
    float g00 = 1.f, g01 = 0.f, g02 = 0.f;
    float g10 = 0.f, g11 = 1.f, g12 = 0.f;
    float g20 = 0.f, g21 = 0.f, g22 = 1.f;

    float2 dBa = *(const float2*)(dBt + (size_t)p * 2);
    float2 dBb = *(const float2*)(dBt + ((size_t)NB + p) * 2);

#pragma unroll 1
    for (int t = 0; t < NSTEP; t++) {
        float d  = fmaf(xtx, xtx, fmaf(xty, xty, xtz * xtz));
        float rs = __builtin_amdgcn_rsqf(d);
        float uu = xtz * rs;
        uu = fminf(fmaxf(uu, -0.999999f), 0.999999f);
        float sa = -uu;
        float rho2 = fmaf(xtx, xtx, xty * xty);
        bool hasrho = rho2 > 0.0f;
        float rr = __builtin_amdgcn_rsqf(rho2);
        float cp = hasrho ? (xtx * rr) : 1.0f;
        float sp = hasrho ? (xty * rr) : 0.0f;
        float ca = hasrho ? (rho2 * rr * rs) : 1.4142135e-3f;
        float T00 = cp * ca, T01 = -sp, T02 = cp * sa;
        float T10 = sp * ca, T11 = cp,  T12 = sp * sa;
        float T20 = -sa,               T22 = ca;   // T21 = 0

        float M01 = fmaf(-sp, g00, cp * g01);
        float M11 = fmaf(-sp, g10, cp * g11);
        float M21 = fmaf(-sp, g20, cp * g21);
        float M02 = fmaf(g00, T02, fmaf(g01, T12, g02 * T22));
        float M12 = fmaf(g10, T02, fmaf(g11, T12, g12 * T22));
        float M22 = fmaf(g20, T02, fmaf(g21, T12, g22 * T22));

        float dB0 = dBa.x, dB1 = dBa.y;
        float w0 = fmaf(dB1, M01, -(dB0 * M02));
        float w1 = fmaf(dB1, M11, -(dB0 * M12));
        float w2v = fmaf(dB1, M21, -(dB0 * M22));

        uint4 xw;
        xw.x = pack_bf16_trunc(xix, xiy);
        xw.y = pack_bf16_trunc(xiz, 1.0f);
        xw.z = __float_as_uint(w0);
        xw.w = __float_as_uint(w1);
        xiw[(size_t)t * NB + p] = xw;
        wz[(size_t)t * NB + p]  = w2v;

        float s0d, c0d, s1d, c1d;
        sincos_small(dB0, s0d, c0d);
        sincos_small(dB1, s1d, c1d);
        float dx30 = fmaf(c0d, c1d, -1.0f);
        float dx31 = c0d * s1d;
        float dx32 = -s0d;

        float dX0 = fmaf(T00, dx30, fmaf(T01, dx31, T02 * dx32));
        float dX1 = fmaf(T10, dx30, fmaf(T11, dx31, T12 * dx32));
        float dX2 = fmaf(T20, dx30, T22 * dx32);

        xtx += dX0; xty += dX1; xtz += dX2;

        float xi0 = xix + fmaf(g00, dX0, fmaf(g01, dX1, g02 * dX2));
        float xi1 = xiy + fmaf(g10, dX0, fmaf(g11, dX1, g12 * dX2));
        float xi2 = xiz + fmaf(g20, dX0, fmaf(g21, dX1, g22 * dX2));

        float ri2 = fmaf(xi0, xi0, fmaf(xi1, xi1, xi2 * xi2));
        float rs2 = __builtin_amdgcn_rsqf(ri2);
        float ri  = ri2 * rs2;
        bool outb = ri > RB;
        float n0 = xi0 * rs2, n1 = xi1 * rs2, n2 = xi2 * rs2;
        float coefs = outb ? (2.0f * (ri - RB)) : 0.0f;

        xix = fmaf(-coefs, n0, xi0);
        xiy = fmaf(-coefs, n1, xi1);
        xiz = fmaf(-coefs, n2, xi2);

        float mm0 = fmaf(n0, g00, fmaf(n1, g10, n2 * g20));
        float mm1 = fmaf(n0, g01, fmaf(n1, g11, n2 * g21));
        float mm2 = fmaf(n0, g02, fmaf(n1, g12, n2 * g22));
        float tw  = outb ? 2.0f : 0.0f;
        float tn0 = tw * n0, tn1 = tw * n1, tn2 = tw * n2;
        g00 = fmaf(-tn0, mm0, g00);
        g01 = fmaf(-tn0, mm1, g01);
        g02 = fmaf(-tn0, mm2, g02);
        g10 = fmaf(-tn1, mm0, g10);
        g11 = fmaf(-tn1, mm1, g11);
        g12 = fmaf(-tn1, mm2, g12);
        g20 = fmaf(-tn2, mm0, g20);
        g21 = fmaf(-tn2, mm1, g21);
        g22 = fmaf(-tn2, mm2, g22);

        dBa = dBb;
        int tn = (t + 2 < NSTEP) ? (t + 2) : (NSTEP - 1);
        dBb = *(const float2*)(dBt + ((size_t)tn * NB + p) * 2);
    }
    out[NB + p] = fmaf(xix, xix, fmaf(xiy, xiy, xiz * xiz));
}

// ---------------- consumer: MLP over (chunk of 16 steps) x (16 particles/wave) ----------------
__global__ __launch_bounds__(256, 8) void sde_mlp(
    const float* __restrict__ xt0,
    const uint4* __restrict__ xiw, const float* __restrict__ wz,
    const uint4* __restrict__ wsB,
    const float* __restrict__ bg2, const float* __restrict__ b2u,
    float* __restrict__ partial)
{
    const int tid  = threadIdx.x;
    const int lane = tid & 63;
    const int wv   = tid >> 6;
    const int g16  = (lane >> 4) & 3;
    const int l15  = lane & 15;
    const int blk  = blockIdx.x;            // 8192 blocks
    const int chunk = blk >> 10;            // 0..7
    const int p    = (blk & 1023) * 64 + wv * 16 + l15;

    float u_loc = 0.0f;
    if (chunk == 0) {
        // u_pre0 via the u-weight slot (t = NSTEP)
        float xx = xt0[p * 3 + 0];
        float xy = xt0[p * 3 + 1];
        float xz = xt0[p * 3 + 2];
        f32x4 a2 = mlp_chain(pack_bf16_trunc(xx, xy), pack_bf16_trunc(xz, 1.0f),
                             wsB + (size_t)NSTEP * TBLK, lane, g16);
        u_loc = a2[0] + b2u[0];
    }

#pragma unroll 1
    for (int s = 0; s < 16; s++) {
        int t = chunk * 16 + s;
        uint4 xw = xiw[(size_t)t * NB + p];
        float w2v = wz[(size_t)t * NB + p];
        f32x4 a2 = mlp_chain(xw.x, xw.y, wsB + (size_t)t * TBLK, lane, g16);
        const float* c2 = bg2 + (size_t)t * 3;
        u_loc = fmaf(a2[0] + c2[0], __uint_as_float(xw.z), u_loc);
        u_loc = fmaf(a2[1] + c2[1], __uint_as_float(xw.w), u_loc);
        u_loc = fmaf(a2[2] + c2[2], w2v, u_loc);
    }
    if (g16 == 0) partial[(size_t)chunk * NB + p] = u_loc;
}

__global__ __launch_bounds__(256) void sde_reduce(const float* __restrict__ partial,
                                                  float* __restrict__ out) {
    int p = blockIdx.x * 256 + threadIdx.x;
    float s = 0.0f;
#pragma unroll
    for (int c = 0; c < 8; c++) s += partial[(size_t)c * NB + p];
    out[p] = s;
}

// --------- unpacked helper (u_pre0 prologue of mid-fallback and sde_ref) ----------
__device__ __forceinline__ void mlp_h2_unpacked(float xx, float xy, float xz,
                                                const float* __restrict__ w0,
                                                const float* __restrict__ c0,
                                                const float* __restrict__ w1,
                                                int lane, f32x4* acc) {
    const int g16 = (lane >> 4) & 3;
    const int l15 = lane & 15;
#pragma unroll
    for (int kk = 0; kk < 2; kk++) {
        bf16x8 af[4];
#pragma unroll
        for (int I = 0; I < 4; I++) {
            uint pk[4];
#pragma unroll
            for (int ep = 0; ep < 4; ep++) {
                float f0 = w1[(kk * 32 + g16 * 8 + 2 * ep + 0) * HD + I * 16 + l15];
                float f1 = w1[(kk * 32 + g16 * 8 + 2 * ep + 1) * HD + I * 16 + l15];
                pk[ep] = (uint)bf16_rne(f0) | ((uint)bf16_rne(f1) << 16);
            }
            uint4 v; v.x = pk[0]; v.y = pk[1]; v.z = pk[2]; v.w = pk[3];
            af[I] = __builtin_bit_cast(bf16x8, v);
        }
        const float* wk = w0 + kk * 32 + g16 * 8;
        float4 wxa = *(const float4*)(wk);
        float4 wxb = *(const float4*)(wk + 4);
        float4 wya = *(const float4*)(wk + HD);
        float4 wyb = *(const float4*)(wk + HD + 4);
        float4 wza = *(const float4*)(wk + 2 * HD);
        float4 wzb = *(const float4*)(wk + 2 * HD + 4);
        const float* ck = c0 + kk * 32 + g16 * 8;
        float4 cva = *(const float4*)(ck);
        float4 cvb = *(const float4*)(ck + 4);
        float p0 = fmaf(xx, wxa.x, fmaf(xy, wya.x, fmaf(xz, wza.x, cva.x)));
        float p1 = fmaf(xx, wxa.y, fmaf(xy, wya.y, fmaf(xz, wza.y, cva.y)));
        float p2 = fmaf(xx, wxa.z, fmaf(xy, wya.z, fmaf(xz, wza.z, cva.z)));
        float p3 = fmaf(xx, wxa.w, fmaf(xy, wya.w, fmaf(xz, wza.w, cva.w)));
        float p4 = fmaf(xx, wxb.x, fmaf(xy, wyb.x, fmaf(xz, wzb.x, cvb.x)));
        float p5 = fmaf(xx, wxb.y, fmaf(xy, wyb.y, fmaf(xz, wzb.y, cvb.y)));
        float p6 = fmaf(xx, wxb.z, fmaf(xy, wyb.z, fmaf(xz, wzb.z, cvb.z)));
        float p7 = fmaf(xx, wxb.w, fmaf(xy, wyb.w, fmaf(xz, wzb.w, cvb.w)));
        uint4 bv;
        bv.x = pack_bf16_trunc(tanh_fast(p0), tanh_fast(p1));
        bv.y = pack_bf16_trunc(tanh_fast(p2), tanh_fast(p3));
        bv.z = pack_bf16_trunc(tanh_fast(p4), tanh_fast(p5));
        bv.w = pack_bf16_trunc(tanh_fast(p6), tanh_fast(p7));
        bf16x8 bf = __builtin_bit_cast(bf16x8, bv);
#pragma unroll
        for (int I = 0; I < 4; I++)
            acc[I] = __builtin_amdgcn_mfma_f32_16x16x32_bf16(af[I], bf, acc[I], 0, 0, 0);
    }
}

// ------------- mid-fallback: R9 monolithic kernel (replicated A2, no shfl) -------------
__global__ __launch_bounds__(256, 4) void sde_fast(
    const float* __restrict__ xt0,
    const float* __restrict__ dBt,
    const float* __restrict__ W0u, const float* __restrict__ b0u,
    const float* __restrict__ W1u, const float* __restrict__ b1u,
    const float* __restrict__ W2u, const float* __restrict__ b2u,
    const float* __restrict__ bg2,
    const uint4* __restrict__ wsB,
    float* __restrict__ out)
{
    const int tid  = threadIdx.x;
    const int lane = tid & 63;
    const int wv   = tid >> 6;
    const int g16  = (lane >> 4) & 3;
    const int l15  = lane & 15;
    const int p    = blockIdx.x * 64 + wv * 16 + l15;

    float xtx = xt0[p * 3 + 0];
    float xty = xt0[p * 3 + 1];
    float xtz = xt0[p * 3 + 2];
    float xix = xtx, xiy = xty, xiz = xtz;
    float g00 = 1.f, g01 = 0.f, g02 = 0.f;
    float g10 = 0.f, g11 = 1.f, g12 = 0.f;
    float g20 = 0.f, g21 = 0.f, g22 = 1.f;

    float u_pre;
    {
        f32x4 acc[4];
#pragma unroll
        for (int I = 0; I < 4; I++) acc[I] = (f32x4){0.f, 0.f, 0.f, 0.f};
        mlp_h2_unpacked(xtx, xty, xtz, W0u, b0u, W1u, lane, acc);
        float pj = 0.f;
#pragma unroll
        for (int I = 0; I < 4; I++) {
            float4 wv2 = *(const float4*)(W2u + I * 16 + g16 * 4);
            float4 cv  = *(const float4*)(b1u + I * 16 + g16 * 4);
            pj = fmaf(tanh_fast(acc[I][0] + cv.x), wv2.x, pj);
            pj = fmaf(tanh_fast(acc[I][1] + cv.y), wv2.y, pj);
            pj = fmaf(tanh_fast(acc[I][2] + cv.z), wv2.z, pj);
            pj = fmaf(tanh_fast(acc[I][3] + cv.w), wv2.w, pj);
        }
        pj += __shfl_xor(pj, 16, 64);
        pj += __shfl_xor(pj, 32, 64);
        u_pre = pj + b2u[0];
    }

#pragma unroll 1
    for (int t = 0; t < NSTEP; t++) {
        const uint4* blob_t = wsB + (size_t)t * TBLK;
        const float* c2     = bg2 + (size_t)t * 3;

        float d  = fmaf(xtx, xtx, fmaf(xty, xty, xtz * xtz));
        float rs = __builtin_amdgcn_rsqf(d);
        float uu = xtz * rs;
        uu = fminf(fmaxf(uu, -0.999999f), 0.999999f);
        float sa = -uu;
        float rho2 = fmaf(xtx, xtx, xty * xty);
        bool hasrho = rho2 > 0.0f;
        float rr = __builtin_amdgcn_rsqf(rho2);
        float cp = hasrho ? (xtx * rr) : 1.0f;
        float sp = hasrho ? (xty * rr) : 0.0f;
        float ca = hasrho ? (rho2 * rr * rs) : 1.4142135e-3f;
        float T00 = cp * ca, T01 = -sp, T02 = cp * sa;
        float T10 = sp * ca, T11 = cp,  T12 = sp * sa;
        float T20 = -sa,               T22 = ca;

        f32x4 a2 = mlp_chain(pack_bf16_trunc(xix, xiy), pack_bf16_trunc(xiz, 1.0f),
                             blob_t, lane, g16);
        float gv0 = a2[0] + c2[0];
        float gv1 = a2[1] + c2[1];
        float gv2 = a2[2] + c2[2];

        float M01 = fmaf(-sp, g00, cp * g01);
        float M11 = fmaf(-sp, g10, cp * g11);
        float M21 = fmaf(-sp, g20, cp * g21);
        float M02 = fmaf(g00, T02, fmaf(g01, T12, g02 * T22));
        float M12 = fmaf(g10, T02, fmaf(g11, T12, g12 * T22));
        float M22 = fmaf(g20, T02, fmaf(g21, T12, g22 * T22));
        float v1 = fmaf(gv0, M01, fmaf(gv1, M11, gv2 * M21));
        float v2 = fmaf(gv0, M02, fmaf(gv1, M12, gv2 * M22));

        const float2 dB = *(const float2*)(dBt + ((size_t)t * NB + p) * 2);
        float dB0 = dB.x, dB1 = dB.y;
        u_pre += fmaf(v1, dB1, -v2 * dB0);

        float s0d, c0d, s1d, c1d;
        sincos_small(dB0, s0d, c0d);
        sincos_small(dB1, s1d, c1d);
        float dx30 = fmaf(c0d, c1d, -1.0f);
        float dx31 = c0d * s1d;
        float dx32 = -s0d;

        float dX0 = fmaf(T00, dx30, fmaf(T01, dx31, T02 * dx32));
        float dX1 = fmaf(T10, dx30, fmaf(T11, dx31, T12 * dx32));
        float dX2 = fmaf(T20, dx30, T22 * dx32);

        xtx += dX0; xty += dX1; xtz += dX2;

        float xi0 = xix + fmaf(g00, dX0, fmaf(g01, dX1, g02 * dX2));
        float xi1 = xiy + fmaf(g10, dX0, fmaf(g11, dX1, g12 * dX2));
        float xi2 = xiz + fmaf(g20, dX0, fmaf(g21, dX1, g22 * dX2));

        float ri2 = fmaf(xi0, xi0, fmaf(xi1, xi1, xi2 * xi2));
        float rs2 = __builtin_amdgcn_rsqf(ri2);
        float ri  = ri2 * rs2;
        bool outb = ri > RB;
        float n0 = xi0 * rs2, n1 = xi1 * rs2, n2 = xi2 * rs2;
        float coefs = outb ? (2.0f * (ri - RB)) : 0.0f;

        xix = fmaf(-coefs, n0, xi0);
        xiy = fmaf(-coefs, n1, xi1);
        xiz = fmaf(-coefs, n2, xi2);

        float mm0 = fmaf(n0, g00, fmaf(n1, g10, n2 * g20));
        float mm1 = fmaf(n0, g01, fmaf(n1, g11, n2 * g21));
        float mm2 = fmaf(n0, g02, fmaf(n1, g12, n2 * g22));
        float tw  = outb ? 2.0f : 0.0f;
        float tn0 = tw * n0, tn1 = tw * n1, tn2 = tw * n2;
        g00 = fmaf(-tn0, mm0, g00);
        g01 = fmaf(-tn0, mm1, g01);
        g02 = fmaf(-tn0, mm2, g02);
        g10 = fmaf(-tn1, mm0, g10);
        g11 = fmaf(-tn1, mm1, g11);
        g12 = fmaf(-tn1, mm2, g12);
        g20 = fmaf(-tn2, mm0, g20);
        g21 = fmaf(-tn2, mm1, g21);
        g22 = fmaf(-tn2, mm2, g22);
    }

    float u_rel = fmaf(xix, xix, fmaf(xiy, xiy, xiz * xiz));
    if (g16 == 0) {
        out[p] = u_pre;
        out[NB + p] = u_rel;
    }
}

// ------------------- final fallback (R3-style, unpacked weights) -------------------
__global__ __launch_bounds__(256, 4) void sde_ref(
    const float* __restrict__ xt0,
    const float* __restrict__ dBt,
    const float* __restrict__ W0u, const float* __restrict__ b0u,
    const float* __restrict__ W1u, const float* __restrict__ b1u,
    const float* __restrict__ W2u, const float* __restrict__ b2u,
    const float* __restrict__ Wg0, const float* __restrict__ bg0,
    const float* __restrict__ Wg1, const float* __restrict__ bg1,
    const float* __restrict__ Wg2, const float* __restrict__ bg2,
    float* __restrict__ out)
{
    const int tid  = threadIdx.x;
    const int lane = tid & 63;
    const int wv   = tid >> 6;
    const int g16  = (lane >> 4) & 3;
    const int l15  = lane & 15;
    const int p    = blockIdx.x * 64 + wv * 16 + l15;

    float xtx = xt0[p * 3 + 0];
    float xty = xt0[p * 3 + 1];
    float xtz = xt0[p * 3 + 2];
    float xix = xtx, xiy = xty, xiz = xtz;
    float g00 = 1.f, g01 = 0.f, g02 = 0.f;
    float g10 = 0.f, g11 = 1.f, g12 = 0.f;
    float g20 = 0.f, g21 = 0.f, g22 = 1.f;

    float u_pre;
    {
        f32x4 acc[4];
#pragma unroll
        for (int I = 0; I < 4; I++) acc[I] = (f32x4){0.f, 0.f, 0.f, 0.f};
        mlp_h2_unpacked(xtx, xty, xtz, W0u, b0u, W1u, lane, acc);
        float pj = 0.f;
#pragma unroll
        for (int I = 0; I < 4; I++) {
            float4 wv2 = *(const float4*)(W2u + I * 16 + g16 * 4);
            float4 cv  = *(const float4*)(b1u + I * 16 + g16 * 4);
            pj = fmaf(tanh_fast(acc[I][0] + cv.x), wv2.x, pj);
            pj = fmaf(tanh_fast(acc[I][1] + cv.y), wv2.y, pj);
            pj = fmaf(tanh_fast(acc[I][2] + cv.z), wv2.z, pj);
            pj = fmaf(tanh_fast(acc[I][3] + cv.w), wv2.w, pj);
        }
        pj += __shfl_xor(pj, 16, 64);
        pj += __shfl_xor(pj, 32, 64);
        u_pre = pj + b2u[0];
    }

#pragma unroll 1
    for (int t = 0; t < NSTEP; t++) {
        const float* w0 = Wg0 + (size_t)t * 3 * HD;
        const float* c0 = bg0 + (size_t)t * HD;
        const float* c1 = bg1 + (size_t)t * HD;
        const float* w2 = Wg2 + (size_t)t * HD * 3;
        const float* c2 = bg2 + (size_t)t * 3;

        float r = sqrtf(fmaf(xtx, xtx, fmaf(xty, xty, xtz * xtz)));
        float uu = xtz / r;
        uu = fminf(fmaxf(uu, -0.999999f), 0.999999f);
        float ca = sqrtf((1.0f - uu) * (1.0f + uu));
        float sa = -uu;
        float rho = sqrtf(fmaf(xtx, xtx, xty * xty));
        float cp = (rho > 0.0f) ? (xtx / rho) : 1.0f;
        float sp = (rho > 0.0f) ? (xty / rho) : 0.0f;
        float T00 = cp * ca, T01 = -sp, T02 = cp * sa;
        float T10 = sp * ca, T11 = cp,  T12 = sp * sa;
        float T20 = -sa,               T22 = ca;

        f32x4 acc[4];
#pragma unroll
        for (int I = 0; I < 4; I++) acc[I] = (f32x4){0.f, 0.f, 0.f, 0.f};
        mlp_h2_unpacked(xix, xiy, xiz, w0, c0, Wg1 + (size_t)t * HD * HD, lane, acc);

        float pj0 = 0.f, pj1 = 0.f, pj2 = 0.f;
#pragma unroll
        for (int I = 0; I < 4; I++) {
            const float* wp = w2 + 3 * (I * 16 + g16 * 4);
            float4 wa = *(const float4*)(wp);
            float4 wb = *(const float4*)(wp + 4);
            float4 wc = *(const float4*)(wp + 8);
            float4 cv = *(const float4*)(c1 + I * 16 + g16 * 4);
            float th0 = tanh_fast(acc[I][0] + cv.x);
            float th1 = tanh_fast(acc[I][1] + cv.y);
            float th2 = tanh_fast(acc[I][2] + cv.z);
            float th3 = tanh_fast(acc[I][3] + cv.w);
            pj0 = fmaf(th0, wa.x, pj0); pj1 = fmaf(th0, wa.y, pj1); pj2 = fmaf(th0, wa.z, pj2);
            pj0 = fmaf(th1, wa.w, pj0); pj1 = fmaf(th1, wb.x, pj1); pj2 = fmaf(th1, wb.y, pj2);
            pj0 = fmaf(th2, wb.z, pj0); pj1 = fmaf(th2, wb.w, pj1); pj2 = fmaf(th2, wc.x, pj2);
            pj0 = fmaf(th3, wc.y, pj0); pj1 = fmaf(th3, wc.z, pj1); pj2 = fmaf(th3, wc.w, pj2);
        }
        pj0 += __shfl_xor(pj0, 16, 64); pj0 += __shfl_xor(pj0, 32, 64);
        pj1 += __shfl_xor(pj1, 16, 64); pj1 += __shfl_xor(pj1, 32, 64);
        pj2 += __shfl_xor(pj2, 16, 64); pj2 += __shfl_xor(pj2, 32, 64);
        float gv0 = pj0 + c2[0];
        float gv1 = pj1 + c2[1];
        float gv2 = pj2 + c2[2];

        float M01 = fmaf(-sp, g00, cp * g01);
        float M11 = fmaf(-sp, g10, cp * g11);
        float M21 = fmaf(-sp, g20, cp * g21);
        float M02 = fmaf(g00, T02, fmaf(g01, T12, g02 * T22));
        float M12 = fmaf(g10, T02, fmaf(g11, T12, g12 * T22));
        float M22 = fmaf(g20, T02, fmaf(g21, T12, g22 * T22));
        float v1 = fmaf(gv0, M01, fmaf(gv1, M11, gv2 * M21));
        float v2 = fmaf(gv0, M02, fmaf(gv1, M12, gv2 * M22));

        const float2 dB = *(const float2*)(dBt + ((size_t)t * NB + p) * 2);
        float dB0 = dB.x, dB1 = dB.y;
        u_pre += fmaf(v1, dB1, -v2 * dB0);

        float s0d, c0d, s1d, c1d;
        __sincosf(dB0, &s0d, &c0d);
        __sincosf(dB1, &s1d, &c1d);
        float dx30 = fmaf(c0d, c1d, -1.0f);
        float dx31 = c0d * s1d;
        float dx32 = -s0d;

        float dX0 = fmaf(T00, dx30, fmaf(T01, dx31, T02 * dx32));
        float dX1 = fmaf(T10, dx30, fmaf(T11, dx31, T12 * dx32));
        float dX2 = fmaf(T20, dx30, T22 * dx32);

        xtx += dX0; xty += dX1; xtz += dX2;

        float xi0 = xix + fmaf(g00, dX0, fmaf(g01, dX1, g02 * dX2));
        float xi1 = xiy + fmaf(g10, dX0, fmaf(g11, dX1, g12 * dX2));
        float xi2 = xiz + fmaf(g20, dX0, fmaf(g21, dX1, g22 * dX2));

        float ri = sqrtf(fmaf(xi0, xi0, fmaf(xi1, xi1, xi2 * xi2)));
        bool outb = ri > RB;
        float n0 = xi0 / ri, n1 = xi1 / ri, n2 = xi2 / ri;
        float coef = 2.0f * (ri - RB);

        xix = outb ? fmaf(-coef, n0, xi0) : xi0;
        xiy = outb ? fmaf(-coef, n1, xi1) : xi1;
        xiz = outb ? fmaf(-coef, n2, xi2) : xi2;

        float mm0 = fmaf(n0, g00, fmaf(n1, g10, n2 * g20));
        float mm1 = fmaf(n0, g01, fmaf(n1, g11, n2 * g21));
        float mm2 = fmaf(n0, g02, fmaf(n1, g12, n2 * g22));
        float tn0 = 2.0f * n0, tn1 = 2.0f * n1, tn2 = 2.0f * n2;
        g00 = outb ? fmaf(-tn0, mm0, g00) : g00;
        g01 = outb ? fmaf(-tn0, mm1, g01) : g01;
        g02 = outb ? fmaf(-tn0, mm2, g02) : g02;
        g10 = outb ? fmaf(-tn1, mm0, g10) : g10;
        g11 = outb ? fmaf(-tn1, mm1, g11) : g11;
        g12 = outb ? fmaf(-tn1, mm2, g12) : g12;
        g20 = outb ? fmaf(-tn2, mm0, g20) : g20;
        g21 = outb ? fmaf(-tn2, mm1, g21) : g21;
        g22 = outb ? fmaf(-tn2, mm2, g22) : g22;
    }

    float u_rel = fmaf(xix, xix, fmaf(xiy, xiy, xiz * xiz));
    if (g16 == 0) {
        out[p] = u_pre;
        out[NB + p] = u_rel;
    }
}

extern "C" void kernel_launch(void* const* d_in, const int* in_sizes, int n_in,
                              void* d_out, int out_size, void* d_ws, size_t ws_size,
                              hipStream_t stream) {
    const float* xt0 = (const float*)d_in[0];
    const float* dBt = (const float*)d_in[1];
    const float* W0u = (const float*)d_in[2];
    const float* b0u = (const float*)d_in[3];
    const float* W1u = (const float*)d_in[4];
    const float* b1u = (const float*)d_in[5];
    const float* W2u = (const float*)d_in[6];
    const float* b2u = (const float*)d_in[7];
    const float* Wg0 = (const float*)d_in[8];
    const float* bg0 = (const float*)d_in[9];
    const float* Wg1 = (const float*)d_in[10];
    const float* bg1 = (const float*)d_in[11];
    const float* Wg2 = (const float*)d_in[12];
    const float* bg2 = (const float*)d_in[13];
    float* out = (float*)d_out;

    const size_t SZ_BLOB = (size_t)(NSTEP + 1) * TBLK * sizeof(uint4);  // ~1.87 MB
    const size_t SZ_XIW  = (size_t)NSTEP * NB * sizeof(uint4);          // 128 MB
    const size_t SZ_WZ   = (size_t)NSTEP * NB * sizeof(float);          // 32 MB
    const size_t SZ_PART = (size_t)8 * NB * sizeof(float);              // 2 MB

    if (ws_size >= SZ_BLOB + SZ_XIW + SZ_WZ + SZ_PART && d_ws != nullptr) {
        uint4* wsB     = (uint4*)d_ws;
        uint4* xiw     = (uint4*)((char*)d_ws + SZ_BLOB);
        float* wz      = (float*)((char*)d_ws + SZ_BLOB + SZ_XIW);
        float* partial = (float*)((char*)d_ws + SZ_BLOB + SZ_XIW + SZ_WZ);
        hipLaunchKernelGGL(prep_a1,  dim3(258), dim3(256), 0, stream, Wg1, W1u, wsB);
        hipLaunchKernelGGL(prep_a0,  dim3(129), dim3(256), 0, stream, Wg0, bg0, W0u, b0u, wsB);
        hipLaunchKernelGGL(prep_a2,  dim3(65),  dim3(256), 0, stream, Wg2, W2u, wsB);
        hipLaunchKernelGGL(prep_bias, dim3(65), dim3(256), 0, stream, bg1, b1u, wsB);
        hipLaunchKernelGGL(sde_state, dim3(NB / 256), dim3(256), 0, stream,
                           xt0, dBt, xiw, wz, out);
        hipLaunchKernelGGL(sde_mlp, dim3(8192), dim3(256), 0, stream,
                           xt0, (const uint4*)xiw, (const float*)wz,
                           (const uint4*)wsB, bg2, b2u, partial);
        hipLaunchKernelGGL(sde_reduce, dim3(NB / 256), dim3(256), 0, stream,
                           (const float*)partial, out);
    } else if (ws_size >= SZ_BLOB && d_ws != nullptr) {
        uint4* wsB = (uint4*)d_ws;
        hipLaunchKernelGGL(prep_a1,  dim3(258), dim3(256), 0, stream, Wg1, W1u, wsB);
        hipLaunchKernelGGL(prep_a0,  dim3(129), dim3(256), 0, stream, Wg0, bg0, W0u, b0u, wsB);
        hipLaunchKernelGGL(prep_a2,  dim3(65),  dim3(256), 0, stream, Wg2, W2u, wsB);
        hipLaunchKernelGGL(prep_bias, dim3(65), dim3(256), 0, stream, bg1, b1u, wsB);
        hipLaunchKernelGGL(sde_fast, dim3(NB * 4 / 256), dim3(256), 0, stream,
                           xt0, dBt, W0u, b0u, W1u, b1u, W2u, b2u,
                           bg2, (const uint4*)wsB, out);
    } else {
        hipLaunchKernelGGL(sde_ref, dim3(NB * 4 / 256), dim3(256), 0, stream,
                           xt0, dBt, W0u, b0u, W1u, b1u, W2u, b2u,
                           Wg0, bg0, Wg1, bg1, Wg2, bg2, out);
    }
}